// Round 9
// baseline (6608.927 us; speedup 1.0000x reference)
//
#include <hip/hip_runtime.h>
#include <math.h>

// DNC forward, fp32. Round 9: identical pipeline to round 8 (3975us) PLUS
// four diagnostic memchain probe dispatches on dead scratch after k_y.
// Probes ablate: V0 full / V1 no-P5(link) / V2 no-butterfly / V3 no-alloc.

#define BZ    16
#define TZ    64
#define HID   512
#define NCELL 256
#define CSZ   64
#define NRD   4
#define G4H   2048
#define IFC   471
#define DEL   1e-6f
#define SMT   257   // LDS mem^T row stride (odd -> conflict-free columns)
#define NLSTM 192
#define NTOT  224
#define PSTEPS 16   // probe step count

__device__ __forceinline__ float sig_(float x) { return 1.f / (1.f + expf(-x)); }
__device__ __forceinline__ float splus_(float x) { return fmaxf(x, 0.f) + log1pf(expf(-fabsf(x))); }

// relaxed-poll until *ptr >= tgt, then ONE acquire load (sync edge, 1 L2 inval)
template <int SLP>
__device__ __forceinline__ unsigned poll_acq(unsigned* ptr, unsigned tgt) {
  unsigned v;
  while ((v = __hip_atomic_load(ptr, __ATOMIC_RELAXED, __HIP_MEMORY_SCOPE_AGENT)) < tgt)
    __builtin_amdgcn_s_sleep(SLP);
  v = __hip_atomic_load(ptr, __ATOMIC_ACQUIRE, __HIP_MEMORY_SCOPE_AGENT);
  return v;
}

// ---------------------------------------------------------------- transpose
__global__ __launch_bounds__(256) void k_transpose(const float* __restrict__ src,
                                                   float* __restrict__ dst,
                                                   int rows, int cols, int kmax, int dst_stride) {
  __shared__ float tile[32][33];
  int c0 = blockIdx.x * 32, r0 = blockIdx.y * 32;
  int tx = threadIdx.x, ty = threadIdx.y;
  for (int i = ty; i < 32; i += 8) {
    int r = r0 + i, c = c0 + tx;
    tile[i][tx] = (r < rows && c < cols) ? src[(size_t)r * cols + c] : 0.f;
  }
  __syncthreads();
  for (int i = ty; i < 32; i += 8) {
    int c = c0 + i, r = r0 + tx;
    if (c < kmax && r < rows) dst[(size_t)c * dst_stride + r] = tile[tx][i];
  }
}

// ---------------------------------------------------------------- xpart GEMM
__global__ __launch_bounds__(256) void k_xpart(const float* __restrict__ x,
                                               const float* __restrict__ Wih0T,
                                               const float* __restrict__ bih0,
                                               const float* __restrict__ bhh0,
                                               float* __restrict__ xpart) {
  const int lane = threadIdx.x, ty = threadIdx.y;
  const int jg = blockIdx.x * 64 + lane;
  const int tb0 = blockIdx.y * 16;
  __shared__ float sx[16][256];
  const int tid = ty * 64 + lane;
  for (int idx = tid; idx < 16 * 256; idx += 256) {
    int row = idx >> 8, k = idx & 255;
    int tb = tb0 + row, tt = tb >> 4, bb = tb & 15;
    sx[row][k] = x[((size_t)bb * TZ + tt) * 256 + k];
  }
  __syncthreads();
  float acc[4] = {0.f, 0.f, 0.f, 0.f};
  for (int k = 0; k < 256; ++k) {
    float wv = Wih0T[(size_t)k * G4H + jg];
#pragma unroll
    for (int i = 0; i < 4; ++i) acc[i] = fmaf(wv, sx[ty * 4 + i][k], acc[i]);
  }
  float bias = bih0[jg] + bhh0[jg];
#pragma unroll
  for (int i = 0; i < 4; ++i)
    xpart[(size_t)(tb0 + ty * 4 + i) * G4H + jg] = acc[i] + bias;
}

// ---------------------------------------------------------------- grid barrier (LSTM blocks only)
__device__ __forceinline__ void gbar(unsigned* done, unsigned* go,
                                     unsigned tgt, int bid, int tid) {
  __syncthreads();
  if (bid == 0) {
    if (tid == 0)
      __hip_atomic_store(&done[0], tgt, __ATOMIC_RELEASE, __HIP_MEMORY_SCOPE_AGENT);
    if (tid < NLSTM) (void)poll_acq<4>(&done[tid], tgt);
    __syncthreads();
    if (tid == 0)
      __hip_atomic_store(go, tgt, __ATOMIC_RELEASE, __HIP_MEMORY_SCOPE_AGENT);
  } else {
    if (tid == 0) {
      __hip_atomic_store(&done[bid], tgt, __ATOMIC_RELEASE, __HIP_MEMORY_SCOPE_AGENT);
      (void)poll_acq<4>(go, tgt);
    }
    __syncthreads();
  }
}

#define SCR(s, i) scr[(s) * 1320 + (i)]

// ---------------------------------------------------------------- fused persistent kernel
__global__ __launch_bounds__(1024, 1) void k_fused(
    const float* __restrict__ xpart,
    const float* __restrict__ Whh0,
    const float* __restrict__ Wih1, const float* __restrict__ Whh1,
    const float* __restrict__ bih1, const float* __restrict__ bhh1,
    const float* __restrict__ WifT, const float* __restrict__ bif,
    float* __restrict__ h0g, float* __restrict__ h1g,
    float* __restrict__ h1_all, float* __restrict__ xi_all,
    float* __restrict__ linkg, float* __restrict__ rv_all,
    unsigned* __restrict__ done, unsigned* __restrict__ go,
    unsigned* __restrict__ xiflag) {
  const int tid = threadIdx.x;
  const int bid = blockIdx.x;
  __shared__ __align__(16) float SMEM[37264];

  if (bid < 64) {
    // ================= cell0 =================
    float* w0 = SMEM;               // [32][524]
    float* hl = SMEM + 16768;       // [16][520]
    float* sc = hl + 8320;          // [8][512]
    float* xpl = sc + 4096;         // [512]
    float* c0l = xpl + 512;         // [128]
    const int j0 = bid * 8;
    for (int lr = 0; lr < 32; ++lr) {
      int g = lr >> 3, jj2 = lr & 7;
      const float* src = Whh0 + (size_t)(g * 512 + j0 + jj2) * 512;
      for (int k = tid; k < 512; k += 1024) w0[lr * 524 + k] = src[k];
    }
    if (tid < 128) c0l[tid] = 0.f;
    const int ks = tid & 7, bq = (tid >> 3) & 3, jj = tid >> 5;
    const int wr0 = (0 * 8 + (jj & 7)) * 524, wr1 = (1 * 8 + (jj & 7)) * 524,
              wr2 = (2 * 8 + (jj & 7)) * 524, wr3 = (3 * 8 + (jj & 7)) * 524;
    const int hb0 = (bq * 4 + 0) * 520, hb1 = (bq * 4 + 1) * 520,
              hb2 = (bq * 4 + 2) * 520, hb3 = (bq * 4 + 3) * 520;
    for (int ph = 0; ph < 65; ++ph) {
      if (ph < 64) {
        const int t = ph, po = t & 1, pn = po ^ 1;
        for (int q = tid; q < 2048; q += 1024) {
          int bb = q >> 7, kq = q & 127;
          ((float4*)&hl[bb * 520])[kq] = ((const float4*)&h0g[(size_t)(po * 16 + bb) * 512])[kq];
        }
        if (tid < 512) {
          int bb = tid >> 5, g = (tid >> 3) & 3, j2 = tid & 7;
          xpl[tid] = xpart[((size_t)t * 16 + bb) * G4H + g * 512 + j0 + j2];
        }
        __syncthreads();
        if (tid < 256) {
          float4 a0 = {0,0,0,0}, a1 = {0,0,0,0}, a2 = {0,0,0,0}, a3 = {0,0,0,0};
#pragma unroll 4
          for (int i = 0; i < 16; ++i) {
            const int off = ks * 4 + 32 * i;
            float4 w4a = *(const float4*)&w0[wr0 + off];
            float4 w4b = *(const float4*)&w0[wr1 + off];
            float4 w4c = *(const float4*)&w0[wr2 + off];
            float4 w4d = *(const float4*)&w0[wr3 + off];
            float4 h4a = *(const float4*)&hl[hb0 + off];
            float4 h4b = *(const float4*)&hl[hb1 + off];
            float4 h4c = *(const float4*)&hl[hb2 + off];
            float4 h4d = *(const float4*)&hl[hb3 + off];
            a0.x += w4a.x*h4a.x + w4a.y*h4a.y + w4a.z*h4a.z + w4a.w*h4a.w;
            a0.y += w4a.x*h4b.x + w4a.y*h4b.y + w4a.z*h4b.z + w4a.w*h4b.w;
            a0.z += w4a.x*h4c.x + w4a.y*h4c.y + w4a.z*h4c.z + w4a.w*h4c.w;
            a0.w += w4a.x*h4d.x + w4a.y*h4d.y + w4a.z*h4d.z + w4a.w*h4d.w;
            a1.x += w4b.x*h4a.x + w4b.y*h4a.y + w4b.z*h4a.z + w4b.w*h4a.w;
            a1.y += w4b.x*h4b.x + w4b.y*h4b.y + w4b.z*h4b.z + w4b.w*h4b.w;
            a1.z += w4b.x*h4c.x + w4b.y*h4c.y + w4b.z*h4c.z + w4b.w*h4c.w;
            a1.w += w4b.x*h4d.x + w4b.y*h4d.y + w4b.z*h4d.z + w4b.w*h4d.w;
            a2.x += w4c.x*h4a.x + w4c.y*h4a.y + w4c.z*h4a.z + w4c.w*h4a.w;
            a2.y += w4c.x*h4b.x + w4c.y*h4b.y + w4c.z*h4b.z + w4c.w*h4b.w;
            a2.z += w4c.x*h4c.x + w4c.y*h4c.y + w4c.z*h4c.z + w4c.w*h4c.w;
            a2.w += w4c.x*h4d.x + w4c.y*h4d.y + w4c.z*h4d.z + w4c.w*h4d.w;
            a3.x += w4d.x*h4a.x + w4d.y*h4a.y + w4d.z*h4a.z + w4d.w*h4a.w;
            a3.y += w4d.x*h4b.x + w4d.y*h4b.y + w4d.z*h4b.z + w4d.w*h4b.w;
            a3.z += w4d.x*h4c.x + w4d.y*h4c.y + w4d.z*h4c.z + w4d.w*h4c.w;
            a3.w += w4d.x*h4d.x + w4d.y*h4d.y + w4d.z*h4d.z + w4d.w*h4d.w;
          }
          *(float4*)&sc[ks * 512 + (0 * 8 + jj) * 16 + bq * 4] = a0;
          *(float4*)&sc[ks * 512 + (1 * 8 + jj) * 16 + bq * 4] = a1;
          *(float4*)&sc[ks * 512 + (2 * 8 + jj) * 16 + bq * 4] = a2;
          *(float4*)&sc[ks * 512 + (3 * 8 + jj) * 16 + bq * 4] = a3;
        }
        __syncthreads();
        if (tid < 128) {
          const int bb = tid >> 3, j2 = tid & 7;
          float gs[4];
#pragma unroll
          for (int g = 0; g < 4; ++g) {
            float s = 0.f;
#pragma unroll
            for (int k2 = 0; k2 < 8; ++k2) s += sc[k2 * 512 + (g * 8 + j2) * 16 + bb];
            gs[g] = s + xpl[bb * 32 + g * 8 + j2];
          }
          float gi = sig_(gs[0]), gf = sig_(gs[1]), gg = tanhf(gs[2]), go_ = sig_(gs[3]);
          float cc = gf * c0l[j2 * 16 + bb] + gi * gg;
          c0l[j2 * 16 + bb] = cc;
          h0g[(size_t)(pn * 16 + bb) * 512 + j0 + j2] = go_ * tanhf(cc);
        }
      }
      gbar(done, go, (unsigned)(ph + 1), bid, tid);
    }
  } else if (bid < 192) {
    // ================= cell1 =================
    float* w1 = SMEM;               // [16][1028]
    float* h0l = SMEM + 16448;      // [16][520]
    float* h1l = h0l + 8320;        // [16][520]
    float* sc = h1l + 8320;         // [16][256]
    float* c1l = sc + 4096;         // [64]
    float* bl = c1l + 64;           // [16]
    const int b1 = bid - 64;
    const int j0 = b1 * 4;
    for (int lr = 0; lr < 16; ++lr) {
      int g = lr >> 2, jj2 = lr & 3;
      const float* si = Wih1 + (size_t)(g * 512 + j0 + jj2) * 512;
      const float* sh = Whh1 + (size_t)(g * 512 + j0 + jj2) * 512;
      for (int k = tid; k < 512; k += 1024) {
        w1[lr * 1028 + k] = si[k];
        w1[lr * 1028 + 512 + k] = sh[k];
      }
    }
    if (tid < 64) c1l[tid] = 0.f;
    if (tid < 16) {
      int g = tid >> 2, jj2 = tid & 3;
      bl[tid] = bih1[g * 512 + j0 + jj2] + bhh1[g * 512 + j0 + jj2];
    }
    const int ks = tid & 15, bq = (tid >> 4) & 3, jj = (tid >> 6) & 3;
    const int wr0 = (0 * 4 + jj) * 1028, wr1 = (1 * 4 + jj) * 1028,
              wr2 = (2 * 4 + jj) * 1028, wr3 = (3 * 4 + jj) * 1028;
    const int hb0 = (bq * 4 + 0) * 520, hb1 = (bq * 4 + 1) * 520,
              hb2 = (bq * 4 + 2) * 520, hb3 = (bq * 4 + 3) * 520;
    for (int ph = 0; ph < 65; ++ph) {
      if (ph >= 1) {
        const int t = ph - 1, po = t & 1, pn = po ^ 1;
        for (int q = tid; q < 2048; q += 1024) {
          int bb = q >> 7, kq = q & 127;
          ((float4*)&h0l[bb * 520])[kq] = ((const float4*)&h0g[(size_t)(pn * 16 + bb) * 512])[kq];
          ((float4*)&h1l[bb * 520])[kq] = ((const float4*)&h1g[(size_t)(po * 16 + bb) * 512])[kq];
        }
        __syncthreads();
        if (tid < 256) {
          float4 a0 = {0,0,0,0}, a1 = {0,0,0,0}, a2 = {0,0,0,0}, a3 = {0,0,0,0};
#pragma unroll 4
          for (int i = 0; i < 16; ++i) {
            const int offw = ks * 4 + 64 * i;
            const int offh = (i < 8) ? offw : (offw - 512);
            const float* hsrc = (i < 8) ? h0l : h1l;
            float4 w4a = *(const float4*)&w1[wr0 + offw];
            float4 w4b = *(const float4*)&w1[wr1 + offw];
            float4 w4c = *(const float4*)&w1[wr2 + offw];
            float4 w4d = *(const float4*)&w1[wr3 + offw];
            float4 h4a = *(const float4*)&hsrc[hb0 + offh];
            float4 h4b = *(const float4*)&hsrc[hb1 + offh];
            float4 h4c = *(const float4*)&hsrc[hb2 + offh];
            float4 h4d = *(const float4*)&hsrc[hb3 + offh];
            a0.x += w4a.x*h4a.x + w4a.y*h4a.y + w4a.z*h4a.z + w4a.w*h4a.w;
            a0.y += w4a.x*h4b.x + w4a.y*h4b.y + w4a.z*h4b.z + w4a.w*h4b.w;
            a0.z += w4a.x*h4c.x + w4a.y*h4c.y + w4a.z*h4c.z + w4a.w*h4c.w;
            a0.w += w4a.x*h4d.x + w4a.y*h4d.y + w4a.z*h4d.z + w4a.w*h4d.w;
            a1.x += w4b.x*h4a.x + w4b.y*h4a.y + w4b.z*h4a.z + w4b.w*h4a.w;
            a1.y += w4b.x*h4b.x + w4b.y*h4b.y + w4b.z*h4b.z + w4b.w*h4b.w;
            a1.z += w4b.x*h4c.x + w4b.y*h4c.y + w4b.z*h4c.z + w4b.w*h4c.w;
            a1.w += w4b.x*h4d.x + w4b.y*h4d.y + w4b.z*h4d.z + w4b.w*h4d.w;
            a2.x += w4c.x*h4a.x + w4c.y*h4a.y + w4c.z*h4a.z + w4c.w*h4a.w;
            a2.y += w4c.x*h4b.x + w4c.y*h4b.y + w4c.z*h4b.z + w4c.w*h4b.w;
            a2.z += w4c.x*h4c.x + w4c.y*h4c.y + w4c.z*h4c.z + w4c.w*h4c.w;
            a2.w += w4c.x*h4d.x + w4c.y*h4d.y + w4c.z*h4d.z + w4c.w*h4d.w;
            a3.x += w4d.x*h4a.x + w4d.y*h4a.y + w4d.z*h4a.z + w4d.w*h4a.w;
            a3.y += w4d.x*h4b.x + w4d.y*h4b.y + w4d.z*h4b.z + w4d.w*h4b.w;
            a3.z += w4d.x*h4c.x + w4d.y*h4c.y + w4d.z*h4c.z + w4d.w*h4c.w;
            a3.w += w4d.x*h4d.x + w4d.y*h4d.y + w4d.z*h4d.z + w4d.w*h4d.w;
          }
          *(float4*)&sc[ks * 256 + (0 * 4 + jj) * 16 + bq * 4] = a0;
          *(float4*)&sc[ks * 256 + (1 * 4 + jj) * 16 + bq * 4] = a1;
          *(float4*)&sc[ks * 256 + (2 * 4 + jj) * 16 + bq * 4] = a2;
          *(float4*)&sc[ks * 256 + (3 * 4 + jj) * 16 + bq * 4] = a3;
        }
        __syncthreads();
        if (tid < 64) {
          const int bb = tid >> 2, j2 = tid & 3;
          float gs[4];
#pragma unroll
          for (int g = 0; g < 4; ++g) {
            float s = 0.f;
#pragma unroll
            for (int k2 = 0; k2 < 16; ++k2) s += sc[k2 * 256 + (g * 4 + j2) * 16 + bb];
            gs[g] = s + bl[g * 4 + j2];
          }
          float gi = sig_(gs[0]), gf = sig_(gs[1]), gg = tanhf(gs[2]), go_ = sig_(gs[3]);
          float cc = gf * c1l[j2 * 16 + bb] + gi * gg;
          c1l[j2 * 16 + bb] = cc;
          float hv = go_ * tanhf(cc);
          h1g[(size_t)(pn * 16 + bb) * 512 + j0 + j2] = hv;
          h1_all[((size_t)t * 16 + bb) * 512 + j0 + j2] = hv;
        }
      }
      gbar(done, go, (unsigned)(ph + 1), bid, tid);
    }
  } else if (bid < 208) {
    // ================= xi producer (one per batch) =================
    const int b = bid - 192;
    float* sh1 = SMEM;        // [512]
    float* sxo = SMEM + 512;  // [2][512]
    __shared__ unsigned sgo;
    unsigned seen_go = 0;
    for (int t = 0; t < TZ; ++t) {
      if (tid == 0 && seen_go < (unsigned)(t + 2)) {
        sgo = poll_acq<8>(go, (unsigned)(t + 2));
      }
      __syncthreads();
      seen_go = (sgo > seen_go) ? sgo : seen_go;
      if (tid < 512) sh1[tid] = h1_all[((size_t)t * BZ + b) * HID + tid];
      __syncthreads();
      {
        const int u = tid & 511, half = tid >> 9;
        if (u < IFC) {
          const float* wc = WifT + u;
          const int k0 = half * 256;
          float acc = 0.f;
#pragma unroll 8
          for (int k = k0; k < k0 + 256; ++k)
            acc = fmaf(sh1[k], wc[(size_t)k * 512], acc);
          sxo[half * 512 + u] = acc;
        }
      }
      __syncthreads();
      if (tid < IFC)
        xi_all[((size_t)t * BZ + b) * 512 + tid] = sxo[tid] + sxo[512 + tid] + bif[tid];
      __syncthreads();
      if (tid == 0)
        __hip_atomic_store(&xiflag[b], (unsigned)(t + 1), __ATOMIC_RELEASE, __HIP_MEMORY_SCOPE_AGENT);
    }
  } else {
    // ================= memory-module chain (one per batch) =================
    const int b = bid - 208;
    const int lane = tid & 63;
    const int wv = tid >> 6;
    const int m8 = tid & 255;
    const int seg = tid >> 8;
    float* LNK = linkg + (size_t)b * (NCELL * NCELL);

    float* smemT = SMEM;               // 16448
    float* sxi   = smemT + 16448;      // 472
    float* srkn  = sxi + 472;          // 256 [4][64]
    float* swkn  = srkn + 256;         // 64
    float* sev   = swkn + 64;          // 64
    float* swvv  = sev + 64;           // 64
    float* sscal = swvv + 64;          // 40
    float* srw   = sscal + 40;         // 1024 [4][256]
    float* sww   = srw + 1024;         // 256
    float* susage = sww + 256;         // 256
    float* sprec = susage + 256;       // 256
    float* ssim  = sprec + 256;        // 1024 [4][256]
    float* sfwd  = ssim + 1024;        // 1024 [4][256]
    float* sbwd  = sfwd + 1024;        // 1056 [4][264]
    float* sa    = sbwd + 1056;        // 256
    float* sc_   = sa + 256;           // 256
    float* sb_   = sc_ + 256;          // 256
    int*   srank = (int*)(sb_ + 256);  // 256
    float* scr   = (float*)(srank + 256); // 5280 [4][1320]
    float* sred2 = scr + 5280;         // 64
    __shared__ unsigned sflag;

    for (int i = tid; i < CSZ * SMT; i += 1024) smemT[i] = 0.f;
    if (tid < 256) {
      sww[tid] = 0.f; susage[tid] = 0.f; sprec[tid] = 0.f;
      srw[tid] = 0.f; srw[256 + tid] = 0.f; srw[512 + tid] = 0.f; srw[768 + tid] = 0.f;
    }
    for (int i = tid; i < (NCELL * NCELL) / 4; i += 1024)
      ((float4*)LNK)[i] = make_float4(0.f, 0.f, 0.f, 0.f);
    __syncthreads();

    unsigned seen = 0;
    for (int t = 0; t < TZ; ++t) {
      if (tid == 0 && seen < (unsigned)(t + 1)) {
        sflag = poll_acq<8>(&xiflag[b], (unsigned)(t + 1));
      }
      __syncthreads();
      if (seen < (unsigned)(t + 1)) seen = sflag;

      // ---- P0: load + parse xi ----
      if (tid < IFC) sxi[tid] = xi_all[((size_t)t * BZ + b) * 512 + tid];
      __syncthreads();
      if (wv < 4) {
        float v = tanhf(sxi[wv * 64 + lane]);
        float s2 = v * v;
#pragma unroll
        for (int off = 32; off; off >>= 1) s2 += __shfl_xor(s2, off);
        srkn[wv * 64 + lane] = v / (sqrtf(s2) + DEL);
      } else if (wv == 4) {
        float v = tanhf(sxi[260 + lane]);
        float s2 = v * v;
#pragma unroll
        for (int off = 32; off; off >>= 1) s2 += __shfl_xor(s2, off);
        swkn[lane] = v / (sqrtf(s2) + DEL);
      } else if (wv == 5) {
        sev[lane] = sig_(sxi[325 + lane]);
      } else if (wv == 6) {
        swvv[lane] = tanhf(sxi[389 + lane]);
      } else if (wv == 7) {
        if (lane < 4) sscal[lane] = splus_(sxi[256 + lane]);
        if (lane == 4) sscal[4] = splus_(sxi[324]);
        if (lane >= 8 && lane < 12) sscal[lane] = sig_(sxi[453 + (lane - 8)]);
        if (lane == 12) sscal[12] = sig_(sxi[457]);
        if (lane == 13) sscal[13] = sig_(sxi[458]);
        if (lane >= 16 && lane < 20) {
          int r = lane - 16;
          float a = sxi[459 + r * 3], b2 = sxi[460 + r * 3], c2 = sxi[461 + r * 3];
          float mx3 = fmaxf(a, fmaxf(b2, c2));
          float ea = expf(a - mx3), eb = expf(b2 - mx3), ec = expf(c2 - mx3);
          float iv = 1.f / (ea + eb + ec);
          sscal[20 + r * 3 + 0] = ea * iv;
          sscal[20 + r * 3 + 1] = eb * iv;
          sscal[20 + r * 3 + 2] = ec * iv;
        }
      }
      __syncthreads();

      // ---- P1 ----
      float un_r = 0.f;
      if (tid < 256) {
        float wwo = sww[tid], uo = susage[tid];
        float u1 = uo + (1.f - uo) * wwo;
        float psi = 1.f;
#pragma unroll
        for (int r = 0; r < 4; ++r) psi *= 1.f - sscal[8 + r] * srw[r * 256 + tid];
        un_r = u1 * psi;
        susage[tid] = un_r;
      }
      {
        float dot = 0.f, nn = 0.f;
#pragma unroll 4
        for (int w = seg * 16; w < seg * 16 + 16; ++w) {
          float mv = smemT[w * SMT + m8];
          dot = fmaf(mv, swkn[w], dot);
          nn = fmaf(mv, mv, nn);
        }
        SCR(seg, 0 * 264 + m8) = dot;
        SCR(seg, 1 * 264 + m8) = nn;
      }
      __syncthreads();
      float e_r = 0.f, simv = 0.f;
      if (tid < 256) {
        float dot = SCR(0, tid) + SCR(1, tid) + SCR(2, tid) + SCR(3, tid);
        float nn = SCR(0, 264 + tid) + SCR(1, 264 + tid) + SCR(2, 264 + tid) + SCR(3, 264 + tid);
        simv = sscal[4] * dot / (sqrtf(nn) + DEL);
        float mx = simv;
#pragma unroll
        for (int off = 32; off; off >>= 1) mx = fmaxf(mx, __shfl_xor(mx, off));
        if (lane == 0) sred2[wv] = mx;
      }
      __syncthreads();
      if (tid < 256) {
        float mx = fmaxf(fmaxf(sred2[0], sred2[1]), fmaxf(sred2[2], sred2[3]));
        e_r = expf(simv - mx);
        float s = e_r;
#pragma unroll
        for (int off = 32; off; off >>= 1) s += __shfl_xor(s, off);
        if (lane == 0) sred2[8 + wv] = s;
      }
      __syncthreads();
      float wcw_r = 0.f;
      if (tid < 256) {
        float sm = sred2[8] + sred2[9] + sred2[10] + sred2[11];
        wcw_r = e_r / sm;
        sa[tid] = DEL + (1.f - DEL) * un_r;
      }
      __syncthreads();

      // ---- P2 ----
      {
        float um = sa[m8];
        int cnt = 0;
        for (int j2 = seg * 64; j2 < seg * 64 + 64; ++j2) {
          float uj = sa[j2];
          cnt += (uj < um || (uj == um && j2 < m8)) ? 1 : 0;
        }
        ((int*)&SCR(seg, 0))[m8] = cnt;
      }
      __syncthreads();
      if (tid < 256) {
        int rank = ((int*)&SCR(0, 0))[tid] + ((int*)&SCR(1, 0))[tid] +
                   ((int*)&SCR(2, 0))[tid] + ((int*)&SCR(3, 0))[tid];
        srank[tid] = rank;
        sb_[rank] = sa[tid];
      }
      __syncthreads();
      float inc = 0.f;
      if (tid < 256) {
        inc = sb_[tid];
#pragma unroll
        for (int off = 1; off < 64; off <<= 1) {
          float pp = __shfl_up(inc, off);
          if (lane >= off) inc *= pp;
        }
        if (lane == 63) sred2[16 + wv] = inc;
      }
      __syncthreads();
      if (tid < 256) {
        float pref = 1.f;
        for (int w2 = 0; w2 < wv; ++w2) pref *= sred2[16 + w2];
        float excl = __shfl_up(inc, 1);
        if (lane == 0) excl = 1.f;
        sc_[tid] = excl * pref;
      }
      __syncthreads();

      // ---- P3 ----
      if (tid < 256) {
        float alo = (1.f - sa[tid]) * sc_[srank[tid]];
        float wwn = sscal[13] * (sscal[12] * alo + (1.f - sscal[12]) * wcw_r);
        sww[tid] = wwn;
        float s = wwn;
#pragma unroll
        for (int off = 32; off; off >>= 1) s += __shfl_xor(s, off);
        if (lane == 0) sred2[24 + wv] = s;
      }
      __syncthreads();
      if (tid == 0) sscal[14] = sred2[24] + sred2[25] + sred2[26] + sred2[27];

      // ---- P4 ----
      {
        float wm = sww[m8];
        float nn = 0.f, d0 = 0.f, d1 = 0.f, d2 = 0.f, d3 = 0.f;
#pragma unroll 4
        for (int w = seg * 16; w < seg * 16 + 16; ++w) {
          float v = smemT[w * SMT + m8];
          v = v * (1.f - wm * sev[w]) + wm * swvv[w];
          smemT[w * SMT + m8] = v;
          nn = fmaf(v, v, nn);
          d0 = fmaf(v, srkn[0 * 64 + w], d0);
          d1 = fmaf(v, srkn[1 * 64 + w], d1);
          d2 = fmaf(v, srkn[2 * 64 + w], d2);
          d3 = fmaf(v, srkn[3 * 64 + w], d3);
        }
        SCR(seg, 0 * 264 + m8) = nn;
        SCR(seg, 1 * 264 + m8) = d0;
        SCR(seg, 2 * 264 + m8) = d1;
        SCR(seg, 3 * 264 + m8) = d2;
        SCR(seg, 4 * 264 + m8) = d3;
      }
      for (int i = tid; i < NRD * 264; i += 1024) sbwd[i] = 0.f;
      __syncthreads();
      float sv0 = 0.f, sv1 = 0.f, sv2 = 0.f, sv3 = 0.f;
      float e0 = 0.f, e1 = 0.f, e2 = 0.f, e3 = 0.f;
      if (tid < 256) {
        float nn = SCR(0, tid) + SCR(1, tid) + SCR(2, tid) + SCR(3, tid);
        float invn = 1.f / (sqrtf(nn) + DEL);
        sv0 = sscal[0] * (SCR(0, 264 + tid) + SCR(1, 264 + tid) + SCR(2, 264 + tid) + SCR(3, 264 + tid)) * invn;
        sv1 = sscal[1] * (SCR(0, 528 + tid) + SCR(1, 528 + tid) + SCR(2, 528 + tid) + SCR(3, 528 + tid)) * invn;
        sv2 = sscal[2] * (SCR(0, 792 + tid) + SCR(1, 792 + tid) + SCR(2, 792 + tid) + SCR(3, 792 + tid)) * invn;
        sv3 = sscal[3] * (SCR(0, 1056 + tid) + SCR(1, 1056 + tid) + SCR(2, 1056 + tid) + SCR(3, 1056 + tid)) * invn;
        float m0 = sv0, m1 = sv1, m2 = sv2, m3 = sv3;
#pragma unroll
        for (int off = 32; off; off >>= 1) {
          m0 = fmaxf(m0, __shfl_xor(m0, off));
          m1 = fmaxf(m1, __shfl_xor(m1, off));
          m2 = fmaxf(m2, __shfl_xor(m2, off));
          m3 = fmaxf(m3, __shfl_xor(m3, off));
        }
        if (lane == 0) {
          sred2[wv * 4 + 0] = m0; sred2[wv * 4 + 1] = m1;
          sred2[wv * 4 + 2] = m2; sred2[wv * 4 + 3] = m3;
        }
      }
      __syncthreads();
      if (tid < 256) {
        float m0 = fmaxf(fmaxf(sred2[0], sred2[4]), fmaxf(sred2[8], sred2[12]));
        float m1 = fmaxf(fmaxf(sred2[1], sred2[5]), fmaxf(sred2[9], sred2[13]));
        float m2 = fmaxf(fmaxf(sred2[2], sred2[6]), fmaxf(sred2[10], sred2[14]));
        float m3 = fmaxf(fmaxf(sred2[3], sred2[7]), fmaxf(sred2[11], sred2[15]));
        e0 = expf(sv0 - m0); e1 = expf(sv1 - m1); e2 = expf(sv2 - m2); e3 = expf(sv3 - m3);
        float s0 = e0, s1 = e1, s2 = e2, s3 = e3;
#pragma unroll
        for (int off = 32; off; off >>= 1) {
          s0 += __shfl_xor(s0, off); s1 += __shfl_xor(s1, off);
          s2 += __shfl_xor(s2, off); s3 += __shfl_xor(s3, off);
        }
        if (lane == 0) {
          sred2[32 + wv * 4 + 0] = s0; sred2[32 + wv * 4 + 1] = s1;
          sred2[32 + wv * 4 + 2] = s2; sred2[32 + wv * 4 + 3] = s3;
        }
      }
      __syncthreads();
      if (tid < 256) {
        float s0 = sred2[32] + sred2[36] + sred2[40] + sred2[44];
        float s1 = sred2[33] + sred2[37] + sred2[41] + sred2[45];
        float s2 = sred2[34] + sred2[38] + sred2[42] + sred2[46];
        float s3 = sred2[35] + sred2[39] + sred2[43] + sred2[47];
        ssim[0 * 256 + tid] = e0 / s0; ssim[1 * 256 + tid] = e1 / s1;
        ssim[2 * 256 + tid] = e2 / s2; ssim[3 * 256 + tid] = e3 / s3;
      }

      // ---- P5 ----
      {
        const float4 r0 = ((const float4*)(srw + 0 * 256))[lane];
        const float4 r1 = ((const float4*)(srw + 1 * 256))[lane];
        const float4 r2 = ((const float4*)(srw + 2 * 256))[lane];
        const float4 r3 = ((const float4*)(srw + 3 * 256))[lane];
        const float4 wc = ((const float4*)sww)[lane];
        const float4 pc = ((const float4*)sprec)[lane];
        const int n0 = lane * 4;
        float4 bp0 = {0,0,0,0}, bp1 = {0,0,0,0}, bp2 = {0,0,0,0}, bp3 = {0,0,0,0};
        for (int rr = 0; rr < 16; ++rr) {
          const int m = wv * 16 + rr;
          const float wm = sww[m];
          float4 lv = ((float4*)(LNK + (size_t)m * 256))[lane];
          lv.x = (1.f - wm - wc.x) * lv.x + wm * pc.x;
          lv.y = (1.f - wm - wc.y) * lv.y + wm * pc.y;
          lv.z = (1.f - wm - wc.z) * lv.z + wm * pc.z;
          lv.w = (1.f - wm - wc.w) * lv.w + wm * pc.w;
          if (m == n0 + 0) lv.x = 0.f;
          if (m == n0 + 1) lv.y = 0.f;
          if (m == n0 + 2) lv.z = 0.f;
          if (m == n0 + 3) lv.w = 0.f;
          ((float4*)(LNK + (size_t)m * 256))[lane] = lv;
          float f0 = lv.x * r0.x + lv.y * r0.y + lv.z * r0.z + lv.w * r0.w;
          float f1 = lv.x * r1.x + lv.y * r1.y + lv.z * r1.z + lv.w * r1.w;
          float f2 = lv.x * r2.x + lv.y * r2.y + lv.z * r2.z + lv.w * r2.w;
          float f3 = lv.x * r3.x + lv.y * r3.y + lv.z * r3.z + lv.w * r3.w;
#pragma unroll
          for (int off = 32; off; off >>= 1) {
            f0 += __shfl_xor(f0, off); f1 += __shfl_xor(f1, off);
            f2 += __shfl_xor(f2, off); f3 += __shfl_xor(f3, off);
          }
          if (lane == 0) {
            sfwd[0 * 256 + m] = f0; sfwd[1 * 256 + m] = f1;
            sfwd[2 * 256 + m] = f2; sfwd[3 * 256 + m] = f3;
          }
          const float s0 = srw[0 * 256 + m], s1 = srw[1 * 256 + m],
                      s2 = srw[2 * 256 + m], s3 = srw[3 * 256 + m];
          bp0.x = fmaf(lv.x, s0, bp0.x); bp0.y = fmaf(lv.y, s0, bp0.y);
          bp0.z = fmaf(lv.z, s0, bp0.z); bp0.w = fmaf(lv.w, s0, bp0.w);
          bp1.x = fmaf(lv.x, s1, bp1.x); bp1.y = fmaf(lv.y, s1, bp1.y);
          bp1.z = fmaf(lv.z, s1, bp1.z); bp1.w = fmaf(lv.w, s1, bp1.w);
          bp2.x = fmaf(lv.x, s2, bp2.x); bp2.y = fmaf(lv.y, s2, bp2.y);
          bp2.z = fmaf(lv.z, s2, bp2.z); bp2.w = fmaf(lv.w, s2, bp2.w);
          bp3.x = fmaf(lv.x, s3, bp3.x); bp3.y = fmaf(lv.y, s3, bp3.y);
          bp3.z = fmaf(lv.z, s3, bp3.z); bp3.w = fmaf(lv.w, s3, bp3.w);
        }
        atomicAdd(&sbwd[0 * 264 + n0 + 0], bp0.x); atomicAdd(&sbwd[0 * 264 + n0 + 1], bp0.y);
        atomicAdd(&sbwd[0 * 264 + n0 + 2], bp0.z); atomicAdd(&sbwd[0 * 264 + n0 + 3], bp0.w);
        atomicAdd(&sbwd[1 * 264 + n0 + 0], bp1.x); atomicAdd(&sbwd[1 * 264 + n0 + 1], bp1.y);
        atomicAdd(&sbwd[1 * 264 + n0 + 2], bp1.z); atomicAdd(&sbwd[1 * 264 + n0 + 3], bp1.w);
        atomicAdd(&sbwd[2 * 264 + n0 + 0], bp2.x); atomicAdd(&sbwd[2 * 264 + n0 + 1], bp2.y);
        atomicAdd(&sbwd[2 * 264 + n0 + 2], bp2.z); atomicAdd(&sbwd[2 * 264 + n0 + 3], bp2.w);
        atomicAdd(&sbwd[3 * 264 + n0 + 0], bp3.x); atomicAdd(&sbwd[3 * 264 + n0 + 1], bp3.y);
        atomicAdd(&sbwd[3 * 264 + n0 + 2], bp3.z); atomicAdd(&sbwd[3 * 264 + n0 + 3], bp3.w);
      }
      __syncthreads();

      // ---- P7 ----
      if (tid < 256) {
#pragma unroll
        for (int r = 0; r < 4; ++r) {
          float rwn = sscal[20 + r * 3 + 0] * sbwd[r * 264 + tid] +
                      sscal[20 + r * 3 + 1] * sfwd[r * 256 + tid] +
                      sscal[20 + r * 3 + 2] * ssim[r * 256 + tid];
          srw[r * 256 + tid] = rwn;
        }
        sprec[tid] = (1.f - sscal[14]) * sprec[tid] + sww[tid];
      }
      __syncthreads();

      // ---- P8 ----
      {
        const int r = tid >> 8, sg = (tid >> 6) & 3, w = lane;
        float acc = 0.f;
#pragma unroll 4
        for (int m2 = sg * 64; m2 < sg * 64 + 64; ++m2)
          acc = fmaf(srw[r * 256 + m2], smemT[w * SMT + m2], acc);
        SCR(sg, r * 64 + w) = acc;
      }
      __syncthreads();
      if (tid < 256)
        rv_all[((size_t)t * BZ + b) * 256 + tid] =
            SCR(0, tid) + SCR(1, tid) + SCR(2, tid) + SCR(3, tid);
      __syncthreads();
    }
  }
}

// ---------------------------------------------------------------- memchain PROBE
// Diagnostic ablation variants on dead scratch. V=0 full, V=1 skip P5,
// V=2 P5 without butterfly/sfwd, V=3 skip allocation rank/scan.
template <int V>
__global__ __launch_bounds__(1024, 1) void k_probe(const float* __restrict__ xi_all,
                                                   float* __restrict__ linkg,
                                                   float* __restrict__ rvscr) {
  const int b = blockIdx.x;
  const int tid = threadIdx.x;
  const int lane = tid & 63;
  const int wv = tid >> 6;
  const int m8 = tid & 255;
  const int seg = tid >> 8;
  float* LNK = linkg + (size_t)b * (NCELL * NCELL);
  __shared__ __align__(16) float SMEM[37264];
  float* smemT = SMEM;
  float* sxi   = smemT + 16448;
  float* srkn  = sxi + 472;
  float* swkn  = srkn + 256;
  float* sev   = swkn + 64;
  float* swvv  = sev + 64;
  float* sscal = swvv + 64;
  float* srw   = sscal + 40;
  float* sww   = srw + 1024;
  float* susage = sww + 256;
  float* sprec = susage + 256;
  float* ssim  = sprec + 256;
  float* sfwd  = ssim + 1024;
  float* sbwd  = sfwd + 1024;
  float* sa    = sbwd + 1056;
  float* sc_   = sa + 256;
  float* sb_   = sc_ + 256;
  int*   srank = (int*)(sb_ + 256);
  float* scr   = (float*)(srank + 256);
  float* sred2 = scr + 5280;

  for (int i = tid; i < CSZ * SMT; i += 1024) smemT[i] = 0.f;
  if (tid < 256) {
    sww[tid] = 0.f; susage[tid] = 0.f; sprec[tid] = 0.f;
    srw[tid] = 0.f; srw[256 + tid] = 0.f; srw[512 + tid] = 0.f; srw[768 + tid] = 0.f;
    sfwd[tid] = 0.f; sfwd[256 + tid] = 0.f; sfwd[512 + tid] = 0.f; sfwd[768 + tid] = 0.f;
    sc_[tid] = 0.f; srank[tid] = tid;
  }
  for (int i = tid; i < (NCELL * NCELL) / 4; i += 1024)
    ((float4*)LNK)[i] = make_float4(0.f, 0.f, 0.f, 0.f);
  __syncthreads();

  for (int t = 0; t < PSTEPS; ++t) {
    // P0
    if (tid < IFC) sxi[tid] = xi_all[((size_t)t * BZ + b) * 512 + tid];
    __syncthreads();
    if (wv < 4) {
      float v = tanhf(sxi[wv * 64 + lane]);
      float s2 = v * v;
#pragma unroll
      for (int off = 32; off; off >>= 1) s2 += __shfl_xor(s2, off);
      srkn[wv * 64 + lane] = v / (sqrtf(s2) + DEL);
    } else if (wv == 4) {
      float v = tanhf(sxi[260 + lane]);
      float s2 = v * v;
#pragma unroll
      for (int off = 32; off; off >>= 1) s2 += __shfl_xor(s2, off);
      swkn[lane] = v / (sqrtf(s2) + DEL);
    } else if (wv == 5) {
      sev[lane] = sig_(sxi[325 + lane]);
    } else if (wv == 6) {
      swvv[lane] = tanhf(sxi[389 + lane]);
    } else if (wv == 7) {
      if (lane < 4) sscal[lane] = splus_(sxi[256 + lane]);
      if (lane == 4) sscal[4] = splus_(sxi[324]);
      if (lane >= 8 && lane < 12) sscal[lane] = sig_(sxi[453 + (lane - 8)]);
      if (lane == 12) sscal[12] = sig_(sxi[457]);
      if (lane == 13) sscal[13] = sig_(sxi[458]);
      if (lane >= 16 && lane < 20) {
        int r = lane - 16;
        float a = sxi[459 + r * 3], b2 = sxi[460 + r * 3], c2 = sxi[461 + r * 3];
        float mx3 = fmaxf(a, fmaxf(b2, c2));
        float ea = expf(a - mx3), eb = expf(b2 - mx3), ec = expf(c2 - mx3);
        float iv = 1.f / (ea + eb + ec);
        sscal[20 + r * 3 + 0] = ea * iv;
        sscal[20 + r * 3 + 1] = eb * iv;
        sscal[20 + r * 3 + 2] = ec * iv;
      }
    }
    __syncthreads();

    // P1
    float un_r = 0.f;
    if (tid < 256) {
      float wwo = sww[tid], uo = susage[tid];
      float u1 = uo + (1.f - uo) * wwo;
      float psi = 1.f;
#pragma unroll
      for (int r = 0; r < 4; ++r) psi *= 1.f - sscal[8 + r] * srw[r * 256 + tid];
      un_r = u1 * psi;
      susage[tid] = un_r;
    }
    {
      float dot = 0.f, nn = 0.f;
#pragma unroll 4
      for (int w = seg * 16; w < seg * 16 + 16; ++w) {
        float mv = smemT[w * SMT + m8];
        dot = fmaf(mv, swkn[w], dot);
        nn = fmaf(mv, mv, nn);
      }
      SCR(seg, 0 * 264 + m8) = dot;
      SCR(seg, 1 * 264 + m8) = nn;
    }
    __syncthreads();
    float e_r = 0.f, simv = 0.f;
    if (tid < 256) {
      float dot = SCR(0, tid) + SCR(1, tid) + SCR(2, tid) + SCR(3, tid);
      float nn = SCR(0, 264 + tid) + SCR(1, 264 + tid) + SCR(2, 264 + tid) + SCR(3, 264 + tid);
      simv = sscal[4] * dot / (sqrtf(nn) + DEL);
      float mx = simv;
#pragma unroll
      for (int off = 32; off; off >>= 1) mx = fmaxf(mx, __shfl_xor(mx, off));
      if (lane == 0) sred2[wv] = mx;
    }
    __syncthreads();
    if (tid < 256) {
      float mx = fmaxf(fmaxf(sred2[0], sred2[1]), fmaxf(sred2[2], sred2[3]));
      e_r = expf(simv - mx);
      float s = e_r;
#pragma unroll
      for (int off = 32; off; off >>= 1) s += __shfl_xor(s, off);
      if (lane == 0) sred2[8 + wv] = s;
    }
    __syncthreads();
    float wcw_r = 0.f;
    if (tid < 256) {
      float sm = sred2[8] + sred2[9] + sred2[10] + sred2[11];
      wcw_r = e_r / sm;
      sa[tid] = DEL + (1.f - DEL) * un_r;
    }
    __syncthreads();

    // P2 (ablated in V3)
    if constexpr (V != 3) {
      {
        float um = sa[m8];
        int cnt = 0;
        for (int j2 = seg * 64; j2 < seg * 64 + 64; ++j2) {
          float uj = sa[j2];
          cnt += (uj < um || (uj == um && j2 < m8)) ? 1 : 0;
        }
        ((int*)&SCR(seg, 0))[m8] = cnt;
      }
      __syncthreads();
      if (tid < 256) {
        int rank = ((int*)&SCR(0, 0))[tid] + ((int*)&SCR(1, 0))[tid] +
                   ((int*)&SCR(2, 0))[tid] + ((int*)&SCR(3, 0))[tid];
        srank[tid] = rank;
        sb_[rank] = sa[tid];
      }
      __syncthreads();
      float inc = 0.f;
      if (tid < 256) {
        inc = sb_[tid];
#pragma unroll
        for (int off = 1; off < 64; off <<= 1) {
          float pp = __shfl_up(inc, off);
          if (lane >= off) inc *= pp;
        }
        if (lane == 63) sred2[16 + wv] = inc;
      }
      __syncthreads();
      if (tid < 256) {
        float pref = 1.f;
        for (int w2 = 0; w2 < wv; ++w2) pref *= sred2[16 + w2];
        float excl = __shfl_up(inc, 1);
        if (lane == 0) excl = 1.f;
        sc_[tid] = excl * pref;
      }
      __syncthreads();
    }

    // P3
    if (tid < 256) {
      float alo = (1.f - sa[tid]) * sc_[srank[tid] & 255];
      float wwn = sscal[13] * (sscal[12] * alo + (1.f - sscal[12]) * wcw_r);
      sww[tid] = wwn;
      float s = wwn;
#pragma unroll
      for (int off = 32; off; off >>= 1) s += __shfl_xor(s, off);
      if (lane == 0) sred2[24 + wv] = s;
    }
    __syncthreads();
    if (tid == 0) sscal[14] = sred2[24] + sred2[25] + sred2[26] + sred2[27];

    // P4
    {
      float wm = sww[m8];
      float nn = 0.f, d0 = 0.f, d1 = 0.f, d2 = 0.f, d3 = 0.f;
#pragma unroll 4
      for (int w = seg * 16; w < seg * 16 + 16; ++w) {
        float v = smemT[w * SMT + m8];
        v = v * (1.f - wm * sev[w]) + wm * swvv[w];
        smemT[w * SMT + m8] = v;
        nn = fmaf(v, v, nn);
        d0 = fmaf(v, srkn[0 * 64 + w], d0);
        d1 = fmaf(v, srkn[1 * 64 + w], d1);
        d2 = fmaf(v, srkn[2 * 64 + w], d2);
        d3 = fmaf(v, srkn[3 * 64 + w], d3);
      }
      SCR(seg, 0 * 264 + m8) = nn;
      SCR(seg, 1 * 264 + m8) = d0;
      SCR(seg, 2 * 264 + m8) = d1;
      SCR(seg, 3 * 264 + m8) = d2;
      SCR(seg, 4 * 264 + m8) = d3;
    }
    for (int i = tid; i < NRD * 264; i += 1024) sbwd[i] = 0.f;
    __syncthreads();
    float sv0 = 0.f, sv1 = 0.f, sv2 = 0.f, sv3 = 0.f;
    float e0 = 0.f, e1 = 0.f, e2 = 0.f, e3 = 0.f;
    if (tid < 256) {
      float nn = SCR(0, tid) + SCR(1, tid) + SCR(2, tid) + SCR(3, tid);
      float invn = 1.f / (sqrtf(nn) + DEL);
      sv0 = sscal[0] * (SCR(0, 264 + tid) + SCR(1, 264 + tid) + SCR(2, 264 + tid) + SCR(3, 264 + tid)) * invn;
      sv1 = sscal[1] * (SCR(0, 528 + tid) + SCR(1, 528 + tid) + SCR(2, 528 + tid) + SCR(3, 528 + tid)) * invn;
      sv2 = sscal[2] * (SCR(0, 792 + tid) + SCR(1, 792 + tid) + SCR(2, 792 + tid) + SCR(3, 792 + tid)) * invn;
      sv3 = sscal[3] * (SCR(0, 1056 + tid) + SCR(1, 1056 + tid) + SCR(2, 1056 + tid) + SCR(3, 1056 + tid)) * invn;
      float m0 = sv0, m1 = sv1, m2 = sv2, m3 = sv3;
#pragma unroll
      for (int off = 32; off; off >>= 1) {
        m0 = fmaxf(m0, __shfl_xor(m0, off));
        m1 = fmaxf(m1, __shfl_xor(m1, off));
        m2 = fmaxf(m2, __shfl_xor(m2, off));
        m3 = fmaxf(m3, __shfl_xor(m3, off));
      }
      if (lane == 0) {
        sred2[wv * 4 + 0] = m0; sred2[wv * 4 + 1] = m1;
        sred2[wv * 4 + 2] = m2; sred2[wv * 4 + 3] = m3;
      }
    }
    __syncthreads();
    if (tid < 256) {
      float m0 = fmaxf(fmaxf(sred2[0], sred2[4]), fmaxf(sred2[8], sred2[12]));
      float m1 = fmaxf(fmaxf(sred2[1], sred2[5]), fmaxf(sred2[9], sred2[13]));
      float m2 = fmaxf(fmaxf(sred2[2], sred2[6]), fmaxf(sred2[10], sred2[14]));
      float m3 = fmaxf(fmaxf(sred2[3], sred2[7]), fmaxf(sred2[11], sred2[15]));
      e0 = expf(sv0 - m0); e1 = expf(sv1 - m1); e2 = expf(sv2 - m2); e3 = expf(sv3 - m3);
      float s0 = e0, s1 = e1, s2 = e2, s3 = e3;
#pragma unroll
      for (int off = 32; off; off >>= 1) {
        s0 += __shfl_xor(s0, off); s1 += __shfl_xor(s1, off);
        s2 += __shfl_xor(s2, off); s3 += __shfl_xor(s3, off);
      }
      if (lane == 0) {
        sred2[32 + wv * 4 + 0] = s0; sred2[32 + wv * 4 + 1] = s1;
        sred2[32 + wv * 4 + 2] = s2; sred2[32 + wv * 4 + 3] = s3;
      }
    }
    __syncthreads();
    if (tid < 256) {
      float s0 = sred2[32] + sred2[36] + sred2[40] + sred2[44];
      float s1 = sred2[33] + sred2[37] + sred2[41] + sred2[45];
      float s2 = sred2[34] + sred2[38] + sred2[42] + sred2[46];
      float s3 = sred2[35] + sred2[39] + sred2[43] + sred2[47];
      ssim[0 * 256 + tid] = e0 / s0; ssim[1 * 256 + tid] = e1 / s1;
      ssim[2 * 256 + tid] = e2 / s2; ssim[3 * 256 + tid] = e3 / s3;
    }

    // P5 (ablated in V1; butterfly ablated in V2)
    if constexpr (V != 1) {
      const float4 r0 = ((const float4*)(srw + 0 * 256))[lane];
      const float4 r1 = ((const float4*)(srw + 1 * 256))[lane];
      const float4 r2 = ((const float4*)(srw + 2 * 256))[lane];
      const float4 r3 = ((const float4*)(srw + 3 * 256))[lane];
      const float4 wc = ((const float4*)sww)[lane];
      const float4 pc = ((const float4*)sprec)[lane];
      const int n0 = lane * 4;
      float4 bp0 = {0,0,0,0}, bp1 = {0,0,0,0}, bp2 = {0,0,0,0}, bp3 = {0,0,0,0};
      for (int rr = 0; rr < 16; ++rr) {
        const int m = wv * 16 + rr;
        const float wm = sww[m];
        float4 lv = ((float4*)(LNK + (size_t)m * 256))[lane];
        lv.x = (1.f - wm - wc.x) * lv.x + wm * pc.x;
        lv.y = (1.f - wm - wc.y) * lv.y + wm * pc.y;
        lv.z = (1.f - wm - wc.z) * lv.z + wm * pc.z;
        lv.w = (1.f - wm - wc.w) * lv.w + wm * pc.w;
        if (m == n0 + 0) lv.x = 0.f;
        if (m == n0 + 1) lv.y = 0.f;
        if (m == n0 + 2) lv.z = 0.f;
        if (m == n0 + 3) lv.w = 0.f;
        ((float4*)(LNK + (size_t)m * 256))[lane] = lv;
        float f0 = lv.x * r0.x + lv.y * r0.y + lv.z * r0.z + lv.w * r0.w;
        float f1 = lv.x * r1.x + lv.y * r1.y + lv.z * r1.z + lv.w * r1.w;
        float f2 = lv.x * r2.x + lv.y * r2.y + lv.z * r2.z + lv.w * r2.w;
        float f3 = lv.x * r3.x + lv.y * r3.y + lv.z * r3.z + lv.w * r3.w;
        if constexpr (V != 2) {
#pragma unroll
          for (int off = 32; off; off >>= 1) {
            f0 += __shfl_xor(f0, off); f1 += __shfl_xor(f1, off);
            f2 += __shfl_xor(f2, off); f3 += __shfl_xor(f3, off);
          }
          if (lane == 0) {
            sfwd[0 * 256 + m] = f0; sfwd[1 * 256 + m] = f1;
            sfwd[2 * 256 + m] = f2; sfwd[3 * 256 + m] = f3;
          }
        } else {
          // keep f0..f3 alive without the reduction
          asm volatile("" :: "v"(f0), "v"(f1), "v"(f2), "v"(f3));
        }
        const float s0 = srw[0 * 256 + m], s1 = srw[1 * 256 + m],
                    s2 = srw[2 * 256 + m], s3 = srw[3 * 256 + m];
        bp0.x = fmaf(lv.x, s0, bp0.x); bp0.y = fmaf(lv.y, s0, bp0.y);
        bp0.z = fmaf(lv.z, s0, bp0.z); bp0.w = fmaf(lv.w, s0, bp0.w);
        bp1.x = fmaf(lv.x, s1, bp1.x); bp1.y = fmaf(lv.y, s1, bp1.y);
        bp1.z = fmaf(lv.z, s1, bp1.z); bp1.w = fmaf(lv.w, s1, bp1.w);
        bp2.x = fmaf(lv.x, s2, bp2.x); bp2.y = fmaf(lv.y, s2, bp2.y);
        bp2.z = fmaf(lv.z, s2, bp2.z); bp2.w = fmaf(lv.w, s2, bp2.w);
        bp3.x = fmaf(lv.x, s3, bp3.x); bp3.y = fmaf(lv.y, s3, bp3.y);
        bp3.z = fmaf(lv.z, s3, bp3.z); bp3.w = fmaf(lv.w, s3, bp3.w);
      }
      atomicAdd(&sbwd[0 * 264 + n0 + 0], bp0.x); atomicAdd(&sbwd[0 * 264 + n0 + 1], bp0.y);
      atomicAdd(&sbwd[0 * 264 + n0 + 2], bp0.z); atomicAdd(&sbwd[0 * 264 + n0 + 3], bp0.w);
      atomicAdd(&sbwd[1 * 264 + n0 + 0], bp1.x); atomicAdd(&sbwd[1 * 264 + n0 + 1], bp1.y);
      atomicAdd(&sbwd[1 * 264 + n0 + 2], bp1.z); atomicAdd(&sbwd[1 * 264 + n0 + 3], bp1.w);
      atomicAdd(&sbwd[2 * 264 + n0 + 0], bp2.x); atomicAdd(&sbwd[2 * 264 + n0 + 1], bp2.y);
      atomicAdd(&sbwd[2 * 264 + n0 + 2], bp2.z); atomicAdd(&sbwd[2 * 264 + n0 + 3], bp2.w);
      atomicAdd(&sbwd[3 * 264 + n0 + 0], bp3.x); atomicAdd(&sbwd[3 * 264 + n0 + 1], bp3.y);
      atomicAdd(&sbwd[3 * 264 + n0 + 2], bp3.z); atomicAdd(&sbwd[3 * 264 + n0 + 3], bp3.w);
    }
    __syncthreads();

    // P7
    if (tid < 256) {
#pragma unroll
      for (int r = 0; r < 4; ++r) {
        float rwn = sscal[20 + r * 3 + 0] * sbwd[r * 264 + tid] +
                    sscal[20 + r * 3 + 1] * sfwd[r * 256 + tid] +
                    sscal[20 + r * 3 + 2] * ssim[r * 256 + tid];
        srw[r * 256 + tid] = rwn;
      }
      sprec[tid] = (1.f - sscal[14]) * sprec[tid] + sww[tid];
    }
    __syncthreads();

    // P8
    {
      const int r = tid >> 8, sg = (tid >> 6) & 3, w = lane;
      float acc = 0.f;
#pragma unroll 4
      for (int m2 = sg * 64; m2 < sg * 64 + 64; ++m2)
        acc = fmaf(srw[r * 256 + m2], smemT[w * SMT + m2], acc);
      SCR(sg, r * 64 + w) = acc;
    }
    __syncthreads();
    if (tid < 256)
      rvscr[((size_t)t * BZ + b) * 256 + tid] =
          SCR(0, tid) + SCR(1, tid) + SCR(2, tid) + SCR(3, tid);
    __syncthreads();
  }
}

// ---------------------------------------------------------------- out GEMM
__global__ __launch_bounds__(256) void k_out(const float* __restrict__ h1_all,
                                             const float* __restrict__ WoutT,
                                             const float* __restrict__ bout,
                                             float* __restrict__ out_all) {
  const int lane = threadIdx.x, ty = threadIdx.y;
  const int u = blockIdx.x * 64 + lane;
  const int row0 = blockIdx.y * 16;
  __shared__ float sh[16][512];
  const int tid = ty * 64 + lane;
  for (int idx = tid; idx < 16 * 512; idx += 256) {
    int r2 = idx >> 9, k = idx & 511;
    sh[r2][k] = h1_all[(size_t)(row0 + r2) * 512 + k];
  }
  __syncthreads();
  const float* wcol = WoutT + u;
  float bias = bout[u];
  float acc[4] = {0.f, 0.f, 0.f, 0.f};
  for (int k = 0; k < 512; ++k) {
    float wv = wcol[(size_t)k * 512];
#pragma unroll
    for (int i = 0; i < 4; ++i) acc[i] = fmaf(wv, sh[ty * 4 + i][k], acc[i]);
  }
#pragma unroll
  for (int i = 0; i < 4; ++i)
    out_all[(size_t)(row0 + ty * 4 + i) * 512 + u] = acc[i] + bias;
}

// ---------------------------------------------------------------- final y GEMM
__global__ __launch_bounds__(256) void k_y(const float* __restrict__ out_all,
                                           const float* __restrict__ rv_all,
                                           const float* __restrict__ WmemT,
                                           const float* __restrict__ bmem,
                                           float* __restrict__ y) {
  const int lane = threadIdx.x, ty = threadIdx.y;
  const int o = blockIdx.x * 64 + lane;
  const int tb0 = blockIdx.y * 16;
  __shared__ float sin_[16][768];
  const int tid = ty * 64 + lane;
  for (int idx = tid; idx < 16 * 768; idx += 256) {
    int row = idx / 768, k = idx % 768;
    int tb = tb0 + row;
    sin_[row][k] = (k < 512) ? out_all[(size_t)tb * HID + k]
                             : rv_all[(size_t)tb * 256 + (k - 512)];
  }
  __syncthreads();
  float acc[4] = {0.f, 0.f, 0.f, 0.f};
  for (int k = 0; k < 768; ++k) {
    float wv = WmemT[(size_t)k * 256 + o];
#pragma unroll
    for (int i = 0; i < 4; ++i) acc[i] = fmaf(wv, sin_[ty * 4 + i][k], acc[i]);
  }
  float bo = bmem[o];
#pragma unroll
  for (int i = 0; i < 4; ++i) {
    int tb = tb0 + ty * 4 + i;
    int tt = tb >> 4, bb = tb & 15;
    y[((size_t)bb * TZ + tt) * 256 + o] = acc[i] + bo;
  }
}

extern "C" void kernel_launch(void* const* d_in, const int* in_sizes, int n_in,
                              void* d_out, int out_size, void* d_ws, size_t ws_size,
                              hipStream_t stream) {
  (void)in_sizes; (void)n_in; (void)out_size; (void)ws_size;
  const float* x    = (const float*)d_in[0];
  const float* Wih0 = (const float*)d_in[1];
  const float* bih0 = (const float*)d_in[2];
  const float* Whh0 = (const float*)d_in[3];
  const float* bhh0 = (const float*)d_in[4];
  const float* Wih1 = (const float*)d_in[5];
  const float* bih1 = (const float*)d_in[6];
  const float* Whh1 = (const float*)d_in[7];
  const float* bhh1 = (const float*)d_in[8];
  const float* Wout = (const float*)d_in[9];
  const float* bout = (const float*)d_in[10];
  const float* Wif  = (const float*)d_in[11];
  const float* bif  = (const float*)d_in[12];
  const float* Wmem = (const float*)d_in[13];
  const float* bmem = (const float*)d_in[14];
  float* y = (float*)d_out;

  float* p = (float*)d_ws;
  auto take = [&](size_t n) { float* q = p; p += n; return q; };
  float* Wih0T   = take((size_t)256 * 2048);
  float* WoutT   = take((size_t)512 * 512);
  float* WifT    = take((size_t)512 * 512);
  float* WmemT   = take((size_t)768 * 256);
  float* xpart   = take((size_t)TZ * BZ * G4H);
  float* h1_all  = take((size_t)TZ * BZ * HID);
  float* out_all = take((size_t)TZ * BZ * HID);
  float* xi_all  = take((size_t)TZ * BZ * 512);
  float* rv_all  = take((size_t)TZ * BZ * 256);
  float* linkg   = take((size_t)BZ * NCELL * NCELL);
  float* zstart  = p;
  float* h0g     = take((size_t)2 * BZ * HID);
  float* h1g     = take((size_t)2 * BZ * HID);
  float* cntf    = take((size_t)512);
  size_t zbytes = (size_t)((char*)p - (char*)zstart);
  unsigned* done   = (unsigned*)cntf;        // [0..191]
  unsigned* go     = done + 256;             // [1]
  unsigned* xiflag = done + 320;             // [16]

  (void)hipMemsetAsync(zstart, 0, zbytes, stream);

  dim3 tb32(32, 8);
  hipLaunchKernelGGL(k_transpose, dim3(8, 64), tb32, 0, stream, Wih0, Wih0T, 2048, 512, 256, 2048);
  hipLaunchKernelGGL(k_transpose, dim3(16, 16), tb32, 0, stream, Wout, WoutT, 512, 512, 512, 512);
  hipLaunchKernelGGL(k_transpose, dim3(16, 15), tb32, 0, stream, Wif, WifT, 471, 512, 512, 512);
  hipLaunchKernelGGL(k_transpose, dim3(24, 8), tb32, 0, stream, Wmem, WmemT, 256, 768, 768, 256);

  hipLaunchKernelGGL(k_xpart, dim3(32, 64), dim3(64, 4), 0, stream, x, Wih0T, bih0, bhh0, xpart);

  hipLaunchKernelGGL(k_fused, dim3(NTOT), dim3(1024), 0, stream,
                     xpart, Whh0, Wih1, Whh1, bih1, bhh1, WifT, bif,
                     h0g, h1g, h1_all, xi_all, linkg, rv_all, done, go, xiflag);

  hipLaunchKernelGGL(k_out, dim3(8, 64), dim3(64, 4), 0, stream, h1_all, WoutT, bout, out_all);

  hipLaunchKernelGGL(k_y, dim3(4, 64), dim3(64, 4), 0, stream, out_all, rv_all, WmemT, bmem, y);

  // ---- diagnostic probes on dead scratch (linkg + xpart), after d_out done ----
  hipLaunchKernelGGL((k_probe<0>), dim3(16), dim3(1024), 0, stream, xi_all, linkg, xpart);
  hipLaunchKernelGGL((k_probe<1>), dim3(16), dim3(1024), 0, stream, xi_all, linkg, xpart);
  hipLaunchKernelGGL((k_probe<2>), dim3(16), dim3(1024), 0, stream, xi_all, linkg, xpart);
  hipLaunchKernelGGL((k_probe<3>), dim3(16), dim3(1024), 0, stream, xi_all, linkg, xpart);
}

// Round 10
// 4632.497 us; speedup vs baseline: 1.4266x; 1.4266x over previous
//
#include <hip/hip_runtime.h>
#include <math.h>

// DNC forward, fp32. Round 10: round-8 pipeline with the memory-module chain
// vectorized for LDS-issue (b128 everywhere: rank, P8, P4/P1 params, P5 row
// params). SMT=260 (16B-aligned mem^T rows). Probes removed.

#define BZ    16
#define TZ    64
#define HID   512
#define NCELL 256
#define CSZ   64
#define NRD   4
#define G4H   2048
#define IFC   471
#define DEL   1e-6f
#define SMT   260   // LDS mem^T row stride (multiple of 4 -> b128-aligned rows)
#define NLSTM 192
#define NTOT  224

__device__ __forceinline__ float sig_(float x) { return 1.f / (1.f + expf(-x)); }
__device__ __forceinline__ float splus_(float x) { return fmaxf(x, 0.f) + log1pf(expf(-fabsf(x))); }

template <int SLP>
__device__ __forceinline__ unsigned poll_acq(unsigned* ptr, unsigned tgt) {
  unsigned v;
  while ((v = __hip_atomic_load(ptr, __ATOMIC_RELAXED, __HIP_MEMORY_SCOPE_AGENT)) < tgt)
    __builtin_amdgcn_s_sleep(SLP);
  v = __hip_atomic_load(ptr, __ATOMIC_ACQUIRE, __HIP_MEMORY_SCOPE_AGENT);
  return v;
}

// ---------------------------------------------------------------- transpose
__global__ __launch_bounds__(256) void k_transpose(const float* __restrict__ src,
                                                   float* __restrict__ dst,
                                                   int rows, int cols, int kmax, int dst_stride) {
  __shared__ float tile[32][33];
  int c0 = blockIdx.x * 32, r0 = blockIdx.y * 32;
  int tx = threadIdx.x, ty = threadIdx.y;
  for (int i = ty; i < 32; i += 8) {
    int r = r0 + i, c = c0 + tx;
    tile[i][tx] = (r < rows && c < cols) ? src[(size_t)r * cols + c] : 0.f;
  }
  __syncthreads();
  for (int i = ty; i < 32; i += 8) {
    int c = c0 + i, r = r0 + tx;
    if (c < kmax && r < rows) dst[(size_t)c * dst_stride + r] = tile[tx][i];
  }
}

// ---------------------------------------------------------------- xpart GEMM
__global__ __launch_bounds__(256) void k_xpart(const float* __restrict__ x,
                                               const float* __restrict__ Wih0T,
                                               const float* __restrict__ bih0,
                                               const float* __restrict__ bhh0,
                                               float* __restrict__ xpart) {
  const int lane = threadIdx.x, ty = threadIdx.y;
  const int jg = blockIdx.x * 64 + lane;
  const int tb0 = blockIdx.y * 16;
  __shared__ float sx[16][256];
  const int tid = ty * 64 + lane;
  for (int idx = tid; idx < 16 * 256; idx += 256) {
    int row = idx >> 8, k = idx & 255;
    int tb = tb0 + row, tt = tb >> 4, bb = tb & 15;
    sx[row][k] = x[((size_t)bb * TZ + tt) * 256 + k];
  }
  __syncthreads();
  float acc[4] = {0.f, 0.f, 0.f, 0.f};
  for (int k = 0; k < 256; ++k) {
    float wv = Wih0T[(size_t)k * G4H + jg];
#pragma unroll
    for (int i = 0; i < 4; ++i) acc[i] = fmaf(wv, sx[ty * 4 + i][k], acc[i]);
  }
  float bias = bih0[jg] + bhh0[jg];
#pragma unroll
  for (int i = 0; i < 4; ++i)
    xpart[(size_t)(tb0 + ty * 4 + i) * G4H + jg] = acc[i] + bias;
}

// ---------------------------------------------------------------- grid barrier (LSTM blocks only)
__device__ __forceinline__ void gbar(unsigned* done, unsigned* go,
                                     unsigned tgt, int bid, int tid) {
  __syncthreads();
  if (bid == 0) {
    if (tid == 0)
      __hip_atomic_store(&done[0], tgt, __ATOMIC_RELEASE, __HIP_MEMORY_SCOPE_AGENT);
    if (tid < NLSTM) (void)poll_acq<4>(&done[tid], tgt);
    __syncthreads();
    if (tid == 0)
      __hip_atomic_store(go, tgt, __ATOMIC_RELEASE, __HIP_MEMORY_SCOPE_AGENT);
  } else {
    if (tid == 0) {
      __hip_atomic_store(&done[bid], tgt, __ATOMIC_RELEASE, __HIP_MEMORY_SCOPE_AGENT);
      (void)poll_acq<4>(go, tgt);
    }
    __syncthreads();
  }
}

#define SCR(s, i) scr[(s) * 1320 + (i)]

// ---------------------------------------------------------------- fused persistent kernel
// blocks 0..63:    LSTM cell0 (8 j-columns each, weights in LDS)
// blocks 64..191:  LSTM cell1 (4 j-columns each, weights in LDS)
// blocks 192..207: xi producer per batch
// blocks 208..223: memory-module chain per batch (b128-vectorized)
__global__ __launch_bounds__(1024, 1) void k_fused(
    const float* __restrict__ xpart,
    const float* __restrict__ Whh0,
    const float* __restrict__ Wih1, const float* __restrict__ Whh1,
    const float* __restrict__ bih1, const float* __restrict__ bhh1,
    const float* __restrict__ WifT, const float* __restrict__ bif,
    float* __restrict__ h0g, float* __restrict__ h1g,
    float* __restrict__ h1_all, float* __restrict__ xi_all,
    float* __restrict__ linkg, float* __restrict__ rv_all,
    unsigned* __restrict__ done, unsigned* __restrict__ go,
    unsigned* __restrict__ xiflag) {
  const int tid = threadIdx.x;
  const int bid = blockIdx.x;
  __shared__ __align__(16) float SMEM[37264];

  if (bid < 64) {
    // ================= cell0 =================
    float* w0 = SMEM;               // [32][524]
    float* hl = SMEM + 16768;       // [16][520]
    float* sc = hl + 8320;          // [8][512]
    float* xpl = sc + 4096;         // [512]
    float* c0l = xpl + 512;         // [128]
    const int j0 = bid * 8;
    for (int lr = 0; lr < 32; ++lr) {
      int g = lr >> 3, jj2 = lr & 7;
      const float* src = Whh0 + (size_t)(g * 512 + j0 + jj2) * 512;
      for (int k = tid; k < 512; k += 1024) w0[lr * 524 + k] = src[k];
    }
    if (tid < 128) c0l[tid] = 0.f;
    const int ks = tid & 7, bq = (tid >> 3) & 3, jj = tid >> 5;
    const int wr0 = (0 * 8 + (jj & 7)) * 524, wr1 = (1 * 8 + (jj & 7)) * 524,
              wr2 = (2 * 8 + (jj & 7)) * 524, wr3 = (3 * 8 + (jj & 7)) * 524;
    const int hb0 = (bq * 4 + 0) * 520, hb1 = (bq * 4 + 1) * 520,
              hb2 = (bq * 4 + 2) * 520, hb3 = (bq * 4 + 3) * 520;
    for (int ph = 0; ph < 65; ++ph) {
      if (ph < 64) {
        const int t = ph, po = t & 1, pn = po ^ 1;
        for (int q = tid; q < 2048; q += 1024) {
          int bb = q >> 7, kq = q & 127;
          ((float4*)&hl[bb * 520])[kq] = ((const float4*)&h0g[(size_t)(po * 16 + bb) * 512])[kq];
        }
        if (tid < 512) {
          int bb = tid >> 5, g = (tid >> 3) & 3, j2 = tid & 7;
          xpl[tid] = xpart[((size_t)t * 16 + bb) * G4H + g * 512 + j0 + j2];
        }
        __syncthreads();
        if (tid < 256) {
          float4 a0 = {0,0,0,0}, a1 = {0,0,0,0}, a2 = {0,0,0,0}, a3 = {0,0,0,0};
#pragma unroll 4
          for (int i = 0; i < 16; ++i) {
            const int off = ks * 4 + 32 * i;
            float4 w4a = *(const float4*)&w0[wr0 + off];
            float4 w4b = *(const float4*)&w0[wr1 + off];
            float4 w4c = *(const float4*)&w0[wr2 + off];
            float4 w4d = *(const float4*)&w0[wr3 + off];
            float4 h4a = *(const float4*)&hl[hb0 + off];
            float4 h4b = *(const float4*)&hl[hb1 + off];
            float4 h4c = *(const float4*)&hl[hb2 + off];
            float4 h4d = *(const float4*)&hl[hb3 + off];
            a0.x += w4a.x*h4a.x + w4a.y*h4a.y + w4a.z*h4a.z + w4a.w*h4a.w;
            a0.y += w4a.x*h4b.x + w4a.y*h4b.y + w4a.z*h4b.z + w4a.w*h4b.w;
            a0.z += w4a.x*h4c.x + w4a.y*h4c.y + w4a.z*h4c.z + w4a.w*h4c.w;
            a0.w += w4a.x*h4d.x + w4a.y*h4d.y + w4a.z*h4d.z + w4a.w*h4d.w;
            a1.x += w4b.x*h4a.x + w4b.y*h4a.y + w4b.z*h4a.z + w4b.w*h4a.w;
            a1.y += w4b.x*h4b.x + w4b.y*h4b.y + w4b.z*h4b.z + w4b.w*h4b.w;
            a1.z += w4b.x*h4c.x + w4b.y*h4c.y + w4b.z*h4c.z + w4b.w*h4c.w;
            a1.w += w4b.x*h4d.x + w4b.y*h4d.y + w4b.z*h4d.z + w4b.w*h4d.w;
            a2.x += w4c.x*h4a.x + w4c.y*h4a.y + w4c.z*h4a.z + w4c.w*h4a.w;
            a2.y += w4c.x*h4b.x + w4c.y*h4b.y + w4c.z*h4b.z + w4c.w*h4b.w;
            a2.z += w4c.x*h4c.x + w4c.y*h4c.y + w4c.z*h4c.z + w4c.w*h4c.w;
            a2.w += w4c.x*h4d.x + w4c.y*h4d.y + w4c.z*h4d.z + w4c.w*h4d.w;
            a3.x += w4d.x*h4a.x + w4d.y*h4a.y + w4d.z*h4a.z + w4d.w*h4a.w;
            a3.y += w4d.x*h4b.x + w4d.y*h4b.y + w4d.z*h4b.z + w4d.w*h4b.w;
            a3.z += w4d.x*h4c.x + w4d.y*h4c.y + w4d.z*h4c.z + w4d.w*h4c.w;
            a3.w += w4d.x*h4d.x + w4d.y*h4d.y + w4d.z*h4d.z + w4d.w*h4d.w;
          }
          *(float4*)&sc[ks * 512 + (0 * 8 + jj) * 16 + bq * 4] = a0;
          *(float4*)&sc[ks * 512 + (1 * 8 + jj) * 16 + bq * 4] = a1;
          *(float4*)&sc[ks * 512 + (2 * 8 + jj) * 16 + bq * 4] = a2;
          *(float4*)&sc[ks * 512 + (3 * 8 + jj) * 16 + bq * 4] = a3;
        }
        __syncthreads();
        if (tid < 128) {
          const int bb = tid >> 3, j2 = tid & 7;
          float gs[4];
#pragma unroll
          for (int g = 0; g < 4; ++g) {
            float s = 0.f;
#pragma unroll
            for (int k2 = 0; k2 < 8; ++k2) s += sc[k2 * 512 + (g * 8 + j2) * 16 + bb];
            gs[g] = s + xpl[bb * 32 + g * 8 + j2];
          }
          float gi = sig_(gs[0]), gf = sig_(gs[1]), gg = tanhf(gs[2]), go_ = sig_(gs[3]);
          float cc = gf * c0l[j2 * 16 + bb] + gi * gg;
          c0l[j2 * 16 + bb] = cc;
          h0g[(size_t)(pn * 16 + bb) * 512 + j0 + j2] = go_ * tanhf(cc);
        }
      }
      gbar(done, go, (unsigned)(ph + 1), bid, tid);
    }
  } else if (bid < 192) {
    // ================= cell1 =================
    float* w1 = SMEM;               // [16][1028]
    float* h0l = SMEM + 16448;      // [16][520]
    float* h1l = h0l + 8320;        // [16][520]
    float* sc = h1l + 8320;         // [16][256]
    float* c1l = sc + 4096;         // [64]
    float* bl = c1l + 64;           // [16]
    const int b1 = bid - 64;
    const int j0 = b1 * 4;
    for (int lr = 0; lr < 16; ++lr) {
      int g = lr >> 2, jj2 = lr & 3;
      const float* si = Wih1 + (size_t)(g * 512 + j0 + jj2) * 512;
      const float* sh = Whh1 + (size_t)(g * 512 + j0 + jj2) * 512;
      for (int k = tid; k < 512; k += 1024) {
        w1[lr * 1028 + k] = si[k];
        w1[lr * 1028 + 512 + k] = sh[k];
      }
    }
    if (tid < 64) c1l[tid] = 0.f;
    if (tid < 16) {
      int g = tid >> 2, jj2 = tid & 3;
      bl[tid] = bih1[g * 512 + j0 + jj2] + bhh1[g * 512 + j0 + jj2];
    }
    const int ks = tid & 15, bq = (tid >> 4) & 3, jj = (tid >> 6) & 3;
    const int wr0 = (0 * 4 + jj) * 1028, wr1 = (1 * 4 + jj) * 1028,
              wr2 = (2 * 4 + jj) * 1028, wr3 = (3 * 4 + jj) * 1028;
    const int hb0 = (bq * 4 + 0) * 520, hb1 = (bq * 4 + 1) * 520,
              hb2 = (bq * 4 + 2) * 520, hb3 = (bq * 4 + 3) * 520;
    for (int ph = 0; ph < 65; ++ph) {
      if (ph >= 1) {
        const int t = ph - 1, po = t & 1, pn = po ^ 1;
        for (int q = tid; q < 2048; q += 1024) {
          int bb = q >> 7, kq = q & 127;
          ((float4*)&h0l[bb * 520])[kq] = ((const float4*)&h0g[(size_t)(pn * 16 + bb) * 512])[kq];
          ((float4*)&h1l[bb * 520])[kq] = ((const float4*)&h1g[(size_t)(po * 16 + bb) * 512])[kq];
        }
        __syncthreads();
        if (tid < 256) {
          float4 a0 = {0,0,0,0}, a1 = {0,0,0,0}, a2 = {0,0,0,0}, a3 = {0,0,0,0};
#pragma unroll 4
          for (int i = 0; i < 16; ++i) {
            const int offw = ks * 4 + 64 * i;
            const int offh = (i < 8) ? offw : (offw - 512);
            const float* hsrc = (i < 8) ? h0l : h1l;
            float4 w4a = *(const float4*)&w1[wr0 + offw];
            float4 w4b = *(const float4*)&w1[wr1 + offw];
            float4 w4c = *(const float4*)&w1[wr2 + offw];
            float4 w4d = *(const float4*)&w1[wr3 + offw];
            float4 h4a = *(const float4*)&hsrc[hb0 + offh];
            float4 h4b = *(const float4*)&hsrc[hb1 + offh];
            float4 h4c = *(const float4*)&hsrc[hb2 + offh];
            float4 h4d = *(const float4*)&hsrc[hb3 + offh];
            a0.x += w4a.x*h4a.x + w4a.y*h4a.y + w4a.z*h4a.z + w4a.w*h4a.w;
            a0.y += w4a.x*h4b.x + w4a.y*h4b.y + w4a.z*h4b.z + w4a.w*h4b.w;
            a0.z += w4a.x*h4c.x + w4a.y*h4c.y + w4a.z*h4c.z + w4a.w*h4c.w;
            a0.w += w4a.x*h4d.x + w4a.y*h4d.y + w4a.z*h4d.z + w4a.w*h4d.w;
            a1.x += w4b.x*h4a.x + w4b.y*h4a.y + w4b.z*h4a.z + w4b.w*h4a.w;
            a1.y += w4b.x*h4b.x + w4b.y*h4b.y + w4b.z*h4b.z + w4b.w*h4b.w;
            a1.z += w4b.x*h4c.x + w4b.y*h4c.y + w4b.z*h4c.z + w4b.w*h4c.w;
            a1.w += w4b.x*h4d.x + w4b.y*h4d.y + w4b.z*h4d.z + w4b.w*h4d.w;
            a2.x += w4c.x*h4a.x + w4c.y*h4a.y + w4c.z*h4a.z + w4c.w*h4a.w;
            a2.y += w4c.x*h4b.x + w4c.y*h4b.y + w4c.z*h4b.z + w4c.w*h4b.w;
            a2.z += w4c.x*h4c.x + w4c.y*h4c.y + w4c.z*h4c.z + w4c.w*h4c.w;
            a2.w += w4c.x*h4d.x + w4c.y*h4d.y + w4c.z*h4d.z + w4c.w*h4d.w;
            a3.x += w4d.x*h4a.x + w4d.y*h4a.y + w4d.z*h4a.z + w4d.w*h4a.w;
            a3.y += w4d.x*h4b.x + w4d.y*h4b.y + w4d.z*h4b.z + w4d.w*h4b.w;
            a3.z += w4d.x*h4c.x + w4d.y*h4c.y + w4d.z*h4c.z + w4d.w*h4c.w;
            a3.w += w4d.x*h4d.x + w4d.y*h4d.y + w4d.z*h4d.z + w4d.w*h4d.w;
          }
          *(float4*)&sc[ks * 256 + (0 * 4 + jj) * 16 + bq * 4] = a0;
          *(float4*)&sc[ks * 256 + (1 * 4 + jj) * 16 + bq * 4] = a1;
          *(float4*)&sc[ks * 256 + (2 * 4 + jj) * 16 + bq * 4] = a2;
          *(float4*)&sc[ks * 256 + (3 * 4 + jj) * 16 + bq * 4] = a3;
        }
        __syncthreads();
        if (tid < 64) {
          const int bb = tid >> 2, j2 = tid & 3;
          float gs[4];
#pragma unroll
          for (int g = 0; g < 4; ++g) {
            float s = 0.f;
#pragma unroll
            for (int k2 = 0; k2 < 16; ++k2) s += sc[k2 * 256 + (g * 4 + j2) * 16 + bb];
            gs[g] = s + bl[g * 4 + j2];
          }
          float gi = sig_(gs[0]), gf = sig_(gs[1]), gg = tanhf(gs[2]), go_ = sig_(gs[3]);
          float cc = gf * c1l[j2 * 16 + bb] + gi * gg;
          c1l[j2 * 16 + bb] = cc;
          float hv = go_ * tanhf(cc);
          h1g[(size_t)(pn * 16 + bb) * 512 + j0 + j2] = hv;
          h1_all[((size_t)t * 16 + bb) * 512 + j0 + j2] = hv;
        }
      }
      gbar(done, go, (unsigned)(ph + 1), bid, tid);
    }
  } else if (bid < 208) {
    // ================= xi producer (one per batch) =================
    const int b = bid - 192;
    float* sh1 = SMEM;        // [512]
    float* sxo = SMEM + 512;  // [2][512]
    __shared__ unsigned sgo;
    unsigned seen_go = 0;
    for (int t = 0; t < TZ; ++t) {
      if (tid == 0 && seen_go < (unsigned)(t + 2)) {
        sgo = poll_acq<8>(go, (unsigned)(t + 2));
      }
      __syncthreads();
      seen_go = (sgo > seen_go) ? sgo : seen_go;
      if (tid < 512) sh1[tid] = h1_all[((size_t)t * BZ + b) * HID + tid];
      __syncthreads();
      {
        const int u = tid & 511, half = tid >> 9;
        if (u < IFC) {
          const float* wc = WifT + u;
          const int k0 = half * 256;
          float acc = 0.f;
#pragma unroll 8
          for (int k = k0; k < k0 + 256; ++k)
            acc = fmaf(sh1[k], wc[(size_t)k * 512], acc);
          sxo[half * 512 + u] = acc;
        }
      }
      __syncthreads();
      if (tid < IFC)
        xi_all[((size_t)t * BZ + b) * 512 + tid] = sxo[tid] + sxo[512 + tid] + bif[tid];
      __syncthreads();
      if (tid == 0)
        __hip_atomic_store(&xiflag[b], (unsigned)(t + 1), __ATOMIC_RELEASE, __HIP_MEMORY_SCOPE_AGENT);
    }
  } else {
    // ================= memory-module chain (one per batch), b128-vectorized =================
    const int b = bid - 208;
    const int lane = tid & 63;
    const int wv = tid >> 6;
    const int m8 = tid & 255;
    const int seg = tid >> 8;
    float* LNK = linkg + (size_t)b * (NCELL * NCELL);

    float* smemT = SMEM;               // 64*260 = 16640
    float* sxi   = smemT + 16640;      // 472
    float* srkn  = sxi + 472;          // 256 [4][64]
    float* swkn  = srkn + 256;         // 64
    float* sev   = swkn + 64;          // 64
    float* swvv  = sev + 64;           // 64
    float* sscal = swvv + 64;          // 40
    float* srw   = sscal + 40;         // 1024 [4][256]
    float* sww   = srw + 1024;         // 256
    float* susage = sww + 256;         // 256
    float* sprec = susage + 256;       // 256
    float* ssim  = sprec + 256;        // 1024 [4][256]
    float* sfwd  = ssim + 1024;        // 1024 [4][256]
    float* sbwd  = sfwd + 1024;        // 1056 [4][264]
    float* sa    = sbwd + 1056;        // 256
    float* sc_   = sa + 256;           // 256
    float* sb_   = sc_ + 256;          // 256
    int*   srank = (int*)(sb_ + 256);  // 256
    float* scr   = (float*)(srank + 256); // 5280 [4][1320]
    float* sred2 = scr + 5280;         // 64
    __shared__ unsigned sflag;

    for (int i = tid; i < CSZ * SMT; i += 1024) smemT[i] = 0.f;
    if (tid < 256) {
      sww[tid] = 0.f; susage[tid] = 0.f; sprec[tid] = 0.f;
      srw[tid] = 0.f; srw[256 + tid] = 0.f; srw[512 + tid] = 0.f; srw[768 + tid] = 0.f;
    }
    for (int i = tid; i < (NCELL * NCELL) / 4; i += 1024)
      ((float4*)LNK)[i] = make_float4(0.f, 0.f, 0.f, 0.f);
    __syncthreads();

    unsigned seen = 0;
    for (int t = 0; t < TZ; ++t) {
      if (tid == 0 && seen < (unsigned)(t + 1)) {
        sflag = poll_acq<8>(&xiflag[b], (unsigned)(t + 1));
      }
      __syncthreads();
      if (seen < (unsigned)(t + 1)) seen = sflag;

      // ---- P0: load + parse xi ----
      if (tid < IFC) sxi[tid] = xi_all[((size_t)t * BZ + b) * 512 + tid];
      __syncthreads();
      if (wv < 4) {
        float v = tanhf(sxi[wv * 64 + lane]);
        float s2 = v * v;
#pragma unroll
        for (int off = 32; off; off >>= 1) s2 += __shfl_xor(s2, off);
        srkn[wv * 64 + lane] = v / (sqrtf(s2) + DEL);
      } else if (wv == 4) {
        float v = tanhf(sxi[260 + lane]);
        float s2 = v * v;
#pragma unroll
        for (int off = 32; off; off >>= 1) s2 += __shfl_xor(s2, off);
        swkn[lane] = v / (sqrtf(s2) + DEL);
      } else if (wv == 5) {
        sev[lane] = sig_(sxi[325 + lane]);
      } else if (wv == 6) {
        swvv[lane] = tanhf(sxi[389 + lane]);
      } else if (wv == 7) {
        if (lane < 4) sscal[lane] = splus_(sxi[256 + lane]);
        if (lane == 4) sscal[4] = splus_(sxi[324]);
        if (lane >= 8 && lane < 12) sscal[lane] = sig_(sxi[453 + (lane - 8)]);
        if (lane == 12) sscal[12] = sig_(sxi[457]);
        if (lane == 13) sscal[13] = sig_(sxi[458]);
        if (lane >= 16 && lane < 20) {
          int r = lane - 16;
          float a = sxi[459 + r * 3], b2 = sxi[460 + r * 3], c2 = sxi[461 + r * 3];
          float mx3 = fmaxf(a, fmaxf(b2, c2));
          float ea = expf(a - mx3), eb = expf(b2 - mx3), ec = expf(c2 - mx3);
          float iv = 1.f / (ea + eb + ec);
          sscal[20 + r * 3 + 0] = ea * iv;
          sscal[20 + r * 3 + 1] = eb * iv;
          sscal[20 + r * 3 + 2] = ec * iv;
        }
      }
      __syncthreads();

      // ---- P1: usage update + write-content dot (old mem), float4 swkn ----
      float un_r = 0.f;
      if (tid < 256) {
        float wwo = sww[tid], uo = susage[tid];
        float u1 = uo + (1.f - uo) * wwo;
        float psi = 1.f;
#pragma unroll
        for (int r = 0; r < 4; ++r) psi *= 1.f - sscal[8 + r] * srw[r * 256 + tid];
        un_r = u1 * psi;
        susage[tid] = un_r;
      }
      {
        float dot = 0.f, nn = 0.f;
#pragma unroll
        for (int wq = 0; wq < 4; ++wq) {
          const int w0 = seg * 16 + wq * 4;
          float4 k4 = *(const float4*)&swkn[w0];
          float va = smemT[(w0 + 0) * SMT + m8];
          float vb = smemT[(w0 + 1) * SMT + m8];
          float vc = smemT[(w0 + 2) * SMT + m8];
          float vd = smemT[(w0 + 3) * SMT + m8];
          dot += va * k4.x + vb * k4.y + vc * k4.z + vd * k4.w;
          nn += va * va + vb * vb + vc * vc + vd * vd;
        }
        SCR(seg, 0 * 264 + m8) = dot;
        SCR(seg, 1 * 264 + m8) = nn;
      }
      __syncthreads();
      float e_r = 0.f, simv = 0.f;
      if (tid < 256) {
        float dot = SCR(0, tid) + SCR(1, tid) + SCR(2, tid) + SCR(3, tid);
        float nn = SCR(0, 264 + tid) + SCR(1, 264 + tid) + SCR(2, 264 + tid) + SCR(3, 264 + tid);
        simv = sscal[4] * dot / (sqrtf(nn) + DEL);
        float mx = simv;
#pragma unroll
        for (int off = 32; off; off >>= 1) mx = fmaxf(mx, __shfl_xor(mx, off));
        if (lane == 0) sred2[wv] = mx;
      }
      __syncthreads();
      if (tid < 256) {
        float mx = fmaxf(fmaxf(sred2[0], sred2[1]), fmaxf(sred2[2], sred2[3]));
        e_r = expf(simv - mx);
        float s = e_r;
#pragma unroll
        for (int off = 32; off; off >>= 1) s += __shfl_xor(s, off);
        if (lane == 0) sred2[8 + wv] = s;
      }
      __syncthreads();
      float wcw_r = 0.f;
      if (tid < 256) {
        float sm = sred2[8] + sred2[9] + sred2[10] + sred2[11];
        wcw_r = e_r / sm;
        sa[tid] = DEL + (1.f - DEL) * un_r;
      }
      __syncthreads();

      // ---- P2: allocation rank (float4) + exclusive cumprod ----
      {
        float um = sa[m8];
        int cnt = 0;
        const float4* saq = (const float4*)&sa[seg * 64];
#pragma unroll
        for (int c4 = 0; c4 < 16; ++c4) {
          float4 uq = saq[c4];
          int j2 = seg * 64 + c4 * 4;
          cnt += (uq.x < um || (uq.x == um && (j2 + 0) < m8)) ? 1 : 0;
          cnt += (uq.y < um || (uq.y == um && (j2 + 1) < m8)) ? 1 : 0;
          cnt += (uq.z < um || (uq.z == um && (j2 + 2) < m8)) ? 1 : 0;
          cnt += (uq.w < um || (uq.w == um && (j2 + 3) < m8)) ? 1 : 0;
        }
        ((int*)&SCR(seg, 0))[m8] = cnt;
      }
      __syncthreads();
      if (tid < 256) {
        int rank = ((int*)&SCR(0, 0))[tid] + ((int*)&SCR(1, 0))[tid] +
                   ((int*)&SCR(2, 0))[tid] + ((int*)&SCR(3, 0))[tid];
        srank[tid] = rank;
        sb_[rank] = sa[tid];
      }
      __syncthreads();
      float inc = 0.f;
      if (tid < 256) {
        inc = sb_[tid];
#pragma unroll
        for (int off = 1; off < 64; off <<= 1) {
          float pp = __shfl_up(inc, off);
          if (lane >= off) inc *= pp;
        }
        if (lane == 63) sred2[16 + wv] = inc;
      }
      __syncthreads();
      if (tid < 256) {
        float pref = 1.f;
        for (int w2 = 0; w2 < wv; ++w2) pref *= sred2[16 + w2];
        float excl = __shfl_up(inc, 1);
        if (lane == 0) excl = 1.f;
        sc_[tid] = excl * pref;
      }
      __syncthreads();

      // ---- P3: write weighting + wsum ----
      if (tid < 256) {
        float alo = (1.f - sa[tid]) * sc_[srank[tid]];
        float wwn = sscal[13] * (sscal[12] * alo + (1.f - sscal[12]) * wcw_r);
        sww[tid] = wwn;
        float s = wwn;
#pragma unroll
        for (int off = 32; off; off >>= 1) s += __shfl_xor(s, off);
        if (lane == 0) sred2[24 + wv] = s;
      }
      __syncthreads();
      if (tid == 0) sscal[14] = sred2[24] + sred2[25] + sred2[26] + sred2[27];

      // ---- P4: memory erase/write + read-content sims (float4 params) ----
      {
        float wm = sww[m8];
        float nn = 0.f, d0 = 0.f, d1 = 0.f, d2 = 0.f, d3 = 0.f;
#pragma unroll
        for (int wq = 0; wq < 4; ++wq) {
          const int w0 = seg * 16 + wq * 4;
          float4 e4 = *(const float4*)&sev[w0];
          float4 v4 = *(const float4*)&swvv[w0];
          float4 k0 = *(const float4*)&srkn[0 * 64 + w0];
          float4 k1 = *(const float4*)&srkn[1 * 64 + w0];
          float4 k2 = *(const float4*)&srkn[2 * 64 + w0];
          float4 k3 = *(const float4*)&srkn[3 * 64 + w0];
          float v;
          v = smemT[(w0 + 0) * SMT + m8];
          v = v * (1.f - wm * e4.x) + wm * v4.x;
          smemT[(w0 + 0) * SMT + m8] = v;
          nn = fmaf(v, v, nn); d0 = fmaf(v, k0.x, d0); d1 = fmaf(v, k1.x, d1);
          d2 = fmaf(v, k2.x, d2); d3 = fmaf(v, k3.x, d3);
          v = smemT[(w0 + 1) * SMT + m8];
          v = v * (1.f - wm * e4.y) + wm * v4.y;
          smemT[(w0 + 1) * SMT + m8] = v;
          nn = fmaf(v, v, nn); d0 = fmaf(v, k0.y, d0); d1 = fmaf(v, k1.y, d1);
          d2 = fmaf(v, k2.y, d2); d3 = fmaf(v, k3.y, d3);
          v = smemT[(w0 + 2) * SMT + m8];
          v = v * (1.f - wm * e4.z) + wm * v4.z;
          smemT[(w0 + 2) * SMT + m8] = v;
          nn = fmaf(v, v, nn); d0 = fmaf(v, k0.z, d0); d1 = fmaf(v, k1.z, d1);
          d2 = fmaf(v, k2.z, d2); d3 = fmaf(v, k3.z, d3);
          v = smemT[(w0 + 3) * SMT + m8];
          v = v * (1.f - wm * e4.w) + wm * v4.w;
          smemT[(w0 + 3) * SMT + m8] = v;
          nn = fmaf(v, v, nn); d0 = fmaf(v, k0.w, d0); d1 = fmaf(v, k1.w, d1);
          d2 = fmaf(v, k2.w, d2); d3 = fmaf(v, k3.w, d3);
        }
        SCR(seg, 0 * 264 + m8) = nn;
        SCR(seg, 1 * 264 + m8) = d0;
        SCR(seg, 2 * 264 + m8) = d1;
        SCR(seg, 3 * 264 + m8) = d2;
        SCR(seg, 4 * 264 + m8) = d3;
      }
      for (int i = tid; i < NRD * 264; i += 1024) sbwd[i] = 0.f;
      __syncthreads();
      float sv0 = 0.f, sv1 = 0.f, sv2 = 0.f, sv3 = 0.f;
      float e0 = 0.f, e1 = 0.f, e2 = 0.f, e3 = 0.f;
      if (tid < 256) {
        float nn = SCR(0, tid) + SCR(1, tid) + SCR(2, tid) + SCR(3, tid);
        float invn = 1.f / (sqrtf(nn) + DEL);
        sv0 = sscal[0] * (SCR(0, 264 + tid) + SCR(1, 264 + tid) + SCR(2, 264 + tid) + SCR(3, 264 + tid)) * invn;
        sv1 = sscal[1] * (SCR(0, 528 + tid) + SCR(1, 528 + tid) + SCR(2, 528 + tid) + SCR(3, 528 + tid)) * invn;
        sv2 = sscal[2] * (SCR(0, 792 + tid) + SCR(1, 792 + tid) + SCR(2, 792 + tid) + SCR(3, 792 + tid)) * invn;
        sv3 = sscal[3] * (SCR(0, 1056 + tid) + SCR(1, 1056 + tid) + SCR(2, 1056 + tid) + SCR(3, 1056 + tid)) * invn;
        float m0 = sv0, m1 = sv1, m2 = sv2, m3 = sv3;
#pragma unroll
        for (int off = 32; off; off >>= 1) {
          m0 = fmaxf(m0, __shfl_xor(m0, off));
          m1 = fmaxf(m1, __shfl_xor(m1, off));
          m2 = fmaxf(m2, __shfl_xor(m2, off));
          m3 = fmaxf(m3, __shfl_xor(m3, off));
        }
        if (lane == 0) {
          sred2[wv * 4 + 0] = m0; sred2[wv * 4 + 1] = m1;
          sred2[wv * 4 + 2] = m2; sred2[wv * 4 + 3] = m3;
        }
      }
      __syncthreads();
      if (tid < 256) {
        float m0 = fmaxf(fmaxf(sred2[0], sred2[4]), fmaxf(sred2[8], sred2[12]));
        float m1 = fmaxf(fmaxf(sred2[1], sred2[5]), fmaxf(sred2[9], sred2[13]));
        float m2 = fmaxf(fmaxf(sred2[2], sred2[6]), fmaxf(sred2[10], sred2[14]));
        float m3 = fmaxf(fmaxf(sred2[3], sred2[7]), fmaxf(sred2[11], sred2[15]));
        e0 = expf(sv0 - m0); e1 = expf(sv1 - m1); e2 = expf(sv2 - m2); e3 = expf(sv3 - m3);
        float s0 = e0, s1 = e1, s2 = e2, s3 = e3;
#pragma unroll
        for (int off = 32; off; off >>= 1) {
          s0 += __shfl_xor(s0, off); s1 += __shfl_xor(s1, off);
          s2 += __shfl_xor(s2, off); s3 += __shfl_xor(s3, off);
        }
        if (lane == 0) {
          sred2[32 + wv * 4 + 0] = s0; sred2[32 + wv * 4 + 1] = s1;
          sred2[32 + wv * 4 + 2] = s2; sred2[32 + wv * 4 + 3] = s3;
        }
      }
      __syncthreads();
      if (tid < 256) {
        float s0 = sred2[32] + sred2[36] + sred2[40] + sred2[44];
        float s1 = sred2[33] + sred2[37] + sred2[41] + sred2[45];
        float s2 = sred2[34] + sred2[38] + sred2[42] + sred2[46];
        float s3 = sred2[35] + sred2[39] + sred2[43] + sred2[47];
        ssim[0 * 256 + tid] = e0 / s0; ssim[1 * 256 + tid] = e1 / s1;
        ssim[2 * 256 + tid] = e2 / s2; ssim[3 * 256 + tid] = e3 / s3;
      }

      // ---- P5: link update + fwd + bwd (float4 row params, full unroll) ----
      {
        const float4 r0 = ((const float4*)(srw + 0 * 256))[lane];
        const float4 r1 = ((const float4*)(srw + 1 * 256))[lane];
        const float4 r2 = ((const float4*)(srw + 2 * 256))[lane];
        const float4 r3 = ((const float4*)(srw + 3 * 256))[lane];
        const float4 wc = ((const float4*)sww)[lane];
        const float4 pc = ((const float4*)sprec)[lane];
        const int n0 = lane * 4;
        const int rbase = wv * 16;
        float4 bp0 = {0,0,0,0}, bp1 = {0,0,0,0}, bp2 = {0,0,0,0}, bp3 = {0,0,0,0};
#pragma unroll
        for (int rq = 0; rq < 4; ++rq) {
          const int mb = rbase + rq * 4;
          float4 wm4 = *(const float4*)&sww[mb];
          float4 s0q = *(const float4*)&srw[0 * 256 + mb];
          float4 s1q = *(const float4*)&srw[1 * 256 + mb];
          float4 s2q = *(const float4*)&srw[2 * 256 + mb];
          float4 s3q = *(const float4*)&srw[3 * 256 + mb];
#pragma unroll
          for (int rj = 0; rj < 4; ++rj) {
            const int m = mb + rj;
            const float wm = (rj == 0) ? wm4.x : (rj == 1) ? wm4.y : (rj == 2) ? wm4.z : wm4.w;
            float4 lv = ((float4*)(LNK + (size_t)m * 256))[lane];
            lv.x = (1.f - wm - wc.x) * lv.x + wm * pc.x;
            lv.y = (1.f - wm - wc.y) * lv.y + wm * pc.y;
            lv.z = (1.f - wm - wc.z) * lv.z + wm * pc.z;
            lv.w = (1.f - wm - wc.w) * lv.w + wm * pc.w;
            if (m == n0 + 0) lv.x = 0.f;
            if (m == n0 + 1) lv.y = 0.f;
            if (m == n0 + 2) lv.z = 0.f;
            if (m == n0 + 3) lv.w = 0.f;
            ((float4*)(LNK + (size_t)m * 256))[lane] = lv;
            float f0 = lv.x * r0.x + lv.y * r0.y + lv.z * r0.z + lv.w * r0.w;
            float f1 = lv.x * r1.x + lv.y * r1.y + lv.z * r1.z + lv.w * r1.w;
            float f2 = lv.x * r2.x + lv.y * r2.y + lv.z * r2.z + lv.w * r2.w;
            float f3 = lv.x * r3.x + lv.y * r3.y + lv.z * r3.z + lv.w * r3.w;
#pragma unroll
            for (int off = 32; off; off >>= 1) {
              f0 += __shfl_xor(f0, off); f1 += __shfl_xor(f1, off);
              f2 += __shfl_xor(f2, off); f3 += __shfl_xor(f3, off);
            }
            if (lane == 0) {
              sfwd[0 * 256 + m] = f0; sfwd[1 * 256 + m] = f1;
              sfwd[2 * 256 + m] = f2; sfwd[3 * 256 + m] = f3;
            }
            const float s0 = (rj == 0) ? s0q.x : (rj == 1) ? s0q.y : (rj == 2) ? s0q.z : s0q.w;
            const float s1 = (rj == 0) ? s1q.x : (rj == 1) ? s1q.y : (rj == 2) ? s1q.z : s1q.w;
            const float s2 = (rj == 0) ? s2q.x : (rj == 1) ? s2q.y : (rj == 2) ? s2q.z : s2q.w;
            const float s3 = (rj == 0) ? s3q.x : (rj == 1) ? s3q.y : (rj == 2) ? s3q.z : s3q.w;
            bp0.x = fmaf(lv.x, s0, bp0.x); bp0.y = fmaf(lv.y, s0, bp0.y);
            bp0.z = fmaf(lv.z, s0, bp0.z); bp0.w = fmaf(lv.w, s0, bp0.w);
            bp1.x = fmaf(lv.x, s1, bp1.x); bp1.y = fmaf(lv.y, s1, bp1.y);
            bp1.z = fmaf(lv.z, s1, bp1.z); bp1.w = fmaf(lv.w, s1, bp1.w);
            bp2.x = fmaf(lv.x, s2, bp2.x); bp2.y = fmaf(lv.y, s2, bp2.y);
            bp2.z = fmaf(lv.z, s2, bp2.z); bp2.w = fmaf(lv.w, s2, bp2.w);
            bp3.x = fmaf(lv.x, s3, bp3.x); bp3.y = fmaf(lv.y, s3, bp3.y);
            bp3.z = fmaf(lv.z, s3, bp3.z); bp3.w = fmaf(lv.w, s3, bp3.w);
          }
        }
        atomicAdd(&sbwd[0 * 264 + n0 + 0], bp0.x); atomicAdd(&sbwd[0 * 264 + n0 + 1], bp0.y);
        atomicAdd(&sbwd[0 * 264 + n0 + 2], bp0.z); atomicAdd(&sbwd[0 * 264 + n0 + 3], bp0.w);
        atomicAdd(&sbwd[1 * 264 + n0 + 0], bp1.x); atomicAdd(&sbwd[1 * 264 + n0 + 1], bp1.y);
        atomicAdd(&sbwd[1 * 264 + n0 + 2], bp1.z); atomicAdd(&sbwd[1 * 264 + n0 + 3], bp1.w);
        atomicAdd(&sbwd[2 * 264 + n0 + 0], bp2.x); atomicAdd(&sbwd[2 * 264 + n0 + 1], bp2.y);
        atomicAdd(&sbwd[2 * 264 + n0 + 2], bp2.z); atomicAdd(&sbwd[2 * 264 + n0 + 3], bp2.w);
        atomicAdd(&sbwd[3 * 264 + n0 + 0], bp3.x); atomicAdd(&sbwd[3 * 264 + n0 + 1], bp3.y);
        atomicAdd(&sbwd[3 * 264 + n0 + 2], bp3.z); atomicAdd(&sbwd[3 * 264 + n0 + 3], bp3.w);
      }
      __syncthreads();

      // ---- P7: rw update + precedence ----
      if (tid < 256) {
#pragma unroll
        for (int r = 0; r < 4; ++r) {
          float rwn = sscal[20 + r * 3 + 0] * sbwd[r * 264 + tid] +
                      sscal[20 + r * 3 + 1] * sfwd[r * 256 + tid] +
                      sscal[20 + r * 3 + 2] * ssim[r * 256 + tid];
          srw[r * 256 + tid] = rwn;
        }
        sprec[tid] = (1.f - sscal[14]) * sprec[tid] + sww[tid];
      }
      __syncthreads();

      // ---- P8: read vectors (b128 both operands) ----
      {
        const int r = tid >> 8, sg = (tid >> 6) & 3, w = lane;
        const float4* mrow = (const float4*)&smemT[w * SMT];
        const float4* rrow = (const float4*)&srw[r * 256];
        float acc = 0.f;
#pragma unroll 4
        for (int mq = sg * 16; mq < sg * 16 + 16; ++mq) {
          float4 rv4 = rrow[mq];
          float4 mv = mrow[mq];
          acc += rv4.x * mv.x + rv4.y * mv.y + rv4.z * mv.z + rv4.w * mv.w;
        }
        SCR(sg, r * 64 + w) = acc;
      }
      __syncthreads();
      if (tid < 256)
        rv_all[((size_t)t * BZ + b) * 256 + tid] =
            SCR(0, tid) + SCR(1, tid) + SCR(2, tid) + SCR(3, tid);
      __syncthreads();
    }
  }
}

// ---------------------------------------------------------------- out GEMM
__global__ __launch_bounds__(256) void k_out(const float* __restrict__ h1_all,
                                             const float* __restrict__ WoutT,
                                             const float* __restrict__ bout,
                                             float* __restrict__ out_all) {
  const int lane = threadIdx.x, ty = threadIdx.y;
  const int u = blockIdx.x * 64 + lane;
  const int row0 = blockIdx.y * 16;
  __shared__ float sh[16][512];
  const int tid = ty * 64 + lane;
  for (int idx = tid; idx < 16 * 512; idx += 256) {
    int r2 = idx >> 9, k = idx & 511;
    sh[r2][k] = h1_all[(size_t)(row0 + r2) * 512 + k];
  }
  __syncthreads();
  const float* wcol = WoutT + u;
  float bias = bout[u];
  float acc[4] = {0.f, 0.f, 0.f, 0.f};
  for (int k = 0; k < 512; ++k) {
    float wv = wcol[(size_t)k * 512];
#pragma unroll
    for (int i = 0; i < 4; ++i) acc[i] = fmaf(wv, sh[ty * 4 + i][k], acc[i]);
  }
#pragma unroll
  for (int i = 0; i < 4; ++i)
    out_all[(size_t)(row0 + ty * 4 + i) * 512 + u] = acc[i] + bias;
}

// ---------------------------------------------------------------- final y GEMM
__global__ __launch_bounds__(256) void k_y(const float* __restrict__ out_all,
                                           const float* __restrict__ rv_all,
                                           const float* __restrict__ WmemT,
                                           const float* __restrict__ bmem,
                                           float* __restrict__ y) {
  const int lane = threadIdx.x, ty = threadIdx.y;
  const int o = blockIdx.x * 64 + lane;
  const int tb0 = blockIdx.y * 16;
  __shared__ float sin_[16][768];
  const int tid = ty * 64 + lane;
  for (int idx = tid; idx < 16 * 768; idx += 256) {
    int row = idx / 768, k = idx % 768;
    int tb = tb0 + row;
    sin_[row][k] = (k < 512) ? out_all[(size_t)tb * HID + k]
                             : rv_all[(size_t)tb * 256 + (k - 512)];
  }
  __syncthreads();
  float acc[4] = {0.f, 0.f, 0.f, 0.f};
  for (int k = 0; k < 768; ++k) {
    float wv = WmemT[(size_t)k * 256 + o];
#pragma unroll
    for (int i = 0; i < 4; ++i) acc[i] = fmaf(wv, sin_[ty * 4 + i][k], acc[i]);
  }
  float bo = bmem[o];
#pragma unroll
  for (int i = 0; i < 4; ++i) {
    int tb = tb0 + ty * 4 + i;
    int tt = tb >> 4, bb = tb & 15;
    y[((size_t)bb * TZ + tt) * 256 + o] = acc[i] + bo;
  }
}

extern "C" void kernel_launch(void* const* d_in, const int* in_sizes, int n_in,
                              void* d_out, int out_size, void* d_ws, size_t ws_size,
                              hipStream_t stream) {
  (void)in_sizes; (void)n_in; (void)out_size; (void)ws_size;
  const float* x    = (const float*)d_in[0];
  const float* Wih0 = (const float*)d_in[1];
  const float* bih0 = (const float*)d_in[2];
  const float* Whh0 = (const float*)d_in[3];
  const float* bhh0 = (const float*)d_in[4];
  const float* Wih1 = (const float*)d_in[5];
  const float* bih1 = (const float*)d_in[6];
  const float* Whh1 = (const float*)d_in[7];
  const float* bhh1 = (const float*)d_in[8];
  const float* Wout = (const float*)d_in[9];
  const float* bout = (const float*)d_in[10];
  const float* Wif  = (const float*)d_in[11];
  const float* bif  = (const float*)d_in[12];
  const float* Wmem = (const float*)d_in[13];
  const float* bmem = (const float*)d_in[14];
  float* y = (float*)d_out;

  float* p = (float*)d_ws;
  auto take = [&](size_t n) { float* q = p; p += n; return q; };
  float* Wih0T   = take((size_t)256 * 2048);
  float* WoutT   = take((size_t)512 * 512);
  float* WifT    = take((size_t)512 * 512);
  float* WmemT   = take((size_t)768 * 256);
  float* xpart   = take((size_t)TZ * BZ * G4H);
  float* h1_all  = take((size_t)TZ * BZ * HID);
  float* out_all = take((size_t)TZ * BZ * HID);
  float* xi_all  = take((size_t)TZ * BZ * 512);
  float* rv_all  = take((size_t)TZ * BZ * 256);
  float* linkg   = take((size_t)BZ * NCELL * NCELL);
  float* zstart  = p;
  float* h0g     = take((size_t)2 * BZ * HID);
  float* h1g     = take((size_t)2 * BZ * HID);
  float* cntf    = take((size_t)512);
  size_t zbytes = (size_t)((char*)p - (char*)zstart);
  unsigned* done   = (unsigned*)cntf;        // [0..191]
  unsigned* go     = done + 256;             // [1]
  unsigned* xiflag = done + 320;             // [16]

  (void)hipMemsetAsync(zstart, 0, zbytes, stream);

  dim3 tb32(32, 8);
  hipLaunchKernelGGL(k_transpose, dim3(8, 64), tb32, 0, stream, Wih0, Wih0T, 2048, 512, 256, 2048);
  hipLaunchKernelGGL(k_transpose, dim3(16, 16), tb32, 0, stream, Wout, WoutT, 512, 512, 512, 512);
  hipLaunchKernelGGL(k_transpose, dim3(16, 15), tb32, 0, stream, Wif, WifT, 471, 512, 512, 512);
  hipLaunchKernelGGL(k_transpose, dim3(24, 8), tb32, 0, stream, Wmem, WmemT, 256, 768, 768, 256);

  hipLaunchKernelGGL(k_xpart, dim3(32, 64), dim3(64, 4), 0, stream, x, Wih0T, bih0, bhh0, xpart);

  hipLaunchKernelGGL(k_fused, dim3(NTOT), dim3(1024), 0, stream,
                     xpart, Whh0, Wih1, Whh1, bih1, bhh1, WifT, bif,
                     h0g, h1g, h1_all, xi_all, linkg, rv_all, done, go, xiflag);

  hipLaunchKernelGGL(k_out, dim3(8, 64), dim3(64, 4), 0, stream, h1_all, WoutT, bout, out_all);

  hipLaunchKernelGGL(k_y, dim3(4, 64), dim3(64, 4), 0, stream, out_all, rv_all, WmemT, bmem, y);
}

// Round 11
// 3819.157 us; speedup vs baseline: 1.7305x; 1.2130x over previous
//
#include <hip/hip_runtime.h>
#include <math.h>

// DNC forward, fp32. Round 11: round-8 memchain (verbatim, SMT=257) +
// acquire-storm mitigation: relaxed-slot gbar aggregation (1 acquire/phase),
// XCD-isolated block roles (memchain+xi on bid%8<2 -> XCD 0/1; LSTM on 2-7),
// xi produced in 4-step chunks (1 acquire per chunk). Grid 256 (1 block/CU).

#define BZ    16
#define TZ    64
#define HID   512
#define NCELL 256
#define CSZ   64
#define NRD   4
#define G4H   2048
#define IFC   471
#define DEL   1e-6f
#define SMT   257   // LDS mem^T row stride (odd -> conflict-free columns)
#define NLSTM 192

__device__ __forceinline__ float sig_(float x) { return 1.f / (1.f + expf(-x)); }
__device__ __forceinline__ float splus_(float x) { return fmaxf(x, 0.f) + log1pf(expf(-fabsf(x))); }

// relaxed-poll until *ptr >= tgt, then ONE acquire load (sync edge, 1 L2 inval)
template <int SLP>
__device__ __forceinline__ unsigned poll_acq(unsigned* ptr, unsigned tgt) {
  unsigned v;
  while ((v = __hip_atomic_load(ptr, __ATOMIC_RELAXED, __HIP_MEMORY_SCOPE_AGENT)) < tgt)
    __builtin_amdgcn_s_sleep(SLP);
  v = __hip_atomic_load(ptr, __ATOMIC_ACQUIRE, __HIP_MEMORY_SCOPE_AGENT);
  return v;
}

// ---------------------------------------------------------------- transpose
__global__ __launch_bounds__(256) void k_transpose(const float* __restrict__ src,
                                                   float* __restrict__ dst,
                                                   int rows, int cols, int kmax, int dst_stride) {
  __shared__ float tile[32][33];
  int c0 = blockIdx.x * 32, r0 = blockIdx.y * 32;
  int tx = threadIdx.x, ty = threadIdx.y;
  for (int i = ty; i < 32; i += 8) {
    int r = r0 + i, c = c0 + tx;
    tile[i][tx] = (r < rows && c < cols) ? src[(size_t)r * cols + c] : 0.f;
  }
  __syncthreads();
  for (int i = ty; i < 32; i += 8) {
    int c = c0 + i, r = r0 + tx;
    if (c < kmax && r < rows) dst[(size_t)c * dst_stride + r] = tile[tx][i];
  }
}

// ---------------------------------------------------------------- xpart GEMM
__global__ __launch_bounds__(256) void k_xpart(const float* __restrict__ x,
                                               const float* __restrict__ Wih0T,
                                               const float* __restrict__ bih0,
                                               const float* __restrict__ bhh0,
                                               float* __restrict__ xpart) {
  const int lane = threadIdx.x, ty = threadIdx.y;
  const int jg = blockIdx.x * 64 + lane;
  const int tb0 = blockIdx.y * 16;
  __shared__ float sx[16][256];
  const int tid = ty * 64 + lane;
  for (int idx = tid; idx < 16 * 256; idx += 256) {
    int row = idx >> 8, k = idx & 255;
    int tb = tb0 + row, tt = tb >> 4, bb = tb & 15;
    sx[row][k] = x[((size_t)bb * TZ + tt) * 256 + k];
  }
  __syncthreads();
  float acc[4] = {0.f, 0.f, 0.f, 0.f};
  for (int k = 0; k < 256; ++k) {
    float wv = Wih0T[(size_t)k * G4H + jg];
#pragma unroll
    for (int i = 0; i < 4; ++i) acc[i] = fmaf(wv, sx[ty * 4 + i][k], acc[i]);
  }
  float bias = bih0[jg] + bhh0[jg];
#pragma unroll
  for (int i = 0; i < 4; ++i)
    xpart[(size_t)(tb0 + ty * 4 + i) * G4H + jg] = acc[i] + bias;
}

// ---------------------------------------------------------------- grid barrier (LSTM blocks, by rank r)
// Aggregator (r==0): relaxed slot polls + ONE acquire fence, then release go.
__device__ __forceinline__ void gbar(unsigned* done, unsigned* go,
                                     unsigned tgt, int r, int tid) {
  __syncthreads();
  if (r == 0) {
    if (tid == 0)
      __hip_atomic_store(&done[0], tgt, __ATOMIC_RELEASE, __HIP_MEMORY_SCOPE_AGENT);
    if (tid < NLSTM) {
      while (__hip_atomic_load(&done[tid], __ATOMIC_RELAXED, __HIP_MEMORY_SCOPE_AGENT) < tgt)
        __builtin_amdgcn_s_sleep(4);
    }
    __syncthreads();
    if (tid == 0) {
      __builtin_amdgcn_fence(__ATOMIC_ACQUIRE, "agent");
      __hip_atomic_store(go, tgt, __ATOMIC_RELEASE, __HIP_MEMORY_SCOPE_AGENT);
    }
  } else {
    if (tid == 0) {
      __hip_atomic_store(&done[r], tgt, __ATOMIC_RELEASE, __HIP_MEMORY_SCOPE_AGENT);
      (void)poll_acq<4>(go, tgt);
    }
    __syncthreads();
  }
}

#define SCR(s, i) scr[(s) * 1320 + (i)]

// ---------------------------------------------------------------- fused persistent kernel
// Role map (XCD isolation; XCD = bid%8 heuristic — perf only, not correctness):
//   bid%8 >= 2            : LSTM rank r=(bid>>3)*6+(bid%8-2); r<64 cell0, else cell1
//   bid%8 < 2, bid < 128  : memchain batch g=(bid>>3)  if (g&1)==bid%8, else exit
//   bid%8 < 2, bid >= 128 : xi producer batch g=(bid>>3)&15 if (g&1)!=bid%8, else exit
__global__ __launch_bounds__(1024, 1) void k_fused(
    const float* __restrict__ xpart,
    const float* __restrict__ Whh0,
    const float* __restrict__ Wih1, const float* __restrict__ Whh1,
    const float* __restrict__ bih1, const float* __restrict__ bhh1,
    const float* __restrict__ WifT, const float* __restrict__ bif,
    float* __restrict__ h0g, float* __restrict__ h1g,
    float* __restrict__ h1_all, float* __restrict__ xi_all,
    float* __restrict__ linkg, float* __restrict__ rv_all,
    unsigned* __restrict__ done, unsigned* __restrict__ go,
    unsigned* __restrict__ xiflag) {
  const int tid = threadIdx.x;
  const int bid = blockIdx.x;
  const int res = bid & 7;
  const int gq = (bid >> 3) & 15;
  int role, idx = 0;
  if (res >= 2) {
    int r = (bid >> 3) * 6 + (res - 2);
    role = (r < 64) ? 0 : 1;
    idx = r;
  } else if (bid < 128) {
    if ((gq & 1) == res) { role = 3; idx = gq; } else { role = 4; }
  } else {
    if ((gq & 1) != res) { role = 2; idx = gq; } else { role = 4; }
  }
  if (role == 4) return;
  __shared__ __align__(16) float SMEM[37264];

  if (role == 0) {
    // ================= cell0 (rank idx in 0..63) =================
    float* w0 = SMEM;               // [32][524]
    float* hl = SMEM + 16768;       // [16][520]
    float* sc = hl + 8320;          // [8][512]
    float* xpl = sc + 4096;         // [512]
    float* c0l = xpl + 512;         // [128]
    const int rnk = idx;
    const int j0 = rnk * 8;
    for (int lr = 0; lr < 32; ++lr) {
      int g = lr >> 3, jj2 = lr & 7;
      const float* src = Whh0 + (size_t)(g * 512 + j0 + jj2) * 512;
      for (int k = tid; k < 512; k += 1024) w0[lr * 524 + k] = src[k];
    }
    if (tid < 128) c0l[tid] = 0.f;
    const int ks = tid & 7, bq = (tid >> 3) & 3, jj = tid >> 5;
    const int wr0 = (0 * 8 + (jj & 7)) * 524, wr1 = (1 * 8 + (jj & 7)) * 524,
              wr2 = (2 * 8 + (jj & 7)) * 524, wr3 = (3 * 8 + (jj & 7)) * 524;
    const int hb0 = (bq * 4 + 0) * 520, hb1 = (bq * 4 + 1) * 520,
              hb2 = (bq * 4 + 2) * 520, hb3 = (bq * 4 + 3) * 520;
    for (int ph = 0; ph < 65; ++ph) {
      if (ph < 64) {
        const int t = ph, po = t & 1, pn = po ^ 1;
        for (int q = tid; q < 2048; q += 1024) {
          int bb = q >> 7, kq = q & 127;
          ((float4*)&hl[bb * 520])[kq] = ((const float4*)&h0g[(size_t)(po * 16 + bb) * 512])[kq];
        }
        if (tid < 512) {
          int bb = tid >> 5, g = (tid >> 3) & 3, j2 = tid & 7;
          xpl[tid] = xpart[((size_t)t * 16 + bb) * G4H + g * 512 + j0 + j2];
        }
        __syncthreads();
        if (tid < 256) {
          float4 a0 = {0,0,0,0}, a1 = {0,0,0,0}, a2 = {0,0,0,0}, a3 = {0,0,0,0};
#pragma unroll 4
          for (int i = 0; i < 16; ++i) {
            const int off = ks * 4 + 32 * i;
            float4 w4a = *(const float4*)&w0[wr0 + off];
            float4 w4b = *(const float4*)&w0[wr1 + off];
            float4 w4c = *(const float4*)&w0[wr2 + off];
            float4 w4d = *(const float4*)&w0[wr3 + off];
            float4 h4a = *(const float4*)&hl[hb0 + off];
            float4 h4b = *(const float4*)&hl[hb1 + off];
            float4 h4c = *(const float4*)&hl[hb2 + off];
            float4 h4d = *(const float4*)&hl[hb3 + off];
            a0.x += w4a.x*h4a.x + w4a.y*h4a.y + w4a.z*h4a.z + w4a.w*h4a.w;
            a0.y += w4a.x*h4b.x + w4a.y*h4b.y + w4a.z*h4b.z + w4a.w*h4b.w;
            a0.z += w4a.x*h4c.x + w4a.y*h4c.y + w4a.z*h4c.z + w4a.w*h4c.w;
            a0.w += w4a.x*h4d.x + w4a.y*h4d.y + w4a.z*h4d.z + w4a.w*h4d.w;
            a1.x += w4b.x*h4a.x + w4b.y*h4a.y + w4b.z*h4a.z + w4b.w*h4a.w;
            a1.y += w4b.x*h4b.x + w4b.y*h4b.y + w4b.z*h4b.z + w4b.w*h4b.w;
            a1.z += w4b.x*h4c.x + w4b.y*h4c.y + w4b.z*h4c.z + w4b.w*h4c.w;
            a1.w += w4b.x*h4d.x + w4b.y*h4d.y + w4b.z*h4d.z + w4b.w*h4d.w;
            a2.x += w4c.x*h4a.x + w4c.y*h4a.y + w4c.z*h4a.z + w4c.w*h4a.w;
            a2.y += w4c.x*h4b.x + w4c.y*h4b.y + w4c.z*h4b.z + w4c.w*h4b.w;
            a2.z += w4c.x*h4c.x + w4c.y*h4c.y + w4c.z*h4c.z + w4c.w*h4c.w;
            a2.w += w4c.x*h4d.x + w4c.y*h4d.y + w4c.z*h4d.z + w4c.w*h4d.w;
            a3.x += w4d.x*h4a.x + w4d.y*h4a.y + w4d.z*h4a.z + w4d.w*h4a.w;
            a3.y += w4d.x*h4b.x + w4d.y*h4b.y + w4d.z*h4b.z + w4d.w*h4b.w;
            a3.z += w4d.x*h4c.x + w4d.y*h4c.y + w4d.z*h4c.z + w4d.w*h4c.w;
            a3.w += w4d.x*h4d.x + w4d.y*h4d.y + w4d.z*h4d.z + w4d.w*h4d.w;
          }
          *(float4*)&sc[ks * 512 + (0 * 8 + jj) * 16 + bq * 4] = a0;
          *(float4*)&sc[ks * 512 + (1 * 8 + jj) * 16 + bq * 4] = a1;
          *(float4*)&sc[ks * 512 + (2 * 8 + jj) * 16 + bq * 4] = a2;
          *(float4*)&sc[ks * 512 + (3 * 8 + jj) * 16 + bq * 4] = a3;
        }
        __syncthreads();
        if (tid < 128) {
          const int bb = tid >> 3, j2 = tid & 7;
          float gs[4];
#pragma unroll
          for (int g = 0; g < 4; ++g) {
            float s = 0.f;
#pragma unroll
            for (int k2 = 0; k2 < 8; ++k2) s += sc[k2 * 512 + (g * 8 + j2) * 16 + bb];
            gs[g] = s + xpl[bb * 32 + g * 8 + j2];
          }
          float gi = sig_(gs[0]), gf = sig_(gs[1]), gg = tanhf(gs[2]), go_ = sig_(gs[3]);
          float cc = gf * c0l[j2 * 16 + bb] + gi * gg;
          c0l[j2 * 16 + bb] = cc;
          h0g[(size_t)(pn * 16 + bb) * 512 + j0 + j2] = go_ * tanhf(cc);
        }
      }
      gbar(done, go, (unsigned)(ph + 1), rnk, tid);
    }
  } else if (role == 1) {
    // ================= cell1 (rank idx in 64..191) =================
    float* w1 = SMEM;               // [16][1028]
    float* h0l = SMEM + 16448;      // [16][520]
    float* h1l = h0l + 8320;        // [16][520]
    float* sc = h1l + 8320;         // [16][256]
    float* c1l = sc + 4096;         // [64]
    float* bl = c1l + 64;           // [16]
    const int rnk = idx;
    const int j0 = (rnk - 64) * 4;
    for (int lr = 0; lr < 16; ++lr) {
      int g = lr >> 2, jj2 = lr & 3;
      const float* si = Wih1 + (size_t)(g * 512 + j0 + jj2) * 512;
      const float* sh = Whh1 + (size_t)(g * 512 + j0 + jj2) * 512;
      for (int k = tid; k < 512; k += 1024) {
        w1[lr * 1028 + k] = si[k];
        w1[lr * 1028 + 512 + k] = sh[k];
      }
    }
    if (tid < 64) c1l[tid] = 0.f;
    if (tid < 16) {
      int g = tid >> 2, jj2 = tid & 3;
      bl[tid] = bih1[g * 512 + j0 + jj2] + bhh1[g * 512 + j0 + jj2];
    }
    const int ks = tid & 15, bq = (tid >> 4) & 3, jj = (tid >> 6) & 3;
    const int wr0 = (0 * 4 + jj) * 1028, wr1 = (1 * 4 + jj) * 1028,
              wr2 = (2 * 4 + jj) * 1028, wr3 = (3 * 4 + jj) * 1028;
    const int hb0 = (bq * 4 + 0) * 520, hb1 = (bq * 4 + 1) * 520,
              hb2 = (bq * 4 + 2) * 520, hb3 = (bq * 4 + 3) * 520;
    for (int ph = 0; ph < 65; ++ph) {
      if (ph >= 1) {
        const int t = ph - 1, po = t & 1, pn = po ^ 1;
        for (int q = tid; q < 2048; q += 1024) {
          int bb = q >> 7, kq = q & 127;
          ((float4*)&h0l[bb * 520])[kq] = ((const float4*)&h0g[(size_t)(pn * 16 + bb) * 512])[kq];
          ((float4*)&h1l[bb * 520])[kq] = ((const float4*)&h1g[(size_t)(po * 16 + bb) * 512])[kq];
        }
        __syncthreads();
        if (tid < 256) {
          float4 a0 = {0,0,0,0}, a1 = {0,0,0,0}, a2 = {0,0,0,0}, a3 = {0,0,0,0};
#pragma unroll 4
          for (int i = 0; i < 16; ++i) {
            const int offw = ks * 4 + 64 * i;
            const int offh = (i < 8) ? offw : (offw - 512);
            const float* hsrc = (i < 8) ? h0l : h1l;
            float4 w4a = *(const float4*)&w1[wr0 + offw];
            float4 w4b = *(const float4*)&w1[wr1 + offw];
            float4 w4c = *(const float4*)&w1[wr2 + offw];
            float4 w4d = *(const float4*)&w1[wr3 + offw];
            float4 h4a = *(const float4*)&hsrc[hb0 + offh];
            float4 h4b = *(const float4*)&hsrc[hb1 + offh];
            float4 h4c = *(const float4*)&hsrc[hb2 + offh];
            float4 h4d = *(const float4*)&hsrc[hb3 + offh];
            a0.x += w4a.x*h4a.x + w4a.y*h4a.y + w4a.z*h4a.z + w4a.w*h4a.w;
            a0.y += w4a.x*h4b.x + w4a.y*h4b.y + w4a.z*h4b.z + w4a.w*h4b.w;
            a0.z += w4a.x*h4c.x + w4a.y*h4c.y + w4a.z*h4c.z + w4a.w*h4c.w;
            a0.w += w4a.x*h4d.x + w4a.y*h4d.y + w4a.z*h4d.z + w4a.w*h4d.w;
            a1.x += w4b.x*h4a.x + w4b.y*h4a.y + w4b.z*h4a.z + w4b.w*h4a.w;
            a1.y += w4b.x*h4b.x + w4b.y*h4b.y + w4b.z*h4b.z + w4b.w*h4b.w;
            a1.z += w4b.x*h4c.x + w4b.y*h4c.y + w4b.z*h4c.z + w4b.w*h4c.w;
            a1.w += w4b.x*h4d.x + w4b.y*h4d.y + w4b.z*h4d.z + w4b.w*h4d.w;
            a2.x += w4c.x*h4a.x + w4c.y*h4a.y + w4c.z*h4a.z + w4c.w*h4a.w;
            a2.y += w4c.x*h4b.x + w4c.y*h4b.y + w4c.z*h4b.z + w4c.w*h4b.w;
            a2.z += w4c.x*h4c.x + w4c.y*h4c.y + w4c.z*h4c.z + w4c.w*h4c.w;
            a2.w += w4c.x*h4d.x + w4c.y*h4d.y + w4c.z*h4d.z + w4c.w*h4d.w;
            a3.x += w4d.x*h4a.x + w4d.y*h4a.y + w4d.z*h4a.z + w4d.w*h4a.w;
            a3.y += w4d.x*h4b.x + w4d.y*h4b.y + w4d.z*h4b.z + w4d.w*h4b.w;
            a3.z += w4d.x*h4c.x + w4d.y*h4c.y + w4d.z*h4c.z + w4d.w*h4c.w;
            a3.w += w4d.x*h4d.x + w4d.y*h4d.y + w4d.z*h4d.z + w4d.w*h4d.w;
          }
          *(float4*)&sc[ks * 256 + (0 * 4 + jj) * 16 + bq * 4] = a0;
          *(float4*)&sc[ks * 256 + (1 * 4 + jj) * 16 + bq * 4] = a1;
          *(float4*)&sc[ks * 256 + (2 * 4 + jj) * 16 + bq * 4] = a2;
          *(float4*)&sc[ks * 256 + (3 * 4 + jj) * 16 + bq * 4] = a3;
        }
        __syncthreads();
        if (tid < 64) {
          const int bb = tid >> 2, j2 = tid & 3;
          float gs[4];
#pragma unroll
          for (int g = 0; g < 4; ++g) {
            float s = 0.f;
#pragma unroll
            for (int k2 = 0; k2 < 16; ++k2) s += sc[k2 * 256 + (g * 4 + j2) * 16 + bb];
            gs[g] = s + bl[g * 4 + j2];
          }
          float gi = sig_(gs[0]), gf = sig_(gs[1]), gg = tanhf(gs[2]), go_ = sig_(gs[3]);
          float cc = gf * c1l[j2 * 16 + bb] + gi * gg;
          c1l[j2 * 16 + bb] = cc;
          float hv = go_ * tanhf(cc);
          h1g[(size_t)(pn * 16 + bb) * 512 + j0 + j2] = hv;
          h1_all[((size_t)t * 16 + bb) * 512 + j0 + j2] = hv;
        }
      }
      gbar(done, go, (unsigned)(ph + 1), rnk, tid);
    }
  } else if (role == 2) {
    // ================= xi producer (one per batch), 4-step chunks =================
    const int b = idx;
    float* sh1 = SMEM;        // [512]
    float* sxo = SMEM + 512;  // [2][512]
    __shared__ unsigned sgo;
    unsigned seen_go = 0;
    for (int tc = 0; tc < TZ / 4; ++tc) {
      const unsigned need = (unsigned)(4 * tc + 5);  // h1(4tc+3) visible at go >= 4tc+5
      if (tid == 0 && seen_go < need) {
        sgo = poll_acq<8>(go, need);
      }
      __syncthreads();
      if (seen_go < need) seen_go = sgo;
      for (int k4 = 0; k4 < 4; ++k4) {
        const int t = 4 * tc + k4;
        if (tid < 512) sh1[tid] = h1_all[((size_t)t * BZ + b) * HID + tid];
        __syncthreads();
        {
          const int u = tid & 511, half = tid >> 9;
          if (u < IFC) {
            const float* wc = WifT + u;
            const int k0 = half * 256;
            float acc = 0.f;
#pragma unroll 8
            for (int k = k0; k < k0 + 256; ++k)
              acc = fmaf(sh1[k], wc[(size_t)k * 512], acc);
            sxo[half * 512 + u] = acc;
          }
        }
        __syncthreads();
        if (tid < IFC)
          xi_all[((size_t)t * BZ + b) * 512 + tid] = sxo[tid] + sxo[512 + tid] + bif[tid];
        __syncthreads();
      }
      if (tid == 0)
        __hip_atomic_store(&xiflag[b], (unsigned)(4 * tc + 4), __ATOMIC_RELEASE, __HIP_MEMORY_SCOPE_AGENT);
    }
  } else {
    // ================= memory-module chain (one per batch) — round-8 verbatim =================
    const int b = idx;
    const int lane = tid & 63;
    const int wv = tid >> 6;
    const int m8 = tid & 255;
    const int seg = tid >> 8;
    float* LNK = linkg + (size_t)b * (NCELL * NCELL);

    float* smemT = SMEM;               // 16448
    float* sxi   = smemT + 16448;      // 472
    float* srkn  = sxi + 472;          // 256 [4][64]
    float* swkn  = srkn + 256;         // 64
    float* sev   = swkn + 64;          // 64
    float* swvv  = sev + 64;           // 64
    float* sscal = swvv + 64;          // 40
    float* srw   = sscal + 40;         // 1024 [4][256]
    float* sww   = srw + 1024;         // 256
    float* susage = sww + 256;         // 256
    float* sprec = susage + 256;       // 256
    float* ssim  = sprec + 256;        // 1024 [4][256]
    float* sfwd  = ssim + 1024;        // 1024 [4][256]
    float* sbwd  = sfwd + 1024;        // 1056 [4][264]
    float* sa    = sbwd + 1056;        // 256
    float* sc_   = sa + 256;           // 256
    float* sb_   = sc_ + 256;          // 256
    int*   srank = (int*)(sb_ + 256);  // 256
    float* scr   = (float*)(srank + 256); // 5280 [4][1320]
    float* sred2 = scr + 5280;         // 64
    __shared__ unsigned sflag;

    for (int i = tid; i < CSZ * SMT; i += 1024) smemT[i] = 0.f;
    if (tid < 256) {
      sww[tid] = 0.f; susage[tid] = 0.f; sprec[tid] = 0.f;
      srw[tid] = 0.f; srw[256 + tid] = 0.f; srw[512 + tid] = 0.f; srw[768 + tid] = 0.f;
    }
    for (int i = tid; i < (NCELL * NCELL) / 4; i += 1024)
      ((float4*)LNK)[i] = make_float4(0.f, 0.f, 0.f, 0.f);
    __syncthreads();

    unsigned seen = 0;
    for (int t = 0; t < TZ; ++t) {
      if (tid == 0 && seen < (unsigned)(t + 1)) {
        sflag = poll_acq<8>(&xiflag[b], (unsigned)(t + 1));
      }
      __syncthreads();
      if (seen < (unsigned)(t + 1)) seen = sflag;

      // ---- P0: load + parse xi ----
      if (tid < IFC) sxi[tid] = xi_all[((size_t)t * BZ + b) * 512 + tid];
      __syncthreads();
      if (wv < 4) {
        float v = tanhf(sxi[wv * 64 + lane]);
        float s2 = v * v;
#pragma unroll
        for (int off = 32; off; off >>= 1) s2 += __shfl_xor(s2, off);
        srkn[wv * 64 + lane] = v / (sqrtf(s2) + DEL);
      } else if (wv == 4) {
        float v = tanhf(sxi[260 + lane]);
        float s2 = v * v;
#pragma unroll
        for (int off = 32; off; off >>= 1) s2 += __shfl_xor(s2, off);
        swkn[lane] = v / (sqrtf(s2) + DEL);
      } else if (wv == 5) {
        sev[lane] = sig_(sxi[325 + lane]);
      } else if (wv == 6) {
        swvv[lane] = tanhf(sxi[389 + lane]);
      } else if (wv == 7) {
        if (lane < 4) sscal[lane] = splus_(sxi[256 + lane]);
        if (lane == 4) sscal[4] = splus_(sxi[324]);
        if (lane >= 8 && lane < 12) sscal[lane] = sig_(sxi[453 + (lane - 8)]);
        if (lane == 12) sscal[12] = sig_(sxi[457]);
        if (lane == 13) sscal[13] = sig_(sxi[458]);
        if (lane >= 16 && lane < 20) {
          int r = lane - 16;
          float a = sxi[459 + r * 3], b2 = sxi[460 + r * 3], c2 = sxi[461 + r * 3];
          float mx3 = fmaxf(a, fmaxf(b2, c2));
          float ea = expf(a - mx3), eb = expf(b2 - mx3), ec = expf(c2 - mx3);
          float iv = 1.f / (ea + eb + ec);
          sscal[20 + r * 3 + 0] = ea * iv;
          sscal[20 + r * 3 + 1] = eb * iv;
          sscal[20 + r * 3 + 2] = ec * iv;
        }
      }
      __syncthreads();

      // ---- P1: usage update + write-content dot (old mem) ----
      float un_r = 0.f;
      if (tid < 256) {
        float wwo = sww[tid], uo = susage[tid];
        float u1 = uo + (1.f - uo) * wwo;
        float psi = 1.f;
#pragma unroll
        for (int r = 0; r < 4; ++r) psi *= 1.f - sscal[8 + r] * srw[r * 256 + tid];
        un_r = u1 * psi;
        susage[tid] = un_r;
      }
      {
        float dot = 0.f, nn = 0.f;
#pragma unroll 4
        for (int w = seg * 16; w < seg * 16 + 16; ++w) {
          float mv = smemT[w * SMT + m8];
          dot = fmaf(mv, swkn[w], dot);
          nn = fmaf(mv, mv, nn);
        }
        SCR(seg, 0 * 264 + m8) = dot;
        SCR(seg, 1 * 264 + m8) = nn;
      }
      __syncthreads();
      float e_r = 0.f, simv = 0.f;
      if (tid < 256) {
        float dot = SCR(0, tid) + SCR(1, tid) + SCR(2, tid) + SCR(3, tid);
        float nn = SCR(0, 264 + tid) + SCR(1, 264 + tid) + SCR(2, 264 + tid) + SCR(3, 264 + tid);
        simv = sscal[4] * dot / (sqrtf(nn) + DEL);
        float mx = simv;
#pragma unroll
        for (int off = 32; off; off >>= 1) mx = fmaxf(mx, __shfl_xor(mx, off));
        if (lane == 0) sred2[wv] = mx;
      }
      __syncthreads();
      if (tid < 256) {
        float mx = fmaxf(fmaxf(sred2[0], sred2[1]), fmaxf(sred2[2], sred2[3]));
        e_r = expf(simv - mx);
        float s = e_r;
#pragma unroll
        for (int off = 32; off; off >>= 1) s += __shfl_xor(s, off);
        if (lane == 0) sred2[8 + wv] = s;
      }
      __syncthreads();
      float wcw_r = 0.f;
      if (tid < 256) {
        float sm = sred2[8] + sred2[9] + sred2[10] + sred2[11];
        wcw_r = e_r / sm;
        sa[tid] = DEL + (1.f - DEL) * un_r;
      }
      __syncthreads();

      // ---- P2: allocation (stable rank + exclusive cumprod) ----
      {
        float um = sa[m8];
        int cnt = 0;
        for (int j2 = seg * 64; j2 < seg * 64 + 64; ++j2) {
          float uj = sa[j2];
          cnt += (uj < um || (uj == um && j2 < m8)) ? 1 : 0;
        }
        ((int*)&SCR(seg, 0))[m8] = cnt;
      }
      __syncthreads();
      if (tid < 256) {
        int rank = ((int*)&SCR(0, 0))[tid] + ((int*)&SCR(1, 0))[tid] +
                   ((int*)&SCR(2, 0))[tid] + ((int*)&SCR(3, 0))[tid];
        srank[tid] = rank;
        sb_[rank] = sa[tid];
      }
      __syncthreads();
      float inc = 0.f;
      if (tid < 256) {
        inc = sb_[tid];
#pragma unroll
        for (int off = 1; off < 64; off <<= 1) {
          float pp = __shfl_up(inc, off);
          if (lane >= off) inc *= pp;
        }
        if (lane == 63) sred2[16 + wv] = inc;
      }
      __syncthreads();
      if (tid < 256) {
        float pref = 1.f;
        for (int w2 = 0; w2 < wv; ++w2) pref *= sred2[16 + w2];
        float excl = __shfl_up(inc, 1);
        if (lane == 0) excl = 1.f;
        sc_[tid] = excl * pref;
      }
      __syncthreads();

      // ---- P3: write weighting + wsum ----
      if (tid < 256) {
        float alo = (1.f - sa[tid]) * sc_[srank[tid]];
        float wwn = sscal[13] * (sscal[12] * alo + (1.f - sscal[12]) * wcw_r);
        sww[tid] = wwn;
        float s = wwn;
#pragma unroll
        for (int off = 32; off; off >>= 1) s += __shfl_xor(s, off);
        if (lane == 0) sred2[24 + wv] = s;
      }
      __syncthreads();
      if (tid == 0) sscal[14] = sred2[24] + sred2[25] + sred2[26] + sred2[27];

      // ---- P4: memory erase/write + read-content sims (+ zero sbwd) ----
      {
        float wm = sww[m8];
        float nn = 0.f, d0 = 0.f, d1 = 0.f, d2 = 0.f, d3 = 0.f;
#pragma unroll 4
        for (int w = seg * 16; w < seg * 16 + 16; ++w) {
          float v = smemT[w * SMT + m8];
          v = v * (1.f - wm * sev[w]) + wm * swvv[w];
          smemT[w * SMT + m8] = v;
          nn = fmaf(v, v, nn);
          d0 = fmaf(v, srkn[0 * 64 + w], d0);
          d1 = fmaf(v, srkn[1 * 64 + w], d1);
          d2 = fmaf(v, srkn[2 * 64 + w], d2);
          d3 = fmaf(v, srkn[3 * 64 + w], d3);
        }
        SCR(seg, 0 * 264 + m8) = nn;
        SCR(seg, 1 * 264 + m8) = d0;
        SCR(seg, 2 * 264 + m8) = d1;
        SCR(seg, 3 * 264 + m8) = d2;
        SCR(seg, 4 * 264 + m8) = d3;
      }
      for (int i = tid; i < NRD * 264; i += 1024) sbwd[i] = 0.f;
      __syncthreads();
      float sv0 = 0.f, sv1 = 0.f, sv2 = 0.f, sv3 = 0.f;
      float e0 = 0.f, e1 = 0.f, e2 = 0.f, e3 = 0.f;
      if (tid < 256) {
        float nn = SCR(0, tid) + SCR(1, tid) + SCR(2, tid) + SCR(3, tid);
        float invn = 1.f / (sqrtf(nn) + DEL);
        sv0 = sscal[0] * (SCR(0, 264 + tid) + SCR(1, 264 + tid) + SCR(2, 264 + tid) + SCR(3, 264 + tid)) * invn;
        sv1 = sscal[1] * (SCR(0, 528 + tid) + SCR(1, 528 + tid) + SCR(2, 528 + tid) + SCR(3, 528 + tid)) * invn;
        sv2 = sscal[2] * (SCR(0, 792 + tid) + SCR(1, 792 + tid) + SCR(2, 792 + tid) + SCR(3, 792 + tid)) * invn;
        sv3 = sscal[3] * (SCR(0, 1056 + tid) + SCR(1, 1056 + tid) + SCR(2, 1056 + tid) + SCR(3, 1056 + tid)) * invn;
        float m0 = sv0, m1 = sv1, m2 = sv2, m3 = sv3;
#pragma unroll
        for (int off = 32; off; off >>= 1) {
          m0 = fmaxf(m0, __shfl_xor(m0, off));
          m1 = fmaxf(m1, __shfl_xor(m1, off));
          m2 = fmaxf(m2, __shfl_xor(m2, off));
          m3 = fmaxf(m3, __shfl_xor(m3, off));
        }
        if (lane == 0) {
          sred2[wv * 4 + 0] = m0; sred2[wv * 4 + 1] = m1;
          sred2[wv * 4 + 2] = m2; sred2[wv * 4 + 3] = m3;
        }
      }
      __syncthreads();
      if (tid < 256) {
        float m0 = fmaxf(fmaxf(sred2[0], sred2[4]), fmaxf(sred2[8], sred2[12]));
        float m1 = fmaxf(fmaxf(sred2[1], sred2[5]), fmaxf(sred2[9], sred2[13]));
        float m2 = fmaxf(fmaxf(sred2[2], sred2[6]), fmaxf(sred2[10], sred2[14]));
        float m3 = fmaxf(fmaxf(sred2[3], sred2[7]), fmaxf(sred2[11], sred2[15]));
        e0 = expf(sv0 - m0); e1 = expf(sv1 - m1); e2 = expf(sv2 - m2); e3 = expf(sv3 - m3);
        float s0 = e0, s1 = e1, s2 = e2, s3 = e3;
#pragma unroll
        for (int off = 32; off; off >>= 1) {
          s0 += __shfl_xor(s0, off); s1 += __shfl_xor(s1, off);
          s2 += __shfl_xor(s2, off); s3 += __shfl_xor(s3, off);
        }
        if (lane == 0) {
          sred2[32 + wv * 4 + 0] = s0; sred2[32 + wv * 4 + 1] = s1;
          sred2[32 + wv * 4 + 2] = s2; sred2[32 + wv * 4 + 3] = s3;
        }
      }
      __syncthreads();
      if (tid < 256) {
        float s0 = sred2[32] + sred2[36] + sred2[40] + sred2[44];
        float s1 = sred2[33] + sred2[37] + sred2[41] + sred2[45];
        float s2 = sred2[34] + sred2[38] + sred2[42] + sred2[46];
        float s3 = sred2[35] + sred2[39] + sred2[43] + sred2[47];
        ssim[0 * 256 + tid] = e0 / s0; ssim[1 * 256 + tid] = e1 / s1;
        ssim[2 * 256 + tid] = e2 / s2; ssim[3 * 256 + tid] = e3 / s3;
      }

      // ---- P5: link update + fwd + bwd, coalesced row-per-wave pass ----
      {
        const float4 r0 = ((const float4*)(srw + 0 * 256))[lane];
        const float4 r1 = ((const float4*)(srw + 1 * 256))[lane];
        const float4 r2 = ((const float4*)(srw + 2 * 256))[lane];
        const float4 r3 = ((const float4*)(srw + 3 * 256))[lane];
        const float4 wc = ((const float4*)sww)[lane];
        const float4 pc = ((const float4*)sprec)[lane];
        const int n0 = lane * 4;
        float4 bp0 = {0,0,0,0}, bp1 = {0,0,0,0}, bp2 = {0,0,0,0}, bp3 = {0,0,0,0};
        for (int rr = 0; rr < 16; ++rr) {
          const int m = wv * 16 + rr;
          const float wm = sww[m];
          float4 lv = ((float4*)(LNK + (size_t)m * 256))[lane];
          lv.x = (1.f - wm - wc.x) * lv.x + wm * pc.x;
          lv.y = (1.f - wm - wc.y) * lv.y + wm * pc.y;
          lv.z = (1.f - wm - wc.z) * lv.z + wm * pc.z;
          lv.w = (1.f - wm - wc.w) * lv.w + wm * pc.w;
          if (m == n0 + 0) lv.x = 0.f;
          if (m == n0 + 1) lv.y = 0.f;
          if (m == n0 + 2) lv.z = 0.f;
          if (m == n0 + 3) lv.w = 0.f;
          ((float4*)(LNK + (size_t)m * 256))[lane] = lv;
          float f0 = lv.x * r0.x + lv.y * r0.y + lv.z * r0.z + lv.w * r0.w;
          float f1 = lv.x * r1.x + lv.y * r1.y + lv.z * r1.z + lv.w * r1.w;
          float f2 = lv.x * r2.x + lv.y * r2.y + lv.z * r2.z + lv.w * r2.w;
          float f3 = lv.x * r3.x + lv.y * r3.y + lv.z * r3.z + lv.w * r3.w;
#pragma unroll
          for (int off = 32; off; off >>= 1) {
            f0 += __shfl_xor(f0, off); f1 += __shfl_xor(f1, off);
            f2 += __shfl_xor(f2, off); f3 += __shfl_xor(f3, off);
          }
          if (lane == 0) {
            sfwd[0 * 256 + m] = f0; sfwd[1 * 256 + m] = f1;
            sfwd[2 * 256 + m] = f2; sfwd[3 * 256 + m] = f3;
          }
          const float s0 = srw[0 * 256 + m], s1 = srw[1 * 256 + m],
                      s2 = srw[2 * 256 + m], s3 = srw[3 * 256 + m];
          bp0.x = fmaf(lv.x, s0, bp0.x); bp0.y = fmaf(lv.y, s0, bp0.y);
          bp0.z = fmaf(lv.z, s0, bp0.z); bp0.w = fmaf(lv.w, s0, bp0.w);
          bp1.x = fmaf(lv.x, s1, bp1.x); bp1.y = fmaf(lv.y, s1, bp1.y);
          bp1.z = fmaf(lv.z, s1, bp1.z); bp1.w = fmaf(lv.w, s1, bp1.w);
          bp2.x = fmaf(lv.x, s2, bp2.x); bp2.y = fmaf(lv.y, s2, bp2.y);
          bp2.z = fmaf(lv.z, s2, bp2.z); bp2.w = fmaf(lv.w, s2, bp2.w);
          bp3.x = fmaf(lv.x, s3, bp3.x); bp3.y = fmaf(lv.y, s3, bp3.y);
          bp3.z = fmaf(lv.z, s3, bp3.z); bp3.w = fmaf(lv.w, s3, bp3.w);
        }
        atomicAdd(&sbwd[0 * 264 + n0 + 0], bp0.x); atomicAdd(&sbwd[0 * 264 + n0 + 1], bp0.y);
        atomicAdd(&sbwd[0 * 264 + n0 + 2], bp0.z); atomicAdd(&sbwd[0 * 264 + n0 + 3], bp0.w);
        atomicAdd(&sbwd[1 * 264 + n0 + 0], bp1.x); atomicAdd(&sbwd[1 * 264 + n0 + 1], bp1.y);
        atomicAdd(&sbwd[1 * 264 + n0 + 2], bp1.z); atomicAdd(&sbwd[1 * 264 + n0 + 3], bp1.w);
        atomicAdd(&sbwd[2 * 264 + n0 + 0], bp2.x); atomicAdd(&sbwd[2 * 264 + n0 + 1], bp2.y);
        atomicAdd(&sbwd[2 * 264 + n0 + 2], bp2.z); atomicAdd(&sbwd[2 * 264 + n0 + 3], bp2.w);
        atomicAdd(&sbwd[3 * 264 + n0 + 0], bp3.x); atomicAdd(&sbwd[3 * 264 + n0 + 1], bp3.y);
        atomicAdd(&sbwd[3 * 264 + n0 + 2], bp3.z); atomicAdd(&sbwd[3 * 264 + n0 + 3], bp3.w);
      }
      __syncthreads();

      // ---- P7: rw update + precedence ----
      if (tid < 256) {
#pragma unroll
        for (int r = 0; r < 4; ++r) {
          float rwn = sscal[20 + r * 3 + 0] * sbwd[r * 264 + tid] +
                      sscal[20 + r * 3 + 1] * sfwd[r * 256 + tid] +
                      sscal[20 + r * 3 + 2] * ssim[r * 256 + tid];
          srw[r * 256 + tid] = rwn;
        }
        sprec[tid] = (1.f - sscal[14]) * sprec[tid] + sww[tid];
      }
      __syncthreads();

      // ---- P8: read vectors ----
      {
        const int r = tid >> 8, sg = (tid >> 6) & 3, w = lane;
        float acc = 0.f;
#pragma unroll 4
        for (int m2 = sg * 64; m2 < sg * 64 + 64; ++m2)
          acc = fmaf(srw[r * 256 + m2], smemT[w * SMT + m2], acc);
        SCR(sg, r * 64 + w) = acc;
      }
      __syncthreads();
      if (tid < 256)
        rv_all[((size_t)t * BZ + b) * 256 + tid] =
            SCR(0, tid) + SCR(1, tid) + SCR(2, tid) + SCR(3, tid);
      __syncthreads();
    }
  }
}

// ---------------------------------------------------------------- out GEMM
__global__ __launch_bounds__(256) void k_out(const float* __restrict__ h1_all,
                                             const float* __restrict__ WoutT,
                                             const float* __restrict__ bout,
                                             float* __restrict__ out_all) {
  const int lane = threadIdx.x, ty = threadIdx.y;
  const int u = blockIdx.x * 64 + lane;
  const int row0 = blockIdx.y * 16;
  __shared__ float sh[16][512];
  const int tid = ty * 64 + lane;
  for (int idx = tid; idx < 16 * 512; idx += 256) {
    int r2 = idx >> 9, k = idx & 511;
    sh[r2][k] = h1_all[(size_t)(row0 + r2) * 512 + k];
  }
  __syncthreads();
  const float* wcol = WoutT + u;
  float bias = bout[u];
  float acc[4] = {0.f, 0.f, 0.f, 0.f};
  for (int k = 0; k < 512; ++k) {
    float wv = wcol[(size_t)k * 512];
#pragma unroll
    for (int i = 0; i < 4; ++i) acc[i] = fmaf(wv, sh[ty * 4 + i][k], acc[i]);
  }
#pragma unroll
  for (int i = 0; i < 4; ++i)
    out_all[(size_t)(row0 + ty * 4 + i) * 512 + u] = acc[i] + bias;
}

// ---------------------------------------------------------------- final y GEMM
__global__ __launch_bounds__(256) void k_y(const float* __restrict__ out_all,
                                           const float* __restrict__ rv_all,
                                           const float* __restrict__ WmemT,
                                           const float* __restrict__ bmem,
                                           float* __restrict__ y) {
  const int lane = threadIdx.x, ty = threadIdx.y;
  const int o = blockIdx.x * 64 + lane;
  const int tb0 = blockIdx.y * 16;
  __shared__ float sin_[16][768];
  const int tid = ty * 64 + lane;
  for (int idx = tid; idx < 16 * 768; idx += 256) {
    int row = idx / 768, k = idx % 768;
    int tb = tb0 + row;
    sin_[row][k] = (k < 512) ? out_all[(size_t)tb * HID + k]
                             : rv_all[(size_t)tb * 256 + (k - 512)];
  }
  __syncthreads();
  float acc[4] = {0.f, 0.f, 0.f, 0.f};
  for (int k = 0; k < 768; ++k) {
    float wv = WmemT[(size_t)k * 256 + o];
#pragma unroll
    for (int i = 0; i < 4; ++i) acc[i] = fmaf(wv, sin_[ty * 4 + i][k], acc[i]);
  }
  float bo = bmem[o];
#pragma unroll
  for (int i = 0; i < 4; ++i) {
    int tb = tb0 + ty * 4 + i;
    int tt = tb >> 4, bb = tb & 15;
    y[((size_t)bb * TZ + tt) * 256 + o] = acc[i] + bo;
  }
}

extern "C" void kernel_launch(void* const* d_in, const int* in_sizes, int n_in,
                              void* d_out, int out_size, void* d_ws, size_t ws_size,
                              hipStream_t stream) {
  (void)in_sizes; (void)n_in; (void)out_size; (void)ws_size;
  const float* x    = (const float*)d_in[0];
  const float* Wih0 = (const float*)d_in[1];
  const float* bih0 = (const float*)d_in[2];
  const float* Whh0 = (const float*)d_in[3];
  const float* bhh0 = (const float*)d_in[4];
  const float* Wih1 = (const float*)d_in[5];
  const float* bih1 = (const float*)d_in[6];
  const float* Whh1 = (const float*)d_in[7];
  const float* bhh1 = (const float*)d_in[8];
  const float* Wout = (const float*)d_in[9];
  const float* bout = (const float*)d_in[10];
  const float* Wif  = (const float*)d_in[11];
  const float* bif  = (const float*)d_in[12];
  const float* Wmem = (const float*)d_in[13];
  const float* bmem = (const float*)d_in[14];
  float* y = (float*)d_out;

  float* p = (float*)d_ws;
  auto take = [&](size_t n) { float* q = p; p += n; return q; };
  float* Wih0T   = take((size_t)256 * 2048);
  float* WoutT   = take((size_t)512 * 512);
  float* WifT    = take((size_t)512 * 512);
  float* WmemT   = take((size_t)768 * 256);
  float* xpart   = take((size_t)TZ * BZ * G4H);
  float* h1_all  = take((size_t)TZ * BZ * HID);
  float* out_all = take((size_t)TZ * BZ * HID);
  float* xi_all  = take((size_t)TZ * BZ * 512);
  float* rv_all  = take((size_t)TZ * BZ * 256);
  float* linkg   = take((size_t)BZ * NCELL * NCELL);
  float* zstart  = p;
  float* h0g     = take((size_t)2 * BZ * HID);
  float* h1g     = take((size_t)2 * BZ * HID);
  float* cntf    = take((size_t)512);
  size_t zbytes = (size_t)((char*)p - (char*)zstart);
  unsigned* done   = (unsigned*)cntf;        // [0..191] by LSTM rank
  unsigned* go     = done + 256;             // [1]
  unsigned* xiflag = done + 320;             // [16]

  (void)hipMemsetAsync(zstart, 0, zbytes, stream);

  dim3 tb32(32, 8);
  hipLaunchKernelGGL(k_transpose, dim3(8, 64), tb32, 0, stream, Wih0, Wih0T, 2048, 512, 256, 2048);
  hipLaunchKernelGGL(k_transpose, dim3(16, 16), tb32, 0, stream, Wout, WoutT, 512, 512, 512, 512);
  hipLaunchKernelGGL(k_transpose, dim3(16, 15), tb32, 0, stream, Wif, WifT, 471, 512, 512, 512);
  hipLaunchKernelGGL(k_transpose, dim3(24, 8), tb32, 0, stream, Wmem, WmemT, 256, 768, 768, 256);

  hipLaunchKernelGGL(k_xpart, dim3(32, 64), dim3(64, 4), 0, stream, x, Wih0T, bih0, bhh0, xpart);

  hipLaunchKernelGGL(k_fused, dim3(256), dim3(1024), 0, stream,
                     xpart, Whh0, Wih1, Whh1, bih1, bhh1, WifT, bif,
                     h0g, h1g, h1_all, xi_all, linkg, rv_all, done, go, xiflag);

  hipLaunchKernelGGL(k_out, dim3(8, 64), dim3(64, 4), 0, stream, h1_all, WoutT, bout, out_all);

  hipLaunchKernelGGL(k_y, dim3(4, 64), dim3(64, 4), 0, stream, out_all, rv_all, WmemT, bmem, y);
}

// Round 12
// 3748.917 us; speedup vs baseline: 1.7629x; 1.0187x over previous
//
#include <hip/hip_runtime.h>
#include <math.h>

// DNC forward, fp32. Round 12: round-11 pipeline (XCD-isolated roles, relaxed
// barrier) with memchain softmax max-passes removed (exp direct — safe since
// |sim| <= ~22 << 88): -2 barriers, -5 butterfly sets per step.

#define BZ    16
#define TZ    64
#define HID   512
#define NCELL 256
#define CSZ   64
#define NRD   4
#define G4H   2048
#define IFC   471
#define DEL   1e-6f
#define SMT   257   // LDS mem^T row stride (odd -> conflict-free columns)
#define NLSTM 192

__device__ __forceinline__ float sig_(float x) { return 1.f / (1.f + expf(-x)); }
__device__ __forceinline__ float splus_(float x) { return fmaxf(x, 0.f) + log1pf(expf(-fabsf(x))); }

// relaxed-poll until *ptr >= tgt, then ONE acquire load (sync edge, 1 L2 inval)
template <int SLP>
__device__ __forceinline__ unsigned poll_acq(unsigned* ptr, unsigned tgt) {
  unsigned v;
  while ((v = __hip_atomic_load(ptr, __ATOMIC_RELAXED, __HIP_MEMORY_SCOPE_AGENT)) < tgt)
    __builtin_amdgcn_s_sleep(SLP);
  v = __hip_atomic_load(ptr, __ATOMIC_ACQUIRE, __HIP_MEMORY_SCOPE_AGENT);
  return v;
}

// ---------------------------------------------------------------- transpose
__global__ __launch_bounds__(256) void k_transpose(const float* __restrict__ src,
                                                   float* __restrict__ dst,
                                                   int rows, int cols, int kmax, int dst_stride) {
  __shared__ float tile[32][33];
  int c0 = blockIdx.x * 32, r0 = blockIdx.y * 32;
  int tx = threadIdx.x, ty = threadIdx.y;
  for (int i = ty; i < 32; i += 8) {
    int r = r0 + i, c = c0 + tx;
    tile[i][tx] = (r < rows && c < cols) ? src[(size_t)r * cols + c] : 0.f;
  }
  __syncthreads();
  for (int i = ty; i < 32; i += 8) {
    int c = c0 + i, r = r0 + tx;
    if (c < kmax && r < rows) dst[(size_t)c * dst_stride + r] = tile[tx][i];
  }
}

// ---------------------------------------------------------------- xpart GEMM
__global__ __launch_bounds__(256) void k_xpart(const float* __restrict__ x,
                                               const float* __restrict__ Wih0T,
                                               const float* __restrict__ bih0,
                                               const float* __restrict__ bhh0,
                                               float* __restrict__ xpart) {
  const int lane = threadIdx.x, ty = threadIdx.y;
  const int jg = blockIdx.x * 64 + lane;
  const int tb0 = blockIdx.y * 16;
  __shared__ float sx[16][256];
  const int tid = ty * 64 + lane;
  for (int idx = tid; idx < 16 * 256; idx += 256) {
    int row = idx >> 8, k = idx & 255;
    int tb = tb0 + row, tt = tb >> 4, bb = tb & 15;
    sx[row][k] = x[((size_t)bb * TZ + tt) * 256 + k];
  }
  __syncthreads();
  float acc[4] = {0.f, 0.f, 0.f, 0.f};
  for (int k = 0; k < 256; ++k) {
    float wv = Wih0T[(size_t)k * G4H + jg];
#pragma unroll
    for (int i = 0; i < 4; ++i) acc[i] = fmaf(wv, sx[ty * 4 + i][k], acc[i]);
  }
  float bias = bih0[jg] + bhh0[jg];
#pragma unroll
  for (int i = 0; i < 4; ++i)
    xpart[(size_t)(tb0 + ty * 4 + i) * G4H + jg] = acc[i] + bias;
}

// ---------------------------------------------------------------- grid barrier (LSTM blocks, by rank r)
__device__ __forceinline__ void gbar(unsigned* done, unsigned* go,
                                     unsigned tgt, int r, int tid) {
  __syncthreads();
  if (r == 0) {
    if (tid == 0)
      __hip_atomic_store(&done[0], tgt, __ATOMIC_RELEASE, __HIP_MEMORY_SCOPE_AGENT);
    if (tid < NLSTM) {
      while (__hip_atomic_load(&done[tid], __ATOMIC_RELAXED, __HIP_MEMORY_SCOPE_AGENT) < tgt)
        __builtin_amdgcn_s_sleep(4);
    }
    __syncthreads();
    if (tid == 0) {
      __builtin_amdgcn_fence(__ATOMIC_ACQUIRE, "agent");
      __hip_atomic_store(go, tgt, __ATOMIC_RELEASE, __HIP_MEMORY_SCOPE_AGENT);
    }
  } else {
    if (tid == 0) {
      __hip_atomic_store(&done[r], tgt, __ATOMIC_RELEASE, __HIP_MEMORY_SCOPE_AGENT);
      (void)poll_acq<4>(go, tgt);
    }
    __syncthreads();
  }
}

#define SCR(s, i) scr[(s) * 1320 + (i)]

// ---------------------------------------------------------------- fused persistent kernel
// Role map (XCD isolation; XCD = bid%8 heuristic — perf only, not correctness):
//   bid%8 >= 2            : LSTM rank r=(bid>>3)*6+(bid%8-2); r<64 cell0, else cell1
//   bid%8 < 2, bid < 128  : memchain batch g=(bid>>3)  if (g&1)==bid%8, else exit
//   bid%8 < 2, bid >= 128 : xi producer batch g=(bid>>3)&15 if (g&1)!=bid%8, else exit
__global__ __launch_bounds__(1024, 1) void k_fused(
    const float* __restrict__ xpart,
    const float* __restrict__ Whh0,
    const float* __restrict__ Wih1, const float* __restrict__ Whh1,
    const float* __restrict__ bih1, const float* __restrict__ bhh1,
    const float* __restrict__ WifT, const float* __restrict__ bif,
    float* __restrict__ h0g, float* __restrict__ h1g,
    float* __restrict__ h1_all, float* __restrict__ xi_all,
    float* __restrict__ linkg, float* __restrict__ rv_all,
    unsigned* __restrict__ done, unsigned* __restrict__ go,
    unsigned* __restrict__ xiflag) {
  const int tid = threadIdx.x;
  const int bid = blockIdx.x;
  const int res = bid & 7;
  const int gq = (bid >> 3) & 15;
  int role, idx = 0;
  if (res >= 2) {
    int r = (bid >> 3) * 6 + (res - 2);
    role = (r < 64) ? 0 : 1;
    idx = r;
  } else if (bid < 128) {
    if ((gq & 1) == res) { role = 3; idx = gq; } else { role = 4; }
  } else {
    if ((gq & 1) != res) { role = 2; idx = gq; } else { role = 4; }
  }
  if (role == 4) return;
  __shared__ __align__(16) float SMEM[37264];

  if (role == 0) {
    // ================= cell0 (rank idx in 0..63) =================
    float* w0 = SMEM;               // [32][524]
    float* hl = SMEM + 16768;       // [16][520]
    float* sc = hl + 8320;          // [8][512]
    float* xpl = sc + 4096;         // [512]
    float* c0l = xpl + 512;         // [128]
    const int rnk = idx;
    const int j0 = rnk * 8;
    for (int lr = 0; lr < 32; ++lr) {
      int g = lr >> 3, jj2 = lr & 7;
      const float* src = Whh0 + (size_t)(g * 512 + j0 + jj2) * 512;
      for (int k = tid; k < 512; k += 1024) w0[lr * 524 + k] = src[k];
    }
    if (tid < 128) c0l[tid] = 0.f;
    const int ks = tid & 7, bq = (tid >> 3) & 3, jj = tid >> 5;
    const int wr0 = (0 * 8 + (jj & 7)) * 524, wr1 = (1 * 8 + (jj & 7)) * 524,
              wr2 = (2 * 8 + (jj & 7)) * 524, wr3 = (3 * 8 + (jj & 7)) * 524;
    const int hb0 = (bq * 4 + 0) * 520, hb1 = (bq * 4 + 1) * 520,
              hb2 = (bq * 4 + 2) * 520, hb3 = (bq * 4 + 3) * 520;
    for (int ph = 0; ph < 65; ++ph) {
      if (ph < 64) {
        const int t = ph, po = t & 1, pn = po ^ 1;
        for (int q = tid; q < 2048; q += 1024) {
          int bb = q >> 7, kq = q & 127;
          ((float4*)&hl[bb * 520])[kq] = ((const float4*)&h0g[(size_t)(po * 16 + bb) * 512])[kq];
        }
        if (tid < 512) {
          int bb = tid >> 5, g = (tid >> 3) & 3, j2 = tid & 7;
          xpl[tid] = xpart[((size_t)t * 16 + bb) * G4H + g * 512 + j0 + j2];
        }
        __syncthreads();
        if (tid < 256) {
          float4 a0 = {0,0,0,0}, a1 = {0,0,0,0}, a2 = {0,0,0,0}, a3 = {0,0,0,0};
#pragma unroll 4
          for (int i = 0; i < 16; ++i) {
            const int off = ks * 4 + 32 * i;
            float4 w4a = *(const float4*)&w0[wr0 + off];
            float4 w4b = *(const float4*)&w0[wr1 + off];
            float4 w4c = *(const float4*)&w0[wr2 + off];
            float4 w4d = *(const float4*)&w0[wr3 + off];
            float4 h4a = *(const float4*)&hl[hb0 + off];
            float4 h4b = *(const float4*)&hl[hb1 + off];
            float4 h4c = *(const float4*)&hl[hb2 + off];
            float4 h4d = *(const float4*)&hl[hb3 + off];
            a0.x += w4a.x*h4a.x + w4a.y*h4a.y + w4a.z*h4a.z + w4a.w*h4a.w;
            a0.y += w4a.x*h4b.x + w4a.y*h4b.y + w4a.z*h4b.z + w4a.w*h4b.w;
            a0.z += w4a.x*h4c.x + w4a.y*h4c.y + w4a.z*h4c.z + w4a.w*h4c.w;
            a0.w += w4a.x*h4d.x + w4a.y*h4d.y + w4a.z*h4d.z + w4a.w*h4d.w;
            a1.x += w4b.x*h4a.x + w4b.y*h4a.y + w4b.z*h4a.z + w4b.w*h4a.w;
            a1.y += w4b.x*h4b.x + w4b.y*h4b.y + w4b.z*h4b.z + w4b.w*h4b.w;
            a1.z += w4b.x*h4c.x + w4b.y*h4c.y + w4b.z*h4c.z + w4b.w*h4c.w;
            a1.w += w4b.x*h4d.x + w4b.y*h4d.y + w4b.z*h4d.z + w4b.w*h4d.w;
            a2.x += w4c.x*h4a.x + w4c.y*h4a.y + w4c.z*h4a.z + w4c.w*h4a.w;
            a2.y += w4c.x*h4b.x + w4c.y*h4b.y + w4c.z*h4b.z + w4c.w*h4b.w;
            a2.z += w4c.x*h4c.x + w4c.y*h4c.y + w4c.z*h4c.z + w4c.w*h4c.w;
            a2.w += w4c.x*h4d.x + w4c.y*h4d.y + w4c.z*h4d.z + w4c.w*h4d.w;
            a3.x += w4d.x*h4a.x + w4d.y*h4a.y + w4d.z*h4a.z + w4d.w*h4a.w;
            a3.y += w4d.x*h4b.x + w4d.y*h4b.y + w4d.z*h4b.z + w4d.w*h4b.w;
            a3.z += w4d.x*h4c.x + w4d.y*h4c.y + w4d.z*h4c.z + w4d.w*h4c.w;
            a3.w += w4d.x*h4d.x + w4d.y*h4d.y + w4d.z*h4d.z + w4d.w*h4d.w;
          }
          *(float4*)&sc[ks * 512 + (0 * 8 + jj) * 16 + bq * 4] = a0;
          *(float4*)&sc[ks * 512 + (1 * 8 + jj) * 16 + bq * 4] = a1;
          *(float4*)&sc[ks * 512 + (2 * 8 + jj) * 16 + bq * 4] = a2;
          *(float4*)&sc[ks * 512 + (3 * 8 + jj) * 16 + bq * 4] = a3;
        }
        __syncthreads();
        if (tid < 128) {
          const int bb = tid >> 3, j2 = tid & 7;
          float gs[4];
#pragma unroll
          for (int g = 0; g < 4; ++g) {
            float s = 0.f;
#pragma unroll
            for (int k2 = 0; k2 < 8; ++k2) s += sc[k2 * 512 + (g * 8 + j2) * 16 + bb];
            gs[g] = s + xpl[bb * 32 + g * 8 + j2];
          }
          float gi = sig_(gs[0]), gf = sig_(gs[1]), gg = tanhf(gs[2]), go_ = sig_(gs[3]);
          float cc = gf * c0l[j2 * 16 + bb] + gi * gg;
          c0l[j2 * 16 + bb] = cc;
          h0g[(size_t)(pn * 16 + bb) * 512 + j0 + j2] = go_ * tanhf(cc);
        }
      }
      gbar(done, go, (unsigned)(ph + 1), rnk, tid);
    }
  } else if (role == 1) {
    // ================= cell1 (rank idx in 64..191) =================
    float* w1 = SMEM;               // [16][1028]
    float* h0l = SMEM + 16448;      // [16][520]
    float* h1l = h0l + 8320;        // [16][520]
    float* sc = h1l + 8320;         // [16][256]
    float* c1l = sc + 4096;         // [64]
    float* bl = c1l + 64;           // [16]
    const int rnk = idx;
    const int j0 = (rnk - 64) * 4;
    for (int lr = 0; lr < 16; ++lr) {
      int g = lr >> 2, jj2 = lr & 3;
      const float* si = Wih1 + (size_t)(g * 512 + j0 + jj2) * 512;
      const float* sh = Whh1 + (size_t)(g * 512 + j0 + jj2) * 512;
      for (int k = tid; k < 512; k += 1024) {
        w1[lr * 1028 + k] = si[k];
        w1[lr * 1028 + 512 + k] = sh[k];
      }
    }
    if (tid < 64) c1l[tid] = 0.f;
    if (tid < 16) {
      int g = tid >> 2, jj2 = tid & 3;
      bl[tid] = bih1[g * 512 + j0 + jj2] + bhh1[g * 512 + j0 + jj2];
    }
    const int ks = tid & 15, bq = (tid >> 4) & 3, jj = (tid >> 6) & 3;
    const int wr0 = (0 * 4 + jj) * 1028, wr1 = (1 * 4 + jj) * 1028,
              wr2 = (2 * 4 + jj) * 1028, wr3 = (3 * 4 + jj) * 1028;
    const int hb0 = (bq * 4 + 0) * 520, hb1 = (bq * 4 + 1) * 520,
              hb2 = (bq * 4 + 2) * 520, hb3 = (bq * 4 + 3) * 520;
    for (int ph = 0; ph < 65; ++ph) {
      if (ph >= 1) {
        const int t = ph - 1, po = t & 1, pn = po ^ 1;
        for (int q = tid; q < 2048; q += 1024) {
          int bb = q >> 7, kq = q & 127;
          ((float4*)&h0l[bb * 520])[kq] = ((const float4*)&h0g[(size_t)(pn * 16 + bb) * 512])[kq];
          ((float4*)&h1l[bb * 520])[kq] = ((const float4*)&h1g[(size_t)(po * 16 + bb) * 512])[kq];
        }
        __syncthreads();
        if (tid < 256) {
          float4 a0 = {0,0,0,0}, a1 = {0,0,0,0}, a2 = {0,0,0,0}, a3 = {0,0,0,0};
#pragma unroll 4
          for (int i = 0; i < 16; ++i) {
            const int offw = ks * 4 + 64 * i;
            const int offh = (i < 8) ? offw : (offw - 512);
            const float* hsrc = (i < 8) ? h0l : h1l;
            float4 w4a = *(const float4*)&w1[wr0 + offw];
            float4 w4b = *(const float4*)&w1[wr1 + offw];
            float4 w4c = *(const float4*)&w1[wr2 + offw];
            float4 w4d = *(const float4*)&w1[wr3 + offw];
            float4 h4a = *(const float4*)&hsrc[hb0 + offh];
            float4 h4b = *(const float4*)&hsrc[hb1 + offh];
            float4 h4c = *(const float4*)&hsrc[hb2 + offh];
            float4 h4d = *(const float4*)&hsrc[hb3 + offh];
            a0.x += w4a.x*h4a.x + w4a.y*h4a.y + w4a.z*h4a.z + w4a.w*h4a.w;
            a0.y += w4a.x*h4b.x + w4a.y*h4b.y + w4a.z*h4b.z + w4a.w*h4b.w;
            a0.z += w4a.x*h4c.x + w4a.y*h4c.y + w4a.z*h4c.z + w4a.w*h4c.w;
            a0.w += w4a.x*h4d.x + w4a.y*h4d.y + w4a.z*h4d.z + w4a.w*h4d.w;
            a1.x += w4b.x*h4a.x + w4b.y*h4a.y + w4b.z*h4a.z + w4b.w*h4a.w;
            a1.y += w4b.x*h4b.x + w4b.y*h4b.y + w4b.z*h4b.z + w4b.w*h4b.w;
            a1.z += w4b.x*h4c.x + w4b.y*h4c.y + w4b.z*h4c.z + w4b.w*h4c.w;
            a1.w += w4b.x*h4d.x + w4b.y*h4d.y + w4b.z*h4d.z + w4b.w*h4d.w;
            a2.x += w4c.x*h4a.x + w4c.y*h4a.y + w4c.z*h4a.z + w4c.w*h4a.w;
            a2.y += w4c.x*h4b.x + w4c.y*h4b.y + w4c.z*h4b.z + w4c.w*h4b.w;
            a2.z += w4c.x*h4c.x + w4c.y*h4c.y + w4c.z*h4c.z + w4c.w*h4c.w;
            a2.w += w4c.x*h4d.x + w4c.y*h4d.y + w4c.z*h4d.z + w4c.w*h4d.w;
            a3.x += w4d.x*h4a.x + w4d.y*h4a.y + w4d.z*h4a.z + w4d.w*h4a.w;
            a3.y += w4d.x*h4b.x + w4d.y*h4b.y + w4d.z*h4b.z + w4d.w*h4b.w;
            a3.z += w4d.x*h4c.x + w4d.y*h4c.y + w4d.z*h4c.z + w4d.w*h4c.w;
            a3.w += w4d.x*h4d.x + w4d.y*h4d.y + w4d.z*h4d.z + w4d.w*h4d.w;
          }
          *(float4*)&sc[ks * 256 + (0 * 4 + jj) * 16 + bq * 4] = a0;
          *(float4*)&sc[ks * 256 + (1 * 4 + jj) * 16 + bq * 4] = a1;
          *(float4*)&sc[ks * 256 + (2 * 4 + jj) * 16 + bq * 4] = a2;
          *(float4*)&sc[ks * 256 + (3 * 4 + jj) * 16 + bq * 4] = a3;
        }
        __syncthreads();
        if (tid < 64) {
          const int bb = tid >> 2, j2 = tid & 3;
          float gs[4];
#pragma unroll
          for (int g = 0; g < 4; ++g) {
            float s = 0.f;
#pragma unroll
            for (int k2 = 0; k2 < 16; ++k2) s += sc[k2 * 256 + (g * 4 + j2) * 16 + bb];
            gs[g] = s + bl[g * 4 + j2];
          }
          float gi = sig_(gs[0]), gf = sig_(gs[1]), gg = tanhf(gs[2]), go_ = sig_(gs[3]);
          float cc = gf * c1l[j2 * 16 + bb] + gi * gg;
          c1l[j2 * 16 + bb] = cc;
          float hv = go_ * tanhf(cc);
          h1g[(size_t)(pn * 16 + bb) * 512 + j0 + j2] = hv;
          h1_all[((size_t)t * 16 + bb) * 512 + j0 + j2] = hv;
        }
      }
      gbar(done, go, (unsigned)(ph + 1), rnk, tid);
    }
  } else if (role == 2) {
    // ================= xi producer (one per batch), 4-step chunks =================
    const int b = idx;
    float* sh1 = SMEM;        // [512]
    float* sxo = SMEM + 512;  // [2][512]
    __shared__ unsigned sgo;
    unsigned seen_go = 0;
    for (int tc = 0; tc < TZ / 4; ++tc) {
      const unsigned need = (unsigned)(4 * tc + 5);  // h1(4tc+3) visible at go >= 4tc+5
      if (tid == 0 && seen_go < need) {
        sgo = poll_acq<8>(go, need);
      }
      __syncthreads();
      if (seen_go < need) seen_go = sgo;
      for (int k4 = 0; k4 < 4; ++k4) {
        const int t = 4 * tc + k4;
        if (tid < 512) sh1[tid] = h1_all[((size_t)t * BZ + b) * HID + tid];
        __syncthreads();
        {
          const int u = tid & 511, half = tid >> 9;
          if (u < IFC) {
            const float* wc = WifT + u;
            const int k0 = half * 256;
            float acc = 0.f;
#pragma unroll 8
            for (int k = k0; k < k0 + 256; ++k)
              acc = fmaf(sh1[k], wc[(size_t)k * 512], acc);
            sxo[half * 512 + u] = acc;
          }
        }
        __syncthreads();
        if (tid < IFC)
          xi_all[((size_t)t * BZ + b) * 512 + tid] = sxo[tid] + sxo[512 + tid] + bif[tid];
        __syncthreads();
      }
      if (tid == 0)
        __hip_atomic_store(&xiflag[b], (unsigned)(4 * tc + 4), __ATOMIC_RELEASE, __HIP_MEMORY_SCOPE_AGENT);
    }
  } else {
    // ================= memory-module chain (one per batch) =================
    const int b = idx;
    const int lane = tid & 63;
    const int wv = tid >> 6;
    const int m8 = tid & 255;
    const int seg = tid >> 8;
    float* LNK = linkg + (size_t)b * (NCELL * NCELL);

    float* smemT = SMEM;               // 16448
    float* sxi   = smemT + 16448;      // 472
    float* srkn  = sxi + 472;          // 256 [4][64]
    float* swkn  = srkn + 256;         // 64
    float* sev   = swkn + 64;          // 64
    float* swvv  = sev + 64;           // 64
    float* sscal = swvv + 64;          // 40
    float* srw   = sscal + 40;         // 1024 [4][256]
    float* sww   = srw + 1024;         // 256
    float* susage = sww + 256;         // 256
    float* sprec = susage + 256;       // 256
    float* ssim  = sprec + 256;        // 1024 [4][256]
    float* sfwd  = ssim + 1024;        // 1024 [4][256]
    float* sbwd  = sfwd + 1024;        // 1056 [4][264]
    float* sa    = sbwd + 1056;        // 256
    float* sc_   = sa + 256;           // 256
    float* sb_   = sc_ + 256;          // 256
    int*   srank = (int*)(sb_ + 256);  // 256
    float* scr   = (float*)(srank + 256); // 5280 [4][1320]
    float* sred2 = scr + 5280;         // 64
    __shared__ unsigned sflag;

    for (int i = tid; i < CSZ * SMT; i += 1024) smemT[i] = 0.f;
    if (tid < 256) {
      sww[tid] = 0.f; susage[tid] = 0.f; sprec[tid] = 0.f;
      srw[tid] = 0.f; srw[256 + tid] = 0.f; srw[512 + tid] = 0.f; srw[768 + tid] = 0.f;
    }
    for (int i = tid; i < (NCELL * NCELL) / 4; i += 1024)
      ((float4*)LNK)[i] = make_float4(0.f, 0.f, 0.f, 0.f);
    __syncthreads();

    unsigned seen = 0;
    for (int t = 0; t < TZ; ++t) {
      if (tid == 0 && seen < (unsigned)(t + 1)) {
        sflag = poll_acq<8>(&xiflag[b], (unsigned)(t + 1));
      }
      __syncthreads();
      if (seen < (unsigned)(t + 1)) seen = sflag;

      // ---- P0: load + parse xi ----
      if (tid < IFC) sxi[tid] = xi_all[((size_t)t * BZ + b) * 512 + tid];
      __syncthreads();
      if (wv < 4) {
        float v = tanhf(sxi[wv * 64 + lane]);
        float s2 = v * v;
#pragma unroll
        for (int off = 32; off; off >>= 1) s2 += __shfl_xor(s2, off);
        srkn[wv * 64 + lane] = v / (sqrtf(s2) + DEL);
      } else if (wv == 4) {
        float v = tanhf(sxi[260 + lane]);
        float s2 = v * v;
#pragma unroll
        for (int off = 32; off; off >>= 1) s2 += __shfl_xor(s2, off);
        swkn[lane] = v / (sqrtf(s2) + DEL);
      } else if (wv == 5) {
        sev[lane] = sig_(sxi[325 + lane]);
      } else if (wv == 6) {
        swvv[lane] = tanhf(sxi[389 + lane]);
      } else if (wv == 7) {
        if (lane < 4) sscal[lane] = splus_(sxi[256 + lane]);
        if (lane == 4) sscal[4] = splus_(sxi[324]);
        if (lane >= 8 && lane < 12) sscal[lane] = sig_(sxi[453 + (lane - 8)]);
        if (lane == 12) sscal[12] = sig_(sxi[457]);
        if (lane == 13) sscal[13] = sig_(sxi[458]);
        if (lane >= 16 && lane < 20) {
          int r = lane - 16;
          float a = sxi[459 + r * 3], b2 = sxi[460 + r * 3], c2 = sxi[461 + r * 3];
          float mx3 = fmaxf(a, fmaxf(b2, c2));
          float ea = expf(a - mx3), eb = expf(b2 - mx3), ec = expf(c2 - mx3);
          float iv = 1.f / (ea + eb + ec);
          sscal[20 + r * 3 + 0] = ea * iv;
          sscal[20 + r * 3 + 1] = eb * iv;
          sscal[20 + r * 3 + 2] = ec * iv;
        }
      }
      __syncthreads();

      // ---- P1: usage update + write-content dot (old mem); direct-exp softmax ----
      float un_r = 0.f;
      if (tid < 256) {
        float wwo = sww[tid], uo = susage[tid];
        float u1 = uo + (1.f - uo) * wwo;
        float psi = 1.f;
#pragma unroll
        for (int r = 0; r < 4; ++r) psi *= 1.f - sscal[8 + r] * srw[r * 256 + tid];
        un_r = u1 * psi;
        susage[tid] = un_r;
      }
      {
        float dot = 0.f, nn = 0.f;
#pragma unroll 4
        for (int w = seg * 16; w < seg * 16 + 16; ++w) {
          float mv = smemT[w * SMT + m8];
          dot = fmaf(mv, swkn[w], dot);
          nn = fmaf(mv, mv, nn);
        }
        SCR(seg, 0 * 264 + m8) = dot;
        SCR(seg, 1 * 264 + m8) = nn;
      }
      __syncthreads();
      float e_r = 0.f;
      if (tid < 256) {
        float dot = SCR(0, tid) + SCR(1, tid) + SCR(2, tid) + SCR(3, tid);
        float nn = SCR(0, 264 + tid) + SCR(1, 264 + tid) + SCR(2, 264 + tid) + SCR(3, 264 + tid);
        float simv = sscal[4] * dot / (sqrtf(nn) + DEL);
        e_r = expf(simv);   // |simv| <= ~22 -> no overflow; softmax ratio unchanged
        float s = e_r;
#pragma unroll
        for (int off = 32; off; off >>= 1) s += __shfl_xor(s, off);
        if (lane == 0) sred2[8 + wv] = s;
      }
      __syncthreads();
      float wcw_r = 0.f;
      if (tid < 256) {
        float sm = sred2[8] + sred2[9] + sred2[10] + sred2[11];
        wcw_r = e_r / sm;
        sa[tid] = DEL + (1.f - DEL) * un_r;
      }
      __syncthreads();

      // ---- P2: allocation (stable rank + exclusive cumprod) ----
      {
        float um = sa[m8];
        int cnt = 0;
        for (int j2 = seg * 64; j2 < seg * 64 + 64; ++j2) {
          float uj = sa[j2];
          cnt += (uj < um || (uj == um && j2 < m8)) ? 1 : 0;
        }
        ((int*)&SCR(seg, 0))[m8] = cnt;
      }
      __syncthreads();
      if (tid < 256) {
        int rank = ((int*)&SCR(0, 0))[tid] + ((int*)&SCR(1, 0))[tid] +
                   ((int*)&SCR(2, 0))[tid] + ((int*)&SCR(3, 0))[tid];
        srank[tid] = rank;
        sb_[rank] = sa[tid];
      }
      __syncthreads();
      float inc = 0.f;
      if (tid < 256) {
        inc = sb_[tid];
#pragma unroll
        for (int off = 1; off < 64; off <<= 1) {
          float pp = __shfl_up(inc, off);
          if (lane >= off) inc *= pp;
        }
        if (lane == 63) sred2[16 + wv] = inc;
      }
      __syncthreads();
      if (tid < 256) {
        float pref = 1.f;
        for (int w2 = 0; w2 < wv; ++w2) pref *= sred2[16 + w2];
        float excl = __shfl_up(inc, 1);
        if (lane == 0) excl = 1.f;
        sc_[tid] = excl * pref;
      }
      __syncthreads();

      // ---- P3: write weighting + wsum ----
      if (tid < 256) {
        float alo = (1.f - sa[tid]) * sc_[srank[tid]];
        float wwn = sscal[13] * (sscal[12] * alo + (1.f - sscal[12]) * wcw_r);
        sww[tid] = wwn;
        float s = wwn;
#pragma unroll
        for (int off = 32; off; off >>= 1) s += __shfl_xor(s, off);
        if (lane == 0) sred2[24 + wv] = s;
      }
      __syncthreads();
      if (tid == 0) sscal[14] = sred2[24] + sred2[25] + sred2[26] + sred2[27];

      // ---- P4: memory erase/write + read-content sims; direct-exp softmax ----
      {
        float wm = sww[m8];
        float nn = 0.f, d0 = 0.f, d1 = 0.f, d2 = 0.f, d3 = 0.f;
#pragma unroll 4
        for (int w = seg * 16; w < seg * 16 + 16; ++w) {
          float v = smemT[w * SMT + m8];
          v = v * (1.f - wm * sev[w]) + wm * swvv[w];
          smemT[w * SMT + m8] = v;
          nn = fmaf(v, v, nn);
          d0 = fmaf(v, srkn[0 * 64 + w], d0);
          d1 = fmaf(v, srkn[1 * 64 + w], d1);
          d2 = fmaf(v, srkn[2 * 64 + w], d2);
          d3 = fmaf(v, srkn[3 * 64 + w], d3);
        }
        SCR(seg, 0 * 264 + m8) = nn;
        SCR(seg, 1 * 264 + m8) = d0;
        SCR(seg, 2 * 264 + m8) = d1;
        SCR(seg, 3 * 264 + m8) = d2;
        SCR(seg, 4 * 264 + m8) = d3;
      }
      for (int i = tid; i < NRD * 264; i += 1024) sbwd[i] = 0.f;
      __syncthreads();
      float e0 = 0.f, e1 = 0.f, e2 = 0.f, e3 = 0.f;
      if (tid < 256) {
        float nn = SCR(0, tid) + SCR(1, tid) + SCR(2, tid) + SCR(3, tid);
        float invn = 1.f / (sqrtf(nn) + DEL);
        float sv0 = sscal[0] * (SCR(0, 264 + tid) + SCR(1, 264 + tid) + SCR(2, 264 + tid) + SCR(3, 264 + tid)) * invn;
        float sv1 = sscal[1] * (SCR(0, 528 + tid) + SCR(1, 528 + tid) + SCR(2, 528 + tid) + SCR(3, 528 + tid)) * invn;
        float sv2 = sscal[2] * (SCR(0, 792 + tid) + SCR(1, 792 + tid) + SCR(2, 792 + tid) + SCR(3, 792 + tid)) * invn;
        float sv3 = sscal[3] * (SCR(0, 1056 + tid) + SCR(1, 1056 + tid) + SCR(2, 1056 + tid) + SCR(3, 1056 + tid)) * invn;
        e0 = expf(sv0); e1 = expf(sv1); e2 = expf(sv2); e3 = expf(sv3);
        float s0 = e0, s1 = e1, s2 = e2, s3 = e3;
#pragma unroll
        for (int off = 32; off; off >>= 1) {
          s0 += __shfl_xor(s0, off); s1 += __shfl_xor(s1, off);
          s2 += __shfl_xor(s2, off); s3 += __shfl_xor(s3, off);
        }
        if (lane == 0) {
          sred2[32 + wv * 4 + 0] = s0; sred2[32 + wv * 4 + 1] = s1;
          sred2[32 + wv * 4 + 2] = s2; sred2[32 + wv * 4 + 3] = s3;
        }
      }
      __syncthreads();
      if (tid < 256) {
        float s0 = sred2[32] + sred2[36] + sred2[40] + sred2[44];
        float s1 = sred2[33] + sred2[37] + sred2[41] + sred2[45];
        float s2 = sred2[34] + sred2[38] + sred2[42] + sred2[46];
        float s3 = sred2[35] + sred2[39] + sred2[43] + sred2[47];
        ssim[0 * 256 + tid] = e0 / s0; ssim[1 * 256 + tid] = e1 / s1;
        ssim[2 * 256 + tid] = e2 / s2; ssim[3 * 256 + tid] = e3 / s3;
      }

      // ---- P5: link update + fwd + bwd, coalesced row-per-wave pass ----
      {
        const float4 r0 = ((const float4*)(srw + 0 * 256))[lane];
        const float4 r1 = ((const float4*)(srw + 1 * 256))[lane];
        const float4 r2 = ((const float4*)(srw + 2 * 256))[lane];
        const float4 r3 = ((const float4*)(srw + 3 * 256))[lane];
        const float4 wc = ((const float4*)sww)[lane];
        const float4 pc = ((const float4*)sprec)[lane];
        const int n0 = lane * 4;
        float4 bp0 = {0,0,0,0}, bp1 = {0,0,0,0}, bp2 = {0,0,0,0}, bp3 = {0,0,0,0};
        for (int rr = 0; rr < 16; ++rr) {
          const int m = wv * 16 + rr;
          const float wm = sww[m];
          float4 lv = ((float4*)(LNK + (size_t)m * 256))[lane];
          lv.x = (1.f - wm - wc.x) * lv.x + wm * pc.x;
          lv.y = (1.f - wm - wc.y) * lv.y + wm * pc.y;
          lv.z = (1.f - wm - wc.z) * lv.z + wm * pc.z;
          lv.w = (1.f - wm - wc.w) * lv.w + wm * pc.w;
          if (m == n0 + 0) lv.x = 0.f;
          if (m == n0 + 1) lv.y = 0.f;
          if (m == n0 + 2) lv.z = 0.f;
          if (m == n0 + 3) lv.w = 0.f;
          ((float4*)(LNK + (size_t)m * 256))[lane] = lv;
          float f0 = lv.x * r0.x + lv.y * r0.y + lv.z * r0.z + lv.w * r0.w;
          float f1 = lv.x * r1.x + lv.y * r1.y + lv.z * r1.z + lv.w * r1.w;
          float f2 = lv.x * r2.x + lv.y * r2.y + lv.z * r2.z + lv.w * r2.w;
          float f3 = lv.x * r3.x + lv.y * r3.y + lv.z * r3.z + lv.w * r3.w;
#pragma unroll
          for (int off = 32; off; off >>= 1) {
            f0 += __shfl_xor(f0, off); f1 += __shfl_xor(f1, off);
            f2 += __shfl_xor(f2, off); f3 += __shfl_xor(f3, off);
          }
          if (lane == 0) {
            sfwd[0 * 256 + m] = f0; sfwd[1 * 256 + m] = f1;
            sfwd[2 * 256 + m] = f2; sfwd[3 * 256 + m] = f3;
          }
          const float s0 = srw[0 * 256 + m], s1 = srw[1 * 256 + m],
                      s2 = srw[2 * 256 + m], s3 = srw[3 * 256 + m];
          bp0.x = fmaf(lv.x, s0, bp0.x); bp0.y = fmaf(lv.y, s0, bp0.y);
          bp0.z = fmaf(lv.z, s0, bp0.z); bp0.w = fmaf(lv.w, s0, bp0.w);
          bp1.x = fmaf(lv.x, s1, bp1.x); bp1.y = fmaf(lv.y, s1, bp1.y);
          bp1.z = fmaf(lv.z, s1, bp1.z); bp1.w = fmaf(lv.w, s1, bp1.w);
          bp2.x = fmaf(lv.x, s2, bp2.x); bp2.y = fmaf(lv.y, s2, bp2.y);
          bp2.z = fmaf(lv.z, s2, bp2.z); bp2.w = fmaf(lv.w, s2, bp2.w);
          bp3.x = fmaf(lv.x, s3, bp3.x); bp3.y = fmaf(lv.y, s3, bp3.y);
          bp3.z = fmaf(lv.z, s3, bp3.z); bp3.w = fmaf(lv.w, s3, bp3.w);
        }
        atomicAdd(&sbwd[0 * 264 + n0 + 0], bp0.x); atomicAdd(&sbwd[0 * 264 + n0 + 1], bp0.y);
        atomicAdd(&sbwd[0 * 264 + n0 + 2], bp0.z); atomicAdd(&sbwd[0 * 264 + n0 + 3], bp0.w);
        atomicAdd(&sbwd[1 * 264 + n0 + 0], bp1.x); atomicAdd(&sbwd[1 * 264 + n0 + 1], bp1.y);
        atomicAdd(&sbwd[1 * 264 + n0 + 2], bp1.z); atomicAdd(&sbwd[1 * 264 + n0 + 3], bp1.w);
        atomicAdd(&sbwd[2 * 264 + n0 + 0], bp2.x); atomicAdd(&sbwd[2 * 264 + n0 + 1], bp2.y);
        atomicAdd(&sbwd[2 * 264 + n0 + 2], bp2.z); atomicAdd(&sbwd[2 * 264 + n0 + 3], bp2.w);
        atomicAdd(&sbwd[3 * 264 + n0 + 0], bp3.x); atomicAdd(&sbwd[3 * 264 + n0 + 1], bp3.y);
        atomicAdd(&sbwd[3 * 264 + n0 + 2], bp3.z); atomicAdd(&sbwd[3 * 264 + n0 + 3], bp3.w);
      }
      __syncthreads();

      // ---- P7: rw update + precedence ----
      if (tid < 256) {
#pragma unroll
        for (int r = 0; r < 4; ++r) {
          float rwn = sscal[20 + r * 3 + 0] * sbwd[r * 264 + tid] +
                      sscal[20 + r * 3 + 1] * sfwd[r * 256 + tid] +
                      sscal[20 + r * 3 + 2] * ssim[r * 256 + tid];
          srw[r * 256 + tid] = rwn;
        }
        sprec[tid] = (1.f - sscal[14]) * sprec[tid] + sww[tid];
      }
      __syncthreads();

      // ---- P8: read vectors ----
      {
        const int r = tid >> 8, sg = (tid >> 6) & 3, w = lane;
        float acc = 0.f;
#pragma unroll 4
        for (int m2 = sg * 64; m2 < sg * 64 + 64; ++m2)
          acc = fmaf(srw[r * 256 + m2], smemT[w * SMT + m2], acc);
        SCR(sg, r * 64 + w) = acc;
      }
      __syncthreads();
      if (tid < 256)
        rv_all[((size_t)t * BZ + b) * 256 + tid] =
            SCR(0, tid) + SCR(1, tid) + SCR(2, tid) + SCR(3, tid);
      __syncthreads();
    }
  }
}

// ---------------------------------------------------------------- out GEMM
__global__ __launch_bounds__(256) void k_out(const float* __restrict__ h1_all,
                                             const float* __restrict__ WoutT,
                                             const float* __restrict__ bout,
                                             float* __restrict__ out_all) {
  const int lane = threadIdx.x, ty = threadIdx.y;
  const int u = blockIdx.x * 64 + lane;
  const int row0 = blockIdx.y * 16;
  __shared__ float sh[16][512];
  const int tid = ty * 64 + lane;
  for (int idx = tid; idx < 16 * 512; idx += 256) {
    int r2 = idx >> 9, k = idx & 511;
    sh[r2][k] = h1_all[(size_t)(row0 + r2) * 512 + k];
  }
  __syncthreads();
  const float* wcol = WoutT + u;
  float bias = bout[u];
  float acc[4] = {0.f, 0.f, 0.f, 0.f};
  for (int k = 0; k < 512; ++k) {
    float wv = wcol[(size_t)k * 512];
#pragma unroll
    for (int i = 0; i < 4; ++i) acc[i] = fmaf(wv, sh[ty * 4 + i][k], acc[i]);
  }
#pragma unroll
  for (int i = 0; i < 4; ++i)
    out_all[(size_t)(row0 + ty * 4 + i) * 512 + u] = acc[i] + bias;
}

// ---------------------------------------------------------------- final y GEMM
__global__ __launch_bounds__(256) void k_y(const float* __restrict__ out_all,
                                           const float* __restrict__ rv_all,
                                           const float* __restrict__ WmemT,
                                           const float* __restrict__ bmem,
                                           float* __restrict__ y) {
  const int lane = threadIdx.x, ty = threadIdx.y;
  const int o = blockIdx.x * 64 + lane;
  const int tb0 = blockIdx.y * 16;
  __shared__ float sin_[16][768];
  const int tid = ty * 64 + lane;
  for (int idx = tid; idx < 16 * 768; idx += 256) {
    int row = idx / 768, k = idx % 768;
    int tb = tb0 + row;
    sin_[row][k] = (k < 512) ? out_all[(size_t)tb * HID + k]
                             : rv_all[(size_t)tb * 256 + (k - 512)];
  }
  __syncthreads();
  float acc[4] = {0.f, 0.f, 0.f, 0.f};
  for (int k = 0; k < 768; ++k) {
    float wv = WmemT[(size_t)k * 256 + o];
#pragma unroll
    for (int i = 0; i < 4; ++i) acc[i] = fmaf(wv, sin_[ty * 4 + i][k], acc[i]);
  }
  float bo = bmem[o];
#pragma unroll
  for (int i = 0; i < 4; ++i) {
    int tb = tb0 + ty * 4 + i;
    int tt = tb >> 4, bb = tb & 15;
    y[((size_t)bb * TZ + tt) * 256 + o] = acc[i] + bo;
  }
}

extern "C" void kernel_launch(void* const* d_in, const int* in_sizes, int n_in,
                              void* d_out, int out_size, void* d_ws, size_t ws_size,
                              hipStream_t stream) {
  (void)in_sizes; (void)n_in; (void)out_size; (void)ws_size;
  const float* x    = (const float*)d_in[0];
  const float* Wih0 = (const float*)d_in[1];
  const float* bih0 = (const float*)d_in[2];
  const float* Whh0 = (const float*)d_in[3];
  const float* bhh0 = (const float*)d_in[4];
  const float* Wih1 = (const float*)d_in[5];
  const float* bih1 = (const float*)d_in[6];
  const float* Whh1 = (const float*)d_in[7];
  const float* bhh1 = (const float*)d_in[8];
  const float* Wout = (const float*)d_in[9];
  const float* bout = (const float*)d_in[10];
  const float* Wif  = (const float*)d_in[11];
  const float* bif  = (const float*)d_in[12];
  const float* Wmem = (const float*)d_in[13];
  const float* bmem = (const float*)d_in[14];
  float* y = (float*)d_out;

  float* p = (float*)d_ws;
  auto take = [&](size_t n) { float* q = p; p += n; return q; };
  float* Wih0T   = take((size_t)256 * 2048);
  float* WoutT   = take((size_t)512 * 512);
  float* WifT    = take((size_t)512 * 512);
  float* WmemT   = take((size_t)768 * 256);
  float* xpart   = take((size_t)TZ * BZ * G4H);
  float* h1_all  = take((size_t)TZ * BZ * HID);
  float* out_all = take((size_t)TZ * BZ * HID);
  float* xi_all  = take((size_t)TZ * BZ * 512);
  float* rv_all  = take((size_t)TZ * BZ * 256);
  float* linkg   = take((size_t)BZ * NCELL * NCELL);
  float* zstart  = p;
  float* h0g     = take((size_t)2 * BZ * HID);
  float* h1g     = take((size_t)2 * BZ * HID);
  float* cntf    = take((size_t)512);
  size_t zbytes = (size_t)((char*)p - (char*)zstart);
  unsigned* done   = (unsigned*)cntf;        // [0..191] by LSTM rank
  unsigned* go     = done + 256;             // [1]
  unsigned* xiflag = done + 320;             // [16]

  (void)hipMemsetAsync(zstart, 0, zbytes, stream);

  dim3 tb32(32, 8);
  hipLaunchKernelGGL(k_transpose, dim3(8, 64), tb32, 0, stream, Wih0, Wih0T, 2048, 512, 256, 2048);
  hipLaunchKernelGGL(k_transpose, dim3(16, 16), tb32, 0, stream, Wout, WoutT, 512, 512, 512, 512);
  hipLaunchKernelGGL(k_transpose, dim3(16, 15), tb32, 0, stream, Wif, WifT, 471, 512, 512, 512);
  hipLaunchKernelGGL(k_transpose, dim3(24, 8), tb32, 0, stream, Wmem, WmemT, 256, 768, 768, 256);

  hipLaunchKernelGGL(k_xpart, dim3(32, 64), dim3(64, 4), 0, stream, x, Wih0T, bih0, bhh0, xpart);

  hipLaunchKernelGGL(k_fused, dim3(256), dim3(1024), 0, stream,
                     xpart, Whh0, Wih1, Whh1, bih1, bhh1, WifT, bif,
                     h0g, h1g, h1_all, xi_all, linkg, rv_all, done, go, xiflag);

  hipLaunchKernelGGL(k_out, dim3(8, 64), dim3(64, 4), 0, stream, h1_all, WoutT, bout, out_all);

  hipLaunchKernelGGL(k_y, dim3(4, 64), dim3(64, 4), 0, stream, out_all, rv_all, WmemT, bmem, y);
}

// Round 13
// 3745.413 us; speedup vs baseline: 1.7645x; 1.0009x over previous
//
#include <hip/hip_runtime.h>
#include <math.h>

// DNC forward, fp32. Round 12: round-11 pipeline (XCD-isolated roles, relaxed
// barrier) with memchain softmax max-passes removed (exp direct — safe since
// |sim| <= ~22 << 88): -2 barriers, -5 butterfly sets per step.

#define BZ    16
#define TZ    64
#define HID   512
#define NCELL 256
#define CSZ   64
#define NRD   4
#define G4H   2048
#define IFC   471
#define DEL   1e-6f
#define SMT   257   // LDS mem^T row stride (odd -> conflict-free columns)
#define NLSTM 192

__device__ __forceinline__ float sig_(float x) { return 1.f / (1.f + expf(-x)); }
__device__ __forceinline__ float splus_(float x) { return fmaxf(x, 0.f) + log1pf(expf(-fabsf(x))); }

// relaxed-poll until *ptr >= tgt, then ONE acquire load (sync edge, 1 L2 inval)
template <int SLP>
__device__ __forceinline__ unsigned poll_acq(unsigned* ptr, unsigned tgt) {
  unsigned v;
  while ((v = __hip_atomic_load(ptr, __ATOMIC_RELAXED, __HIP_MEMORY_SCOPE_AGENT)) < tgt)
    __builtin_amdgcn_s_sleep(SLP);
  v = __hip_atomic_load(ptr, __ATOMIC_ACQUIRE, __HIP_MEMORY_SCOPE_AGENT);
  return v;
}

// ---------------------------------------------------------------- transpose
__global__ __launch_bounds__(256) void k_transpose(const float* __restrict__ src,
                                                   float* __restrict__ dst,
                                                   int rows, int cols, int kmax, int dst_stride) {
  __shared__ float tile[32][33];
  int c0 = blockIdx.x * 32, r0 = blockIdx.y * 32;
  int tx = threadIdx.x, ty = threadIdx.y;
  for (int i = ty; i < 32; i += 8) {
    int r = r0 + i, c = c0 + tx;
    tile[i][tx] = (r < rows && c < cols) ? src[(size_t)r * cols + c] : 0.f;
  }
  __syncthreads();
  for (int i = ty; i < 32; i += 8) {
    int c = c0 + i, r = r0 + tx;
    if (c < kmax && r < rows) dst[(size_t)c * dst_stride + r] = tile[tx][i];
  }
}

// ---------------------------------------------------------------- xpart GEMM
__global__ __launch_bounds__(256) void k_xpart(const float* __restrict__ x,
                                               const float* __restrict__ Wih0T,
                                               const float* __restrict__ bih0,
                                               const float* __restrict__ bhh0,
                                               float* __restrict__ xpart) {
  const int lane = threadIdx.x, ty = threadIdx.y;
  const int jg = blockIdx.x * 64 + lane;
  const int tb0 = blockIdx.y * 16;
  __shared__ float sx[16][256];
  const int tid = ty * 64 + lane;
  for (int idx = tid; idx < 16 * 256; idx += 256) {
    int row = idx >> 8, k = idx & 255;
    int tb = tb0 + row, tt = tb >> 4, bb = tb & 15;
    sx[row][k] = x[((size_t)bb * TZ + tt) * 256 + k];
  }
  __syncthreads();
  float acc[4] = {0.f, 0.f, 0.f, 0.f};
  for (int k = 0; k < 256; ++k) {
    float wv = Wih0T[(size_t)k * G4H + jg];
#pragma unroll
    for (int i = 0; i < 4; ++i) acc[i] = fmaf(wv, sx[ty * 4 + i][k], acc[i]);
  }
  float bias = bih0[jg] + bhh0[jg];
#pragma unroll
  for (int i = 0; i < 4; ++i)
    xpart[(size_t)(tb0 + ty * 4 + i) * G4H + jg] = acc[i] + bias;
}

// ---------------------------------------------------------------- grid barrier (LSTM blocks, by rank r)
__device__ __forceinline__ void gbar(unsigned* done, unsigned* go,
                                     unsigned tgt, int r, int tid) {
  __syncthreads();
  if (r == 0) {
    if (tid == 0)
      __hip_atomic_store(&done[0], tgt, __ATOMIC_RELEASE, __HIP_MEMORY_SCOPE_AGENT);
    if (tid < NLSTM) {
      while (__hip_atomic_load(&done[tid], __ATOMIC_RELAXED, __HIP_MEMORY_SCOPE_AGENT) < tgt)
        __builtin_amdgcn_s_sleep(4);
    }
    __syncthreads();
    if (tid == 0) {
      __builtin_amdgcn_fence(__ATOMIC_ACQUIRE, "agent");
      __hip_atomic_store(go, tgt, __ATOMIC_RELEASE, __HIP_MEMORY_SCOPE_AGENT);
    }
  } else {
    if (tid == 0) {
      __hip_atomic_store(&done[r], tgt, __ATOMIC_RELEASE, __HIP_MEMORY_SCOPE_AGENT);
      (void)poll_acq<4>(go, tgt);
    }
    __syncthreads();
  }
}

#define SCR(s, i) scr[(s) * 1320 + (i)]

// ---------------------------------------------------------------- fused persistent kernel
// Role map (XCD isolation; XCD = bid%8 heuristic — perf only, not correctness):
//   bid%8 >= 2            : LSTM rank r=(bid>>3)*6+(bid%8-2); r<64 cell0, else cell1
//   bid%8 < 2, bid < 128  : memchain batch g=(bid>>3)  if (g&1)==bid%8, else exit
//   bid%8 < 2, bid >= 128 : xi producer batch g=(bid>>3)&15 if (g&1)!=bid%8, else exit
__global__ __launch_bounds__(1024, 1) void k_fused(
    const float* __restrict__ xpart,
    const float* __restrict__ Whh0,
    const float* __restrict__ Wih1, const float* __restrict__ Whh1,
    const float* __restrict__ bih1, const float* __restrict__ bhh1,
    const float* __restrict__ WifT, const float* __restrict__ bif,
    float* __restrict__ h0g, float* __restrict__ h1g,
    float* __restrict__ h1_all, float* __restrict__ xi_all,
    float* __restrict__ linkg, float* __restrict__ rv_all,
    unsigned* __restrict__ done, unsigned* __restrict__ go,
    unsigned* __restrict__ xiflag) {
  const int tid = threadIdx.x;
  const int bid = blockIdx.x;
  const int res = bid & 7;
  const int gq = (bid >> 3) & 15;
  int role, idx = 0;
  if (res >= 2) {
    int r = (bid >> 3) * 6 + (res - 2);
    role = (r < 64) ? 0 : 1;
    idx = r;
  } else if (bid < 128) {
    if ((gq & 1) == res) { role = 3; idx = gq; } else { role = 4; }
  } else {
    if ((gq & 1) != res) { role = 2; idx = gq; } else { role = 4; }
  }
  if (role == 4) return;
  __shared__ __align__(16) float SMEM[37264];

  if (role == 0) {
    // ================= cell0 (rank idx in 0..63) =================
    float* w0 = SMEM;               // [32][524]
    float* hl = SMEM + 16768;       // [16][520]
    float* sc = hl + 8320;          // [8][512]
    float* xpl = sc + 4096;         // [512]
    float* c0l = xpl + 512;         // [128]
    const int rnk = idx;
    const int j0 = rnk * 8;
    for (int lr = 0; lr < 32; ++lr) {
      int g = lr >> 3, jj2 = lr & 7;
      const float* src = Whh0 + (size_t)(g * 512 + j0 + jj2) * 512;
      for (int k = tid; k < 512; k += 1024) w0[lr * 524 + k] = src[k];
    }
    if (tid < 128) c0l[tid] = 0.f;
    const int ks = tid & 7, bq = (tid >> 3) & 3, jj = tid >> 5;
    const int wr0 = (0 * 8 + (jj & 7)) * 524, wr1 = (1 * 8 + (jj & 7)) * 524,
              wr2 = (2 * 8 + (jj & 7)) * 524, wr3 = (3 * 8 + (jj & 7)) * 524;
    const int hb0 = (bq * 4 + 0) * 520, hb1 = (bq * 4 + 1) * 520,
              hb2 = (bq * 4 + 2) * 520, hb3 = (bq * 4 + 3) * 520;
    for (int ph = 0; ph < 65; ++ph) {
      if (ph < 64) {
        const int t = ph, po = t & 1, pn = po ^ 1;
        for (int q = tid; q < 2048; q += 1024) {
          int bb = q >> 7, kq = q & 127;
          ((float4*)&hl[bb * 520])[kq] = ((const float4*)&h0g[(size_t)(po * 16 + bb) * 512])[kq];
        }
        if (tid < 512) {
          int bb = tid >> 5, g = (tid >> 3) & 3, j2 = tid & 7;
          xpl[tid] = xpart[((size_t)t * 16 + bb) * G4H + g * 512 + j0 + j2];
        }
        __syncthreads();
        if (tid < 256) {
          float4 a0 = {0,0,0,0}, a1 = {0,0,0,0}, a2 = {0,0,0,0}, a3 = {0,0,0,0};
#pragma unroll 4
          for (int i = 0; i < 16; ++i) {
            const int off = ks * 4 + 32 * i;
            float4 w4a = *(const float4*)&w0[wr0 + off];
            float4 w4b = *(const float4*)&w0[wr1 + off];
            float4 w4c = *(const float4*)&w0[wr2 + off];
            float4 w4d = *(const float4*)&w0[wr3 + off];
            float4 h4a = *(const float4*)&hl[hb0 + off];
            float4 h4b = *(const float4*)&hl[hb1 + off];
            float4 h4c = *(const float4*)&hl[hb2 + off];
            float4 h4d = *(const float4*)&hl[hb3 + off];
            a0.x += w4a.x*h4a.x + w4a.y*h4a.y + w4a.z*h4a.z + w4a.w*h4a.w;
            a0.y += w4a.x*h4b.x + w4a.y*h4b.y + w4a.z*h4b.z + w4a.w*h4b.w;
            a0.z += w4a.x*h4c.x + w4a.y*h4c.y + w4a.z*h4c.z + w4a.w*h4c.w;
            a0.w += w4a.x*h4d.x + w4a.y*h4d.y + w4a.z*h4d.z + w4a.w*h4d.w;
            a1.x += w4b.x*h4a.x + w4b.y*h4a.y + w4b.z*h4a.z + w4b.w*h4a.w;
            a1.y += w4b.x*h4b.x + w4b.y*h4b.y + w4b.z*h4b.z + w4b.w*h4b.w;
            a1.z += w4b.x*h4c.x + w4b.y*h4c.y + w4b.z*h4c.z + w4b.w*h4c.w;
            a1.w += w4b.x*h4d.x + w4b.y*h4d.y + w4b.z*h4d.z + w4b.w*h4d.w;
            a2.x += w4c.x*h4a.x + w4c.y*h4a.y + w4c.z*h4a.z + w4c.w*h4a.w;
            a2.y += w4c.x*h4b.x + w4c.y*h4b.y + w4c.z*h4b.z + w4c.w*h4b.w;
            a2.z += w4c.x*h4c.x + w4c.y*h4c.y + w4c.z*h4c.z + w4c.w*h4c.w;
            a2.w += w4c.x*h4d.x + w4c.y*h4d.y + w4c.z*h4d.z + w4c.w*h4d.w;
            a3.x += w4d.x*h4a.x + w4d.y*h4a.y + w4d.z*h4a.z + w4d.w*h4a.w;
            a3.y += w4d.x*h4b.x + w4d.y*h4b.y + w4d.z*h4b.z + w4d.w*h4b.w;
            a3.z += w4d.x*h4c.x + w4d.y*h4c.y + w4d.z*h4c.z + w4d.w*h4c.w;
            a3.w += w4d.x*h4d.x + w4d.y*h4d.y + w4d.z*h4d.z + w4d.w*h4d.w;
          }
          *(float4*)&sc[ks * 512 + (0 * 8 + jj) * 16 + bq * 4] = a0;
          *(float4*)&sc[ks * 512 + (1 * 8 + jj) * 16 + bq * 4] = a1;
          *(float4*)&sc[ks * 512 + (2 * 8 + jj) * 16 + bq * 4] = a2;
          *(float4*)&sc[ks * 512 + (3 * 8 + jj) * 16 + bq * 4] = a3;
        }
        __syncthreads();
        if (tid < 128) {
          const int bb = tid >> 3, j2 = tid & 7;
          float gs[4];
#pragma unroll
          for (int g = 0; g < 4; ++g) {
            float s = 0.f;
#pragma unroll
            for (int k2 = 0; k2 < 8; ++k2) s += sc[k2 * 512 + (g * 8 + j2) * 16 + bb];
            gs[g] = s + xpl[bb * 32 + g * 8 + j2];
          }
          float gi = sig_(gs[0]), gf = sig_(gs[1]), gg = tanhf(gs[2]), go_ = sig_(gs[3]);
          float cc = gf * c0l[j2 * 16 + bb] + gi * gg;
          c0l[j2 * 16 + bb] = cc;
          h0g[(size_t)(pn * 16 + bb) * 512 + j0 + j2] = go_ * tanhf(cc);
        }
      }
      gbar(done, go, (unsigned)(ph + 1), rnk, tid);
    }
  } else if (role == 1) {
    // ================= cell1 (rank idx in 64..191) =================
    float* w1 = SMEM;               // [16][1028]
    float* h0l = SMEM + 16448;      // [16][520]
    float* h1l = h0l + 8320;        // [16][520]
    float* sc = h1l + 8320;         // [16][256]
    float* c1l = sc + 4096;         // [64]
    float* bl = c1l + 64;           // [16]
    const int rnk = idx;
    const int j0 = (rnk - 64) * 4;
    for (int lr = 0; lr < 16; ++lr) {
      int g = lr >> 2, jj2 = lr & 3;
      const float* si = Wih1 + (size_t)(g * 512 + j0 + jj2) * 512;
      const float* sh = Whh1 + (size_t)(g * 512 + j0 + jj2) * 512;
      for (int k = tid; k < 512; k += 1024) {
        w1[lr * 1028 + k] = si[k];
        w1[lr * 1028 + 512 + k] = sh[k];
      }
    }
    if (tid < 64) c1l[tid] = 0.f;
    if (tid < 16) {
      int g = tid >> 2, jj2 = tid & 3;
      bl[tid] = bih1[g * 512 + j0 + jj2] + bhh1[g * 512 + j0 + jj2];
    }
    const int ks = tid & 15, bq = (tid >> 4) & 3, jj = (tid >> 6) & 3;
    const int wr0 = (0 * 4 + jj) * 1028, wr1 = (1 * 4 + jj) * 1028,
              wr2 = (2 * 4 + jj) * 1028, wr3 = (3 * 4 + jj) * 1028;
    const int hb0 = (bq * 4 + 0) * 520, hb1 = (bq * 4 + 1) * 520,
              hb2 = (bq * 4 + 2) * 520, hb3 = (bq * 4 + 3) * 520;
    for (int ph = 0; ph < 65; ++ph) {
      if (ph >= 1) {
        const int t = ph - 1, po = t & 1, pn = po ^ 1;
        for (int q = tid; q < 2048; q += 1024) {
          int bb = q >> 7, kq = q & 127;
          ((float4*)&h0l[bb * 520])[kq] = ((const float4*)&h0g[(size_t)(pn * 16 + bb) * 512])[kq];
          ((float4*)&h1l[bb * 520])[kq] = ((const float4*)&h1g[(size_t)(po * 16 + bb) * 512])[kq];
        }
        __syncthreads();
        if (tid < 256) {
          float4 a0 = {0,0,0,0}, a1 = {0,0,0,0}, a2 = {0,0,0,0}, a3 = {0,0,0,0};
#pragma unroll 4
          for (int i = 0; i < 16; ++i) {
            const int offw = ks * 4 + 64 * i;
            const int offh = (i < 8) ? offw : (offw - 512);
            const float* hsrc = (i < 8) ? h0l : h1l;
            float4 w4a = *(const float4*)&w1[wr0 + offw];
            float4 w4b = *(const float4*)&w1[wr1 + offw];
            float4 w4c = *(const float4*)&w1[wr2 + offw];
            float4 w4d = *(const float4*)&w1[wr3 + offw];
            float4 h4a = *(const float4*)&hsrc[hb0 + offh];
            float4 h4b = *(const float4*)&hsrc[hb1 + offh];
            float4 h4c = *(const float4*)&hsrc[hb2 + offh];
            float4 h4d = *(const float4*)&hsrc[hb3 + offh];
            a0.x += w4a.x*h4a.x + w4a.y*h4a.y + w4a.z*h4a.z + w4a.w*h4a.w;
            a0.y += w4a.x*h4b.x + w4a.y*h4b.y + w4a.z*h4b.z + w4a.w*h4b.w;
            a0.z += w4a.x*h4c.x + w4a.y*h4c.y + w4a.z*h4c.z + w4a.w*h4c.w;
            a0.w += w4a.x*h4d.x + w4a.y*h4d.y + w4a.z*h4d.z + w4a.w*h4d.w;
            a1.x += w4b.x*h4a.x + w4b.y*h4a.y + w4b.z*h4a.z + w4b.w*h4a.w;
            a1.y += w4b.x*h4b.x + w4b.y*h4b.y + w4b.z*h4b.z + w4b.w*h4b.w;
            a1.z += w4b.x*h4c.x + w4b.y*h4c.y + w4b.z*h4c.z + w4b.w*h4c.w;
            a1.w += w4b.x*h4d.x + w4b.y*h4d.y + w4b.z*h4d.z + w4b.w*h4d.w;
            a2.x += w4c.x*h4a.x + w4c.y*h4a.y + w4c.z*h4a.z + w4c.w*h4a.w;
            a2.y += w4c.x*h4b.x + w4c.y*h4b.y + w4c.z*h4b.z + w4c.w*h4b.w;
            a2.z += w4c.x*h4c.x + w4c.y*h4c.y + w4c.z*h4c.z + w4c.w*h4c.w;
            a2.w += w4c.x*h4d.x + w4c.y*h4d.y + w4c.z*h4d.z + w4c.w*h4d.w;
            a3.x += w4d.x*h4a.x + w4d.y*h4a.y + w4d.z*h4a.z + w4d.w*h4a.w;
            a3.y += w4d.x*h4b.x + w4d.y*h4b.y + w4d.z*h4b.z + w4d.w*h4b.w;
            a3.z += w4d.x*h4c.x + w4d.y*h4c.y + w4d.z*h4c.z + w4d.w*h4c.w;
            a3.w += w4d.x*h4d.x + w4d.y*h4d.y + w4d.z*h4d.z + w4d.w*h4d.w;
          }
          *(float4*)&sc[ks * 256 + (0 * 4 + jj) * 16 + bq * 4] = a0;
          *(float4*)&sc[ks * 256 + (1 * 4 + jj) * 16 + bq * 4] = a1;
          *(float4*)&sc[ks * 256 + (2 * 4 + jj) * 16 + bq * 4] = a2;
          *(float4*)&sc[ks * 256 + (3 * 4 + jj) * 16 + bq * 4] = a3;
        }
        __syncthreads();
        if (tid < 64) {
          const int bb = tid >> 2, j2 = tid & 3;
          float gs[4];
#pragma unroll
          for (int g = 0; g < 4; ++g) {
            float s = 0.f;
#pragma unroll
            for (int k2 = 0; k2 < 16; ++k2) s += sc[k2 * 256 + (g * 4 + j2) * 16 + bb];
            gs[g] = s + bl[g * 4 + j2];
          }
          float gi = sig_(gs[0]), gf = sig_(gs[1]), gg = tanhf(gs[2]), go_ = sig_(gs[3]);
          float cc = gf * c1l[j2 * 16 + bb] + gi * gg;
          c1l[j2 * 16 + bb] = cc;
          float hv = go_ * tanhf(cc);
          h1g[(size_t)(pn * 16 + bb) * 512 + j0 + j2] = hv;
          h1_all[((size_t)t * 16 + bb) * 512 + j0 + j2] = hv;
        }
      }
      gbar(done, go, (unsigned)(ph + 1), rnk, tid);
    }
  } else if (role == 2) {
    // ================= xi producer (one per batch), 4-step chunks =================
    const int b = idx;
    float* sh1 = SMEM;        // [512]
    float* sxo = SMEM + 512;  // [2][512]
    __shared__ unsigned sgo;
    unsigned seen_go = 0;
    for (int tc = 0; tc < TZ / 4; ++tc) {
      const unsigned need = (unsigned)(4 * tc + 5);  // h1(4tc+3) visible at go >= 4tc+5
      if (tid == 0 && seen_go < need) {
        sgo = poll_acq<8>(go, need);
      }
      __syncthreads();
      if (seen_go < need) seen_go = sgo;
      for (int k4 = 0; k4 < 4; ++k4) {
        const int t = 4 * tc + k4;
        if (tid < 512) sh1[tid] = h1_all[((size_t)t * BZ + b) * HID + tid];
        __syncthreads();
        {
          const int u = tid & 511, half = tid >> 9;
          if (u < IFC) {
            const float* wc = WifT + u;
            const int k0 = half * 256;
            float acc = 0.f;
#pragma unroll 8
            for (int k = k0; k < k0 + 256; ++k)
              acc = fmaf(sh1[k], wc[(size_t)k * 512], acc);
            sxo[half * 512 + u] = acc;
          }
        }
        __syncthreads();
        if (tid < IFC)
          xi_all[((size_t)t * BZ + b) * 512 + tid] = sxo[tid] + sxo[512 + tid] + bif[tid];
        __syncthreads();
      }
      if (tid == 0)
        __hip_atomic_store(&xiflag[b], (unsigned)(4 * tc + 4), __ATOMIC_RELEASE, __HIP_MEMORY_SCOPE_AGENT);
    }
  } else {
    // ================= memory-module chain (one per batch) =================
    const int b = idx;
    const int lane = tid & 63;
    const int wv = tid >> 6;
    const int m8 = tid & 255;
    const int seg = tid >> 8;
    float* LNK = linkg + (size_t)b * (NCELL * NCELL);

    float* smemT = SMEM;               // 16448
    float* sxi   = smemT + 16448;      // 472
    float* srkn  = sxi + 472;          // 256 [4][64]
    float* swkn  = srkn + 256;         // 64
    float* sev   = swkn + 64;          // 64
    float* swvv  = sev + 64;           // 64
    float* sscal = swvv + 64;          // 40
    float* srw   = sscal + 40;         // 1024 [4][256]
    float* sww   = srw + 1024;         // 256
    float* susage = sww + 256;         // 256
    float* sprec = susage + 256;       // 256
    float* ssim  = sprec + 256;        // 1024 [4][256]
    float* sfwd  = ssim + 1024;        // 1024 [4][256]
    float* sbwd  = sfwd + 1024;        // 1056 [4][264]
    float* sa    = sbwd + 1056;        // 256
    float* sc_   = sa + 256;           // 256
    float* sb_   = sc_ + 256;          // 256
    int*   srank = (int*)(sb_ + 256);  // 256
    float* scr   = (float*)(srank + 256); // 5280 [4][1320]
    float* sred2 = scr + 5280;         // 64
    __shared__ unsigned sflag;

    for (int i = tid; i < CSZ * SMT; i += 1024) smemT[i] = 0.f;
    if (tid < 256) {
      sww[tid] = 0.f; susage[tid] = 0.f; sprec[tid] = 0.f;
      srw[tid] = 0.f; srw[256 + tid] = 0.f; srw[512 + tid] = 0.f; srw[768 + tid] = 0.f;
    }
    for (int i = tid; i < (NCELL * NCELL) / 4; i += 1024)
      ((float4*)LNK)[i] = make_float4(0.f, 0.f, 0.f, 0.f);
    __syncthreads();

    unsigned seen = 0;
    for (int t = 0; t < TZ; ++t) {
      if (tid == 0 && seen < (unsigned)(t + 1)) {
        sflag = poll_acq<8>(&xiflag[b], (unsigned)(t + 1));
      }
      __syncthreads();
      if (seen < (unsigned)(t + 1)) seen = sflag;

      // ---- P0: load + parse xi ----
      if (tid < IFC) sxi[tid] = xi_all[((size_t)t * BZ + b) * 512 + tid];
      __syncthreads();
      if (wv < 4) {
        float v = tanhf(sxi[wv * 64 + lane]);
        float s2 = v * v;
#pragma unroll
        for (int off = 32; off; off >>= 1) s2 += __shfl_xor(s2, off);
        srkn[wv * 64 + lane] = v / (sqrtf(s2) + DEL);
      } else if (wv == 4) {
        float v = tanhf(sxi[260 + lane]);
        float s2 = v * v;
#pragma unroll
        for (int off = 32; off; off >>= 1) s2 += __shfl_xor(s2, off);
        swkn[lane] = v / (sqrtf(s2) + DEL);
      } else if (wv == 5) {
        sev[lane] = sig_(sxi[325 + lane]);
      } else if (wv == 6) {
        swvv[lane] = tanhf(sxi[389 + lane]);
      } else if (wv == 7) {
        if (lane < 4) sscal[lane] = splus_(sxi[256 + lane]);
        if (lane == 4) sscal[4] = splus_(sxi[324]);
        if (lane >= 8 && lane < 12) sscal[lane] = sig_(sxi[453 + (lane - 8)]);
        if (lane == 12) sscal[12] = sig_(sxi[457]);
        if (lane == 13) sscal[13] = sig_(sxi[458]);
        if (lane >= 16 && lane < 20) {
          int r = lane - 16;
          float a = sxi[459 + r * 3], b2 = sxi[460 + r * 3], c2 = sxi[461 + r * 3];
          float mx3 = fmaxf(a, fmaxf(b2, c2));
          float ea = expf(a - mx3), eb = expf(b2 - mx3), ec = expf(c2 - mx3);
          float iv = 1.f / (ea + eb + ec);
          sscal[20 + r * 3 + 0] = ea * iv;
          sscal[20 + r * 3 + 1] = eb * iv;
          sscal[20 + r * 3 + 2] = ec * iv;
        }
      }
      __syncthreads();

      // ---- P1: usage update + write-content dot (old mem); direct-exp softmax ----
      float un_r = 0.f;
      if (tid < 256) {
        float wwo = sww[tid], uo = susage[tid];
        float u1 = uo + (1.f - uo) * wwo;
        float psi = 1.f;
#pragma unroll
        for (int r = 0; r < 4; ++r) psi *= 1.f - sscal[8 + r] * srw[r * 256 + tid];
        un_r = u1 * psi;
        susage[tid] = un_r;
      }
      {
        float dot = 0.f, nn = 0.f;
#pragma unroll 4
        for (int w = seg * 16; w < seg * 16 + 16; ++w) {
          float mv = smemT[w * SMT + m8];
          dot = fmaf(mv, swkn[w], dot);
          nn = fmaf(mv, mv, nn);
        }
        SCR(seg, 0 * 264 + m8) = dot;
        SCR(seg, 1 * 264 + m8) = nn;
      }
      __syncthreads();
      float e_r = 0.f;
      if (tid < 256) {
        float dot = SCR(0, tid) + SCR(1, tid) + SCR(2, tid) + SCR(3, tid);
        float nn = SCR(0, 264 + tid) + SCR(1, 264 + tid) + SCR(2, 264 + tid) + SCR(3, 264 + tid);
        float simv = sscal[4] * dot / (sqrtf(nn) + DEL);
        e_r = expf(simv);   // |simv| <= ~22 -> no overflow; softmax ratio unchanged
        float s = e_r;
#pragma unroll
        for (int off = 32; off; off >>= 1) s += __shfl_xor(s, off);
        if (lane == 0) sred2[8 + wv] = s;
      }
      __syncthreads();
      float wcw_r = 0.f;
      if (tid < 256) {
        float sm = sred2[8] + sred2[9] + sred2[10] + sred2[11];
        wcw_r = e_r / sm;
        sa[tid] = DEL + (1.f - DEL) * un_r;
      }
      __syncthreads();

      // ---- P2: allocation (stable rank + exclusive cumprod) ----
      {
        float um = sa[m8];
        int cnt = 0;
        for (int j2 = seg * 64; j2 < seg * 64 + 64; ++j2) {
          float uj = sa[j2];
          cnt += (uj < um || (uj == um && j2 < m8)) ? 1 : 0;
        }
        ((int*)&SCR(seg, 0))[m8] = cnt;
      }
      __syncthreads();
      if (tid < 256) {
        int rank = ((int*)&SCR(0, 0))[tid] + ((int*)&SCR(1, 0))[tid] +
                   ((int*)&SCR(2, 0))[tid] + ((int*)&SCR(3, 0))[tid];
        srank[tid] = rank;
        sb_[rank] = sa[tid];
      }
      __syncthreads();
      float inc = 0.f;
      if (tid < 256) {
        inc = sb_[tid];
#pragma unroll
        for (int off = 1; off < 64; off <<= 1) {
          float pp = __shfl_up(inc, off);
          if (lane >= off) inc *= pp;
        }
        if (lane == 63) sred2[16 + wv] = inc;
      }
      __syncthreads();
      if (tid < 256) {
        float pref = 1.f;
        for (int w2 = 0; w2 < wv; ++w2) pref *= sred2[16 + w2];
        float excl = __shfl_up(inc, 1);
        if (lane == 0) excl = 1.f;
        sc_[tid] = excl * pref;
      }
      __syncthreads();

      // ---- P3: write weighting + wsum ----
      if (tid < 256) {
        float alo = (1.f - sa[tid]) * sc_[srank[tid]];
        float wwn = sscal[13] * (sscal[12] * alo + (1.f - sscal[12]) * wcw_r);
        sww[tid] = wwn;
        float s = wwn;
#pragma unroll
        for (int off = 32; off; off >>= 1) s += __shfl_xor(s, off);
        if (lane == 0) sred2[24 + wv] = s;
      }
      __syncthreads();
      if (tid == 0) sscal[14] = sred2[24] + sred2[25] + sred2[26] + sred2[27];

      // ---- P4: memory erase/write + read-content sims; direct-exp softmax ----
      {
        float wm = sww[m8];
        float nn = 0.f, d0 = 0.f, d1 = 0.f, d2 = 0.f, d3 = 0.f;
#pragma unroll 4
        for (int w = seg * 16; w < seg * 16 + 16; ++w) {
          float v = smemT[w * SMT + m8];
          v = v * (1.f - wm * sev[w]) + wm * swvv[w];
          smemT[w * SMT + m8] = v;
          nn = fmaf(v, v, nn);
          d0 = fmaf(v, srkn[0 * 64 + w], d0);
          d1 = fmaf(v, srkn[1 * 64 + w], d1);
          d2 = fmaf(v, srkn[2 * 64 + w], d2);
          d3 = fmaf(v, srkn[3 * 64 + w], d3);
        }
        SCR(seg, 0 * 264 + m8) = nn;
        SCR(seg, 1 * 264 + m8) = d0;
        SCR(seg, 2 * 264 + m8) = d1;
        SCR(seg, 3 * 264 + m8) = d2;
        SCR(seg, 4 * 264 + m8) = d3;
      }
      for (int i = tid; i < NRD * 264; i += 1024) sbwd[i] = 0.f;
      __syncthreads();
      float e0 = 0.f, e1 = 0.f, e2 = 0.f, e3 = 0.f;
      if (tid < 256) {
        float nn = SCR(0, tid) + SCR(1, tid) + SCR(2, tid) + SCR(3, tid);
        float invn = 1.f / (sqrtf(nn) + DEL);
        float sv0 = sscal[0] * (SCR(0, 264 + tid) + SCR(1, 264 + tid) + SCR(2, 264 + tid) + SCR(3, 264 + tid)) * invn;
        float sv1 = sscal[1] * (SCR(0, 528 + tid) + SCR(1, 528 + tid) + SCR(2, 528 + tid) + SCR(3, 528 + tid)) * invn;
        float sv2 = sscal[2] * (SCR(0, 792 + tid) + SCR(1, 792 + tid) + SCR(2, 792 + tid) + SCR(3, 792 + tid)) * invn;
        float sv3 = sscal[3] * (SCR(0, 1056 + tid) + SCR(1, 1056 + tid) + SCR(2, 1056 + tid) + SCR(3, 1056 + tid)) * invn;
        e0 = expf(sv0); e1 = expf(sv1); e2 = expf(sv2); e3 = expf(sv3);
        float s0 = e0, s1 = e1, s2 = e2, s3 = e3;
#pragma unroll
        for (int off = 32; off; off >>= 1) {
          s0 += __shfl_xor(s0, off); s1 += __shfl_xor(s1, off);
          s2 += __shfl_xor(s2, off); s3 += __shfl_xor(s3, off);
        }
        if (lane == 0) {
          sred2[32 + wv * 4 + 0] = s0; sred2[32 + wv * 4 + 1] = s1;
          sred2[32 + wv * 4 + 2] = s2; sred2[32 + wv * 4 + 3] = s3;
        }
      }
      __syncthreads();
      if (tid < 256) {
        float s0 = sred2[32] + sred2[36] + sred2[40] + sred2[44];
        float s1 = sred2[33] + sred2[37] + sred2[41] + sred2[45];
        float s2 = sred2[34] + sred2[38] + sred2[42] + sred2[46];
        float s3 = sred2[35] + sred2[39] + sred2[43] + sred2[47];
        ssim[0 * 256 + tid] = e0 / s0; ssim[1 * 256 + tid] = e1 / s1;
        ssim[2 * 256 + tid] = e2 / s2; ssim[3 * 256 + tid] = e3 / s3;
      }

      // ---- P5: link update + fwd + bwd, coalesced row-per-wave pass ----
      {
        const float4 r0 = ((const float4*)(srw + 0 * 256))[lane];
        const float4 r1 = ((const float4*)(srw + 1 * 256))[lane];
        const float4 r2 = ((const float4*)(srw + 2 * 256))[lane];
        const float4 r3 = ((const float4*)(srw + 3 * 256))[lane];
        const float4 wc = ((const float4*)sww)[lane];
        const float4 pc = ((const float4*)sprec)[lane];
        const int n0 = lane * 4;
        float4 bp0 = {0,0,0,0}, bp1 = {0,0,0,0}, bp2 = {0,0,0,0}, bp3 = {0,0,0,0};
        for (int rr = 0; rr < 16; ++rr) {
          const int m = wv * 16 + rr;
          const float wm = sww[m];
          float4 lv = ((float4*)(LNK + (size_t)m * 256))[lane];
          lv.x = (1.f - wm - wc.x) * lv.x + wm * pc.x;
          lv.y = (1.f - wm - wc.y) * lv.y + wm * pc.y;
          lv.z = (1.f - wm - wc.z) * lv.z + wm * pc.z;
          lv.w = (1.f - wm - wc.w) * lv.w + wm * pc.w;
          if (m == n0 + 0) lv.x = 0.f;
          if (m == n0 + 1) lv.y = 0.f;
          if (m == n0 + 2) lv.z = 0.f;
          if (m == n0 + 3) lv.w = 0.f;
          ((float4*)(LNK + (size_t)m * 256))[lane] = lv;
          float f0 = lv.x * r0.x + lv.y * r0.y + lv.z * r0.z + lv.w * r0.w;
          float f1 = lv.x * r1.x + lv.y * r1.y + lv.z * r1.z + lv.w * r1.w;
          float f2 = lv.x * r2.x + lv.y * r2.y + lv.z * r2.z + lv.w * r2.w;
          float f3 = lv.x * r3.x + lv.y * r3.y + lv.z * r3.z + lv.w * r3.w;
#pragma unroll
          for (int off = 32; off; off >>= 1) {
            f0 += __shfl_xor(f0, off); f1 += __shfl_xor(f1, off);
            f2 += __shfl_xor(f2, off); f3 += __shfl_xor(f3, off);
          }
          if (lane == 0) {
            sfwd[0 * 256 + m] = f0; sfwd[1 * 256 + m] = f1;
            sfwd[2 * 256 + m] = f2; sfwd[3 * 256 + m] = f3;
          }
          const float s0 = srw[0 * 256 + m], s1 = srw[1 * 256 + m],
                      s2 = srw[2 * 256 + m], s3 = srw[3 * 256 + m];
          bp0.x = fmaf(lv.x, s0, bp0.x); bp0.y = fmaf(lv.y, s0, bp0.y);
          bp0.z = fmaf(lv.z, s0, bp0.z); bp0.w = fmaf(lv.w, s0, bp0.w);
          bp1.x = fmaf(lv.x, s1, bp1.x); bp1.y = fmaf(lv.y, s1, bp1.y);
          bp1.z = fmaf(lv.z, s1, bp1.z); bp1.w = fmaf(lv.w, s1, bp1.w);
          bp2.x = fmaf(lv.x, s2, bp2.x); bp2.y = fmaf(lv.y, s2, bp2.y);
          bp2.z = fmaf(lv.z, s2, bp2.z); bp2.w = fmaf(lv.w, s2, bp2.w);
          bp3.x = fmaf(lv.x, s3, bp3.x); bp3.y = fmaf(lv.y, s3, bp3.y);
          bp3.z = fmaf(lv.z, s3, bp3.z); bp3.w = fmaf(lv.w, s3, bp3.w);
        }
        atomicAdd(&sbwd[0 * 264 + n0 + 0], bp0.x); atomicAdd(&sbwd[0 * 264 + n0 + 1], bp0.y);
        atomicAdd(&sbwd[0 * 264 + n0 + 2], bp0.z); atomicAdd(&sbwd[0 * 264 + n0 + 3], bp0.w);
        atomicAdd(&sbwd[1 * 264 + n0 + 0], bp1.x); atomicAdd(&sbwd[1 * 264 + n0 + 1], bp1.y);
        atomicAdd(&sbwd[1 * 264 + n0 + 2], bp1.z); atomicAdd(&sbwd[1 * 264 + n0 + 3], bp1.w);
        atomicAdd(&sbwd[2 * 264 + n0 + 0], bp2.x); atomicAdd(&sbwd[2 * 264 + n0 + 1], bp2.y);
        atomicAdd(&sbwd[2 * 264 + n0 + 2], bp2.z); atomicAdd(&sbwd[2 * 264 + n0 + 3], bp2.w);
        atomicAdd(&sbwd[3 * 264 + n0 + 0], bp3.x); atomicAdd(&sbwd[3 * 264 + n0 + 1], bp3.y);
        atomicAdd(&sbwd[3 * 264 + n0 + 2], bp3.z); atomicAdd(&sbwd[3 * 264 + n0 + 3], bp3.w);
      }
      __syncthreads();

      // ---- P7: rw update + precedence ----
      if (tid < 256) {
#pragma unroll
        for (int r = 0; r < 4; ++r) {
          float rwn = sscal[20 + r * 3 + 0] * sbwd[r * 264 + tid] +
                      sscal[20 + r * 3 + 1] * sfwd[r * 256 + tid] +
                      sscal[20 + r * 3 + 2] * ssim[r * 256 + tid];
          srw[r * 256 + tid] = rwn;
        }
        sprec[tid] = (1.f - sscal[14]) * sprec[tid] + sww[tid];
      }
      __syncthreads();

      // ---- P8: read vectors ----
      {
        const int r = tid >> 8, sg = (tid >> 6) & 3, w = lane;
        float acc = 0.f;
#pragma unroll 4
        for (int m2 = sg * 64; m2 < sg * 64 + 64; ++m2)
          acc = fmaf(srw[r * 256 + m2], smemT[w * SMT + m2], acc);
        SCR(sg, r * 64 + w) = acc;
      }
      __syncthreads();
      if (tid < 256)
        rv_all[((size_t)t * BZ + b) * 256 + tid] =
            SCR(0, tid) + SCR(1, tid) + SCR(2, tid) + SCR(3, tid);
      __syncthreads();
    }
  }
}

// ---------------------------------------------------------------- out GEMM
__global__ __launch_bounds__(256) void k_out(const float* __restrict__ h1_all,
                                             const float* __restrict__ WoutT,
                                             const float* __restrict__ bout,
                                             float* __restrict__ out_all) {
  const int lane = threadIdx.x, ty = threadIdx.y;
  const int u = blockIdx.x * 64 + lane;
  const int row0 = blockIdx.y * 16;
  __shared__ float sh[16][512];
  const int tid = ty * 64 + lane;
  for (int idx = tid; idx < 16 * 512; idx += 256) {
    int r2 = idx >> 9, k = idx & 511;
    sh[r2][k] = h1_all[(size_t)(row0 + r2) * 512 + k];
  }
  __syncthreads();
  const float* wcol = WoutT + u;
  float bias = bout[u];
  float acc[4] = {0.f, 0.f, 0.f, 0.f};
  for (int k = 0; k < 512; ++k) {
    float wv = wcol[(size_t)k * 512];
#pragma unroll
    for (int i = 0; i < 4; ++i) acc[i] = fmaf(wv, sh[ty * 4 + i][k], acc[i]);
  }
#pragma unroll
  for (int i = 0; i < 4; ++i)
    out_all[(size_t)(row0 + ty * 4 + i) * 512 + u] = acc[i] + bias;
}

// ---------------------------------------------------------------- final y GEMM
__global__ __launch_bounds__(256) void k_y(const float* __restrict__ out_all,
                                           const float* __restrict__ rv_all,
                                           const float* __restrict__ WmemT,
                                           const float* __restrict__ bmem,
                                           float* __restrict__ y) {
  const int lane = threadIdx.x, ty = threadIdx.y;
  const int o = blockIdx.x * 64 + lane;
  const int tb0 = blockIdx.y * 16;
  __shared__ float sin_[16][768];
  const int tid = ty * 64 + lane;
  for (int idx = tid; idx < 16 * 768; idx += 256) {
    int row = idx / 768, k = idx % 768;
    int tb = tb0 + row;
    sin_[row][k] = (k < 512) ? out_all[(size_t)tb * HID + k]
                             : rv_all[(size_t)tb * 256 + (k - 512)];
  }
  __syncthreads();
  float acc[4] = {0.f, 0.f, 0.f, 0.f};
  for (int k = 0; k < 768; ++k) {
    float wv = WmemT[(size_t)k * 256 + o];
#pragma unroll
    for (int i = 0; i < 4; ++i) acc[i] = fmaf(wv, sin_[ty * 4 + i][k], acc[i]);
  }
  float bo = bmem[o];
#pragma unroll
  for (int i = 0; i < 4; ++i) {
    int tb = tb0 + ty * 4 + i;
    int tt = tb >> 4, bb = tb & 15;
    y[((size_t)bb * TZ + tt) * 256 + o] = acc[i] + bo;
  }
}

extern "C" void kernel_launch(void* const* d_in, const int* in_sizes, int n_in,
                              void* d_out, int out_size, void* d_ws, size_t ws_size,
                              hipStream_t stream) {
  (void)in_sizes; (void)n_in; (void)out_size; (void)ws_size;
  const float* x    = (const float*)d_in[0];
  const float* Wih0 = (const float*)d_in[1];
  const float* bih0 = (const float*)d_in[2];
  const float* Whh0 = (const float*)d_in[3];
  const float* bhh0 = (const float*)d_in[4];
  const float* Wih1 = (const float*)d_in[5];
  const float* bih1 = (const float*)d_in[6];
  const float* Whh1 = (const float*)d_in[7];
  const float* bhh1 = (const float*)d_in[8];
  const float* Wout = (const float*)d_in[9];
  const float* bout = (const float*)d_in[10];
  const float* Wif  = (const float*)d_in[11];
  const float* bif  = (const float*)d_in[12];
  const float* Wmem = (const float*)d_in[13];
  const float* bmem = (const float*)d_in[14];
  float* y = (float*)d_out;

  float* p = (float*)d_ws;
  auto take = [&](size_t n) { float* q = p; p += n; return q; };
  float* Wih0T   = take((size_t)256 * 2048);
  float* WoutT   = take((size_t)512 * 512);
  float* WifT    = take((size_t)512 * 512);
  float* WmemT   = take((size_t)768 * 256);
  float* xpart   = take((size_t)TZ * BZ * G4H);
  float* h1_all  = take((size_t)TZ * BZ * HID);
  float* out_all = take((size_t)TZ * BZ * HID);
  float* xi_all  = take((size_t)TZ * BZ * 512);
  float* rv_all  = take((size_t)TZ * BZ * 256);
  float* linkg   = take((size_t)BZ * NCELL * NCELL);
  float* zstart  = p;
  float* h0g     = take((size_t)2 * BZ * HID);
  float* h1g     = take((size_t)2 * BZ * HID);
  float* cntf    = take((size_t)512);
  size_t zbytes = (size_t)((char*)p - (char*)zstart);
  unsigned* done   = (unsigned*)cntf;        // [0..191] by LSTM rank
  unsigned* go     = done + 256;             // [1]
  unsigned* xiflag = done + 320;             // [16]

  (void)hipMemsetAsync(zstart, 0, zbytes, stream);

  dim3 tb32(32, 8);
  hipLaunchKernelGGL(k_transpose, dim3(8, 64), tb32, 0, stream, Wih0, Wih0T, 2048, 512, 256, 2048);
  hipLaunchKernelGGL(k_transpose, dim3(16, 16), tb32, 0, stream, Wout, WoutT, 512, 512, 512, 512);
  hipLaunchKernelGGL(k_transpose, dim3(16, 15), tb32, 0, stream, Wif, WifT, 471, 512, 512, 512);
  hipLaunchKernelGGL(k_transpose, dim3(24, 8), tb32, 0, stream, Wmem, WmemT, 256, 768, 768, 256);

  hipLaunchKernelGGL(k_xpart, dim3(32, 64), dim3(64, 4), 0, stream, x, Wih0T, bih0, bhh0, xpart);

  hipLaunchKernelGGL(k_fused, dim3(256), dim3(1024), 0, stream,
                     xpart, Whh0, Wih1, Whh1, bih1, bhh1, WifT, bif,
                     h0g, h1g, h1_all, xi_all, linkg, rv_all, done, go, xiflag);

  hipLaunchKernelGGL(k_out, dim3(8, 64), dim3(64, 4), 0, stream, h1_all, WoutT, bout, out_all);

  hipLaunchKernelGGL(k_y, dim3(4, 64), dim3(64, 4), 0, stream, out_all, rv_all, WmemT, bmem, y);
}